// Round 1
// baseline (1512.884 us; speedup 1.0000x reference)
//
#include <hip/hip_runtime.h>
#include <math.h>

#define N_NODES 1024
#define HDIM 128
#define EDGES 65536
#define LAYERS 6

// workspace float offsets
#define OFF_H     0
#define OFF_Q     131072
#define OFF_K     262144
#define OFF_V     393216
#define OFF_SKP   524288
#define OFF_G     655360
#define OFF_SS    917504
#define OFF_EA    920576
#define OFF_CVEC  986112
#define OFF_INT   986240
#define OFF_M     1054912
#define OFF_U     3152064

__device__ __forceinline__ float silu_f(float x) { return x / (1.f + expf(-x)); }

// ---------------- setup: timestep embedding -> t_mod -> ss[6][512], cvec ---------------
__global__ __launch_bounds__(512) void k_setup(const void* tptr,
    const float* __restrict__ Wt1, const float* __restrict__ bt1,
    const float* __restrict__ Wt2, const float* __restrict__ bt2,
    const float* __restrict__ Wa, const float* __restrict__ ba,
    const float* __restrict__ bb, const float* __restrict__ Wm1, const float* __restrict__ bm1,
    float* __restrict__ ss_all, float* __restrict__ cvec)
{
    __shared__ float emb_s[256];
    __shared__ float tmp1_s[128];
    __shared__ float tmod_s[128];
    int tid = threadIdx.x;
    int iv = *(const int*)tptr;
    float fv = __int_as_float(iv);
    float tval = (iv > -1000000 && iv < 1000000) ? (float)iv : fv;
    if (tid < 128) {
        float fr = expf(-logf(10000.f) * (float)tid / 128.f);
        float ta = tval * fr;
        emb_s[tid] = cosf(ta);
        emb_s[128 + tid] = sinf(ta);
    }
    __syncthreads();
    if (tid < 128) {
        float a = bt1[tid];
        for (int i = 0; i < 256; i++) a += emb_s[i] * Wt1[i * 128 + tid];
        tmp1_s[tid] = silu_f(a);
    }
    __syncthreads();
    if (tid < 128) {
        float a = bt2[tid];
        for (int i = 0; i < 128; i++) a += tmp1_s[i] * Wt2[i * 128 + tid];
        tmod_s[tid] = silu_f(a);
    }
    __syncthreads();
    for (int idx = tid; idx < LAYERS * 512; idx += 512) {
        int l = idx >> 9, j = idx & 511;
        float a = ba[l * 512 + j];
        const float* w = Wa + l * 65536 + j;
        for (int k = 0; k < 128; k++) a += tmod_s[k] * w[k * 512];
        ss_all[idx] = a;
    }
    if (tid < 128) {
        float a = bm1[tid];
        for (int o = 0; o < 128; o++) a += bb[o] * Wm1[o * 128 + tid];
        cvec[tid] = a;
    }
}

// ---------------- h = x @ Wn + bn  (K=5) ----------------
__global__ __launch_bounds__(256) void k_input(const float* __restrict__ x,
    const float* __restrict__ Wn, const float* __restrict__ bn, float* __restrict__ h)
{
    int idx = blockIdx.x * 256 + threadIdx.x;  // < 131072
    int i = idx >> 7, j = idx & 127;
    float acc = bn[j];
#pragma unroll
    for (int kk = 0; kk < 5; kk++) acc += x[i * 5 + kk] * Wn[kk * 128 + j];
    h[idx] = acc;
}

// ---------------- edge_attr ----------------
__global__ __launch_bounds__(256) void k_edge(const int* __restrict__ ei,
    const float* __restrict__ tm, const float* __restrict__ Wee, const float* __restrict__ bee,
    float* __restrict__ ea)
{
    int e = blockIdx.x * 256 + threadIdx.x;
    int s = ei[e], d = ei[EDGES + e];
    ea[e] = tm[s * N_NODES + d] * Wee[0] + bee[0];
}

// ---------------- CSR build ----------------
__global__ __launch_bounds__(256) void k_count(const int* __restrict__ ei, int* __restrict__ deg)
{
    int e = blockIdx.x * 256 + threadIdx.x;
    atomicAdd(&deg[ei[EDGES + e]], 1);
}

__global__ __launch_bounds__(1024) void k_scan(const int* __restrict__ deg, int* __restrict__ rowptr)
{
    __shared__ int tmp[1024];
    int tid = threadIdx.x;
    tmp[tid] = deg[tid];
    __syncthreads();
    for (int off = 1; off < 1024; off <<= 1) {
        int vv = (tid >= off) ? tmp[tid - off] : 0;
        __syncthreads();
        tmp[tid] += vv;
        __syncthreads();
    }
    rowptr[tid + 1] = tmp[tid];
    if (tid == 0) rowptr[0] = 0;
}

__global__ __launch_bounds__(256) void k_scatter(const int* __restrict__ ei,
    const int* __restrict__ rowptr, int* __restrict__ cursor, int* __restrict__ eorder)
{
    int e = blockIdx.x * 256 + threadIdx.x;
    int d = ei[EDGES + e];
    int pos = atomicAdd(&cursor[d], 1);
    eorder[rowptr[d] + pos] = e;
}

__global__ __launch_bounds__(256) void k_sort(const int* __restrict__ rowptr, int* __restrict__ eorder)
{
    int node = blockIdx.x * 256 + threadIdx.x;
    if (node >= N_NODES) return;
    int beg = rowptr[node], end = rowptr[node + 1];
    for (int i = beg + 1; i < end; ++i) {
        int key = eorder[i];
        int j = i - 1;
        while (j >= beg && eorder[j] > key) { eorder[j + 1] = eorder[j]; --j; }
        eorder[j + 1] = key;
    }
}

// ---------------- fused LN+mod + 4x GEMM (q,k,v,skip) ----------------
__global__ __launch_bounds__(256) void k_qkvs(const float* __restrict__ h,
    const float* __restrict__ ss,
    const float* __restrict__ Wq, const float* __restrict__ Wk,
    const float* __restrict__ Wv, const float* __restrict__ Wsk,
    const float* __restrict__ bq, const float* __restrict__ bk,
    const float* __restrict__ bv, const float* __restrict__ bsk,
    float* __restrict__ q, float* __restrict__ k, float* __restrict__ v, float* __restrict__ skp)
{
    __shared__ float a[16][128];
    __shared__ float mu_s[16], rs_s[16];
    int tid = threadIdx.x;
    int r0 = blockIdx.x * 16;
    for (int idx = tid; idx < 2048; idx += 256) a[idx >> 7][idx & 127] = h[r0 * 128 + idx];
    __syncthreads();
    if (tid < 16) {
        float s = 0.f, s2 = 0.f;
        for (int c = 0; c < 128; c++) { float xx = a[tid][c]; s += xx; s2 += xx * xx; }
        float mu = s * (1.f / 128.f);
        float var = s2 * (1.f / 128.f) - mu * mu;
        mu_s[tid] = mu; rs_s[tid] = rsqrtf(var + 1e-5f);
    }
    __syncthreads();
    const float* sh = ss; const float* sc = ss + 128;
    for (int idx = tid; idx < 2048; idx += 256) {
        int r = idx >> 7, c = idx & 127;
        a[r][c] = (a[r][c] - mu_s[r]) * rs_s[r] * (1.f + sc[c]) + sh[c];
    }
    __syncthreads();
    const float* W; const float* bias; float* out;
    switch (blockIdx.y) {
        case 0:  W = Wq;  bias = bq;  out = q;   break;
        case 1:  W = Wk;  bias = bk;  out = k;   break;
        case 2:  W = Wv;  bias = bv;  out = v;   break;
        default: W = Wsk; bias = bsk; out = skp; break;
    }
    int col = tid & 127, grp = tid >> 7;
    float acc[8] = {};
    for (int kk = 0; kk < 128; ++kk) {
        float bvv = W[kk * 128 + col];
#pragma unroll
        for (int rr = 0; rr < 8; rr++) acc[rr] += a[grp * 8 + rr][kk] * bvv;
    }
#pragma unroll
    for (int rr = 0; rr < 8; rr++)
        out[(r0 + grp * 8 + rr) * 128 + col] = acc[rr] + bias[col];
}

// ---------------- generic 16-row GEMM (optional LN front, gelu, add) ----------------
template <int K, int NCOL, bool LNF, bool GELU_ACT, bool ADD>
__global__ __launch_bounds__(256) void k_gemm(const float* __restrict__ A,
    const float* __restrict__ W, const float* __restrict__ bias, float* __restrict__ C,
    const float* __restrict__ sh, const float* __restrict__ sc)
{
    __shared__ float a[16][K];
    __shared__ float mu_s[16], rs_s[16];
    int tid = threadIdx.x;
    int r0 = blockIdx.x * 16;
    for (int idx = tid; idx < 16 * K; idx += 256) a[idx / K][idx % K] = A[r0 * K + idx];
    __syncthreads();
    if (LNF) {
        if (tid < 16) {
            float s = 0.f, s2 = 0.f;
            for (int c = 0; c < K; c++) { float xx = a[tid][c]; s += xx; s2 += xx * xx; }
            float mu = s * (1.f / K);
            float var = s2 * (1.f / K) - mu * mu;
            mu_s[tid] = mu; rs_s[tid] = rsqrtf(var + 1e-5f);
        }
        __syncthreads();
        for (int idx = tid; idx < 16 * K; idx += 256) {
            int r = idx / K, c = idx % K;
            a[r][c] = (a[r][c] - mu_s[r]) * rs_s[r] * (1.f + sc[c]) + sh[c];
        }
        __syncthreads();
    }
    constexpr int G = 256 / NCOL;
    constexpr int RPT = 16 / G;
    int col = tid % NCOL;
    int grp = tid / NCOL;
    float acc[RPT] = {};
    for (int kk = 0; kk < K; ++kk) {
        float bvv = W[kk * NCOL + col];
#pragma unroll
        for (int rr = 0; rr < RPT; rr++) acc[rr] += a[grp * RPT + rr][kk] * bvv;
    }
#pragma unroll
    for (int rr = 0; rr < RPT; rr++) {
        float y = acc[rr] + bias[col];
        if (GELU_ACT) y = 0.5f * y * (1.f + erff(y * 0.70710678118654752f));
        int r = r0 + grp * RPT + rr;
        if (ADD) C[r * NCOL + col] += y; else C[r * NCOL + col] = y;
    }
}

// ---------------- attention: one wave per dst node, online softmax over CSR edges -------
__global__ __launch_bounds__(64) void k_attn(const float* __restrict__ q,
    const float* __restrict__ k, const float* __restrict__ v,
    const float* __restrict__ skp, float* __restrict__ h,
    const int* __restrict__ ei, const float* __restrict__ ea,
    const float* __restrict__ We_l,
    const int* __restrict__ rowptr, const int* __restrict__ eorder)
{
    int node = blockIdx.x;
    int lane = threadIdx.x;
    int c0 = lane * 2;
    float q0 = q[node * 128 + c0], q1 = q[node * 128 + c0 + 1];
    float we0 = We_l[c0], we1 = We_l[c0 + 1];
    int beg = rowptr[node], end = rowptr[node + 1];
    float m = -INFINITY, s = 0.f, a0 = 0.f, a1 = 0.f;
    const float isc = 0.17677669529663687f;  // 1/sqrt(32)
    for (int t = beg; t < end; ++t) {
        int e = eorder[t];
        int sn = ei[e];                 // src
        float eav = ea[e];
        float k0 = k[sn * 128 + c0] + eav * we0;
        float k1 = k[sn * 128 + c0 + 1] + eav * we1;
        float part = q0 * k0 + q1 * k1;
        part += __shfl_xor(part, 1, 16);
        part += __shfl_xor(part, 2, 16);
        part += __shfl_xor(part, 4, 16);
        part += __shfl_xor(part, 8, 16);
        float alpha = part * isc;
        float mn = fmaxf(m, alpha);
        float scale = expf(m - mn);
        float w = expf(alpha - mn);
        s = s * scale + w;
        float v0 = v[sn * 128 + c0] + eav * we0;
        float v1 = v[sn * 128 + c0 + 1] + eav * we1;
        a0 = a0 * scale + w * v0;
        a1 = a1 * scale + w * v1;
        m = mn;
    }
    float inv = 1.f / (s + 1e-16f);
    int o = node * 128 + c0;
    h[o]     += skp[o]     + a0 * inv;
    h[o + 1] += skp[o + 1] + a1 * inv;
}

// ---------------- M[k][l][m] = sum_o Wb[o,k,l] * Wm1[o,m] ----------------
__global__ __launch_bounds__(256) void k_mprep(const float* __restrict__ Wb,
    const float* __restrict__ Wm1, float* __restrict__ M)
{
    __shared__ float wb_s[64][128];
    __shared__ float wm_s[64][128];
    int tid = threadIdx.x;
    int k = blockIdx.x;
    int mg = tid & 15, lg = tid >> 4;
    int m0 = mg * 8, l0 = lg * 8;
    float acc[8][8] = {};
    for (int oh = 0; oh < 2; ++oh) {
        __syncthreads();
        for (int idx = tid; idx < 8192; idx += 256) {
            int o = idx >> 7, c = idx & 127;
            wb_s[o][c] = Wb[(size_t)(oh * 64 + o) * 16384 + k * 128 + c];
            wm_s[o][c] = Wm1[(oh * 64 + o) * 128 + c];
        }
        __syncthreads();
        for (int o = 0; o < 64; o++) {
            float lv[8], mv[8];
#pragma unroll
            for (int i = 0; i < 8; i++) { lv[i] = wb_s[o][l0 + i]; mv[i] = wm_s[o][m0 + i]; }
#pragma unroll
            for (int li = 0; li < 8; li++)
#pragma unroll
                for (int mi = 0; mi < 8; mi++) acc[li][mi] += lv[li] * mv[mi];
        }
    }
    for (int li = 0; li < 8; li++)
        for (int mi = 0; mi < 8; mi++)
            M[(size_t)k * 16384 + (l0 + li) * 128 + (m0 + mi)] = acc[li][mi];
}

// ---------------- U[i][l][m] = sum_k h[i,k] * M[k][l][m] ----------------
__global__ __launch_bounds__(256) void k_phase1(const float* __restrict__ h,
    const float* __restrict__ M, float* __restrict__ U, int i0)
{
    __shared__ float a[16][128];
    int tid = threadIdx.x;
    int ib = i0 + blockIdx.y * 16;
    for (int idx = tid; idx < 2048; idx += 256) a[idx >> 7][idx & 127] = h[ib * 128 + idx];
    __syncthreads();
    int col = blockIdx.x * 256 + tid;
    float acc[16] = {};
    for (int kk = 0; kk < 128; kk++) {
        float bv = M[(size_t)kk * 16384 + col];
#pragma unroll
        for (int r = 0; r < 16; r++) acc[r] += a[r][kk] * bv;
    }
#pragma unroll
    for (int r = 0; r < 16; r++) U[(size_t)(blockIdx.y * 16 + r) * 16384 + col] = acc[r];
}

// ---------------- Y[j,m] = sum_l U[i][l][m]*h[j,l] + cvec; out = silu(Y)@Wm2+bm2 --------
__global__ __launch_bounds__(256) void k_phase2(const float* __restrict__ U,
    const float* __restrict__ h, const float* __restrict__ cvec,
    const float* __restrict__ Wm2, const float* __restrict__ bm2,
    float* __restrict__ out, int i0)
{
    __shared__ float Ut[64][132];   // [l-half][m] padded
    __shared__ float hs[64][68];    // [j][l-half] padded
    int tid = threadIdx.x;
    int ci = blockIdx.y;
    int gi = i0 + ci;
    int b = gi >> 8;
    int jb = blockIdx.x * 64;
    int mcol = tid & 31, jgrp = tid >> 5;
    int m0 = mcol * 4, j0 = jgrp * 8;
    float acc[8][4] = {};
    const float4* Usrc = (const float4*)(U + (size_t)ci * 16384);
    for (int lh = 0; lh < 2; ++lh) {
        __syncthreads();
        for (int idx = tid; idx < 2048; idx += 256) {
            int lr = idx >> 5;
            int mq = idx & 31;
            float4 uv = Usrc[(size_t)(lh * 64 + lr) * 32 + mq];
            *(float4*)&Ut[lr][mq * 4] = uv;
        }
        for (int idx = tid; idx < 1024; idx += 256) {
            int j = idx >> 4;
            int lq = idx & 15;
            float4 hv = *(const float4*)&h[(size_t)(b * 256 + jb + j) * 128 + lh * 64 + lq * 4];
            *(float4*)&hs[j][lq * 4] = hv;
        }
        __syncthreads();
        for (int ll = 0; ll < 64; ++ll) {
            float4 uv = *(const float4*)&Ut[ll][m0];
#pragma unroll
            for (int jj = 0; jj < 8; jj++) {
                float hv = hs[j0 + jj][ll];
                acc[jj][0] += hv * uv.x; acc[jj][1] += hv * uv.y;
                acc[jj][2] += hv * uv.z; acc[jj][3] += hv * uv.w;
            }
        }
    }
    // epilogue: Y=acc+cvec, silu, @Wm2, reduce over m (lanes), +bm2
    float w2[4][4];
#pragma unroll
    for (int r4 = 0; r4 < 4; r4++)
#pragma unroll
        for (int r = 0; r < 4; r++) w2[r4][r] = Wm2[(m0 + r4) * 4 + r];
    float cv[4];
#pragma unroll
    for (int r4 = 0; r4 < 4; r4++) cv[r4] = cvec[m0 + r4];
    float p[8][4];
#pragma unroll
    for (int jj = 0; jj < 8; jj++) {
#pragma unroll
        for (int r = 0; r < 4; r++) p[jj][r] = 0.f;
#pragma unroll
        for (int r4 = 0; r4 < 4; r4++) {
            float y = acc[jj][r4] + cv[r4];
            float sv = y / (1.f + expf(-y));
#pragma unroll
            for (int r = 0; r < 4; r++) p[jj][r] += sv * w2[r4][r];
        }
    }
#pragma unroll
    for (int jj = 0; jj < 8; jj++)
#pragma unroll
        for (int r = 0; r < 4; r++) {
            float vsum = p[jj][r];
            for (int off = 16; off >= 1; off >>= 1) vsum += __shfl_xor(vsum, off, 32);
            p[jj][r] = vsum;
        }
    if (mcol == 0) {
#pragma unroll
        for (int jj = 0; jj < 8; jj++) {
            float4 o4;
            o4.x = p[jj][0] + bm2[0]; o4.y = p[jj][1] + bm2[1];
            o4.z = p[jj][2] + bm2[2]; o4.w = p[jj][3] + bm2[3];
            *(float4*)&out[((size_t)gi * 256 + jb + j0 + jj) * 4] = o4;
        }
    }
}

extern "C" void kernel_launch(void* const* d_in, const int* in_sizes, int n_in,
                              void* d_out, int out_size, void* d_ws, size_t ws_size,
                              hipStream_t stream)
{
    const float* x   = (const float*)d_in[0];
    const int*   ei  = (const int*)d_in[1];
    const void*  tptr= d_in[3];
    const float* tm  = (const float*)d_in[4];
    const float* Wn  = (const float*)d_in[5];
    const float* bn  = (const float*)d_in[6];
    const float* Wee = (const float*)d_in[7];
    const float* bee = (const float*)d_in[8];
    const float* Wt1 = (const float*)d_in[9];
    const float* bt1 = (const float*)d_in[10];
    const float* Wt2 = (const float*)d_in[11];
    const float* bt2 = (const float*)d_in[12];
    const float* Wa  = (const float*)d_in[13];
    const float* ba  = (const float*)d_in[14];
    const float* Wq  = (const float*)d_in[15];
    const float* bq  = (const float*)d_in[16];
    const float* Wk  = (const float*)d_in[17];
    const float* bk  = (const float*)d_in[18];
    const float* Wv  = (const float*)d_in[19];
    const float* bv  = (const float*)d_in[20];
    const float* We  = (const float*)d_in[21];
    const float* Wsk = (const float*)d_in[22];
    const float* bsk = (const float*)d_in[23];
    const float* Wf1 = (const float*)d_in[24];
    const float* bf1 = (const float*)d_in[25];
    const float* Wf2 = (const float*)d_in[26];
    const float* bf2 = (const float*)d_in[27];
    const float* Wb  = (const float*)d_in[28];
    const float* bb  = (const float*)d_in[29];
    const float* Wm1 = (const float*)d_in[30];
    const float* bm1 = (const float*)d_in[31];
    const float* Wm2 = (const float*)d_in[32];
    const float* bm2 = (const float*)d_in[33];
    float* out = (float*)d_out;
    float* ws = (float*)d_ws;

    float* h    = ws + OFF_H;
    float* qb   = ws + OFF_Q;
    float* kb   = ws + OFF_K;
    float* vb   = ws + OFF_V;
    float* skp  = ws + OFF_SKP;
    float* g    = ws + OFF_G;
    float* ss   = ws + OFF_SS;
    float* ea   = ws + OFF_EA;
    float* cvec = ws + OFF_CVEC;
    int* iws    = (int*)(ws + OFF_INT);
    int* deg    = iws;
    int* cursor = iws + 1024;
    int* rowptr = iws + 2048;
    int* eorder = iws + 3073;
    float* Mst  = ws + OFF_M;
    float* U    = ws + OFF_U;

    hipMemsetAsync(deg, 0, 2048 * sizeof(int), stream);
    k_setup<<<1, 512, 0, stream>>>(tptr, Wt1, bt1, Wt2, bt2, Wa, ba, bb, Wm1, bm1, ss, cvec);
    k_input<<<512, 256, 0, stream>>>(x, Wn, bn, h);
    k_edge<<<256, 256, 0, stream>>>(ei, tm, Wee, bee, ea);
    k_count<<<256, 256, 0, stream>>>(ei, deg);
    k_scan<<<1, 1024, 0, stream>>>(deg, rowptr);
    k_scatter<<<256, 256, 0, stream>>>(ei, rowptr, cursor, eorder);
    k_sort<<<4, 256, 0, stream>>>(rowptr, eorder);

    for (int l = 0; l < LAYERS; l++) {
        const float* ssl = ss + l * 512;
        k_qkvs<<<dim3(64, 4), 256, 0, stream>>>(h, ssl,
            Wq + l * 16384, Wk + l * 16384, Wv + l * 16384, Wsk + l * 16384,
            bq + l * 128, bk + l * 128, bv + l * 128, bsk + l * 128,
            qb, kb, vb, skp);
        k_attn<<<1024, 64, 0, stream>>>(qb, kb, vb, skp, h, ei, ea, We + l * 128, rowptr, eorder);
        k_gemm<128, 256, true, true, false><<<64, 256, 0, stream>>>(
            h, Wf1 + l * 32768, bf1 + l * 256, g, ssl + 256, ssl + 384);
        k_gemm<256, 128, false, false, true><<<64, 256, 0, stream>>>(
            g, Wf2 + l * 32768, bf2 + l * 128, h, nullptr, nullptr);
    }

    k_mprep<<<128, 256, 0, stream>>>(Wb, Wm1, Mst);

    size_t ws_floats = ws_size / 4;
    int CH = 1024;
    while (CH > 16 && (size_t)OFF_U + (size_t)CH * 16384 > ws_floats) CH >>= 1;
    for (int i0 = 0; i0 < 1024; i0 += CH) {
        k_phase1<<<dim3(64, CH / 16), 256, 0, stream>>>(h, Mst, U, i0);
        k_phase2<<<dim3(4, CH), 256, 0, stream>>>(U, h, cvec, Wm2, bm2, out, i0);
    }
}

// Round 2
// 804.041 us; speedup vs baseline: 1.8816x; 1.8816x over previous
//
#include <hip/hip_runtime.h>
#include <math.h>

#define N_NODES 1024
#define HDIM 128
#define EDGES 65536
#define LAYERS 6

// workspace float offsets
#define OFF_H     0
#define OFF_Q     131072
#define OFF_K     262144
#define OFF_V     393216
#define OFF_SKP   524288
#define OFF_G     655360
#define OFF_SS    917504
#define OFF_EA    920576
#define OFF_CVEC  986112
#define OFF_INT   986240
#define OFF_M     1054912
#define OFF_U     3152064

__device__ __forceinline__ float silu_f(float x) { return x / (1.f + expf(-x)); }

// ---------------- setup: timestep embedding -> t_mod -> ss[6][512], cvec ---------------
__global__ __launch_bounds__(512) void k_setup(const void* tptr,
    const float* __restrict__ Wt1, const float* __restrict__ bt1,
    const float* __restrict__ Wt2, const float* __restrict__ bt2,
    const float* __restrict__ Wa, const float* __restrict__ ba,
    const float* __restrict__ bb, const float* __restrict__ Wm1, const float* __restrict__ bm1,
    float* __restrict__ ss_all, float* __restrict__ cvec)
{
    __shared__ float emb_s[256];
    __shared__ float tmp1_s[128];
    __shared__ float tmod_s[128];
    int tid = threadIdx.x;
    int iv = *(const int*)tptr;
    float fv = __int_as_float(iv);
    float tval = (iv > -1000000 && iv < 1000000) ? (float)iv : fv;
    if (tid < 128) {
        float fr = expf(-logf(10000.f) * (float)tid / 128.f);
        float ta = tval * fr;
        emb_s[tid] = cosf(ta);
        emb_s[128 + tid] = sinf(ta);
    }
    __syncthreads();
    if (tid < 128) {
        float a = bt1[tid];
        for (int i = 0; i < 256; i++) a += emb_s[i] * Wt1[i * 128 + tid];
        tmp1_s[tid] = silu_f(a);
    }
    __syncthreads();
    if (tid < 128) {
        float a = bt2[tid];
        for (int i = 0; i < 128; i++) a += tmp1_s[i] * Wt2[i * 128 + tid];
        tmod_s[tid] = silu_f(a);
    }
    __syncthreads();
    for (int idx = tid; idx < LAYERS * 512; idx += 512) {
        int l = idx >> 9, j = idx & 511;
        float a = ba[l * 512 + j];
        const float* w = Wa + l * 65536 + j;
        for (int k = 0; k < 128; k++) a += tmod_s[k] * w[k * 512];
        ss_all[idx] = a;
    }
    if (tid < 128) {
        float a = bm1[tid];
        for (int o = 0; o < 128; o++) a += bb[o] * Wm1[o * 128 + tid];
        cvec[tid] = a;
    }
}

// ---------------- h = x @ Wn + bn  (K=5) ----------------
__global__ __launch_bounds__(256) void k_input(const float* __restrict__ x,
    const float* __restrict__ Wn, const float* __restrict__ bn, float* __restrict__ h)
{
    int idx = blockIdx.x * 256 + threadIdx.x;  // < 131072
    int i = idx >> 7, j = idx & 127;
    float acc = bn[j];
#pragma unroll
    for (int kk = 0; kk < 5; kk++) acc += x[i * 5 + kk] * Wn[kk * 128 + j];
    h[idx] = acc;
}

// ---------------- edge_attr ----------------
__global__ __launch_bounds__(256) void k_edge(const int* __restrict__ ei,
    const float* __restrict__ tm, const float* __restrict__ Wee, const float* __restrict__ bee,
    float* __restrict__ ea)
{
    int e = blockIdx.x * 256 + threadIdx.x;
    int s = ei[e], d = ei[EDGES + e];
    ea[e] = tm[s * N_NODES + d] * Wee[0] + bee[0];
}

// ---------------- CSR build ----------------
__global__ __launch_bounds__(256) void k_count(const int* __restrict__ ei, int* __restrict__ deg)
{
    int e = blockIdx.x * 256 + threadIdx.x;
    atomicAdd(&deg[ei[EDGES + e]], 1);
}

__global__ __launch_bounds__(1024) void k_scan(const int* __restrict__ deg, int* __restrict__ rowptr)
{
    __shared__ int tmp[1024];
    int tid = threadIdx.x;
    tmp[tid] = deg[tid];
    __syncthreads();
    for (int off = 1; off < 1024; off <<= 1) {
        int vv = (tid >= off) ? tmp[tid - off] : 0;
        __syncthreads();
        tmp[tid] += vv;
        __syncthreads();
    }
    rowptr[tid + 1] = tmp[tid];
    if (tid == 0) rowptr[0] = 0;
}

__global__ __launch_bounds__(256) void k_scatter(const int* __restrict__ ei,
    const int* __restrict__ rowptr, int* __restrict__ cursor, int* __restrict__ eorder)
{
    int e = blockIdx.x * 256 + threadIdx.x;
    int d = ei[EDGES + e];
    int pos = atomicAdd(&cursor[d], 1);
    eorder[rowptr[d] + pos] = e;
}

// ---------------- per-node bitonic sort of edge ids in LDS ----------------
__global__ __launch_bounds__(128) void k_sort2(const int* __restrict__ rowptr,
                                               int* __restrict__ eorder)
{
    __shared__ int key[256];
    int node = blockIdx.x;
    int tid = threadIdx.x;
    int beg = rowptr[node], end = rowptr[node + 1];
    int n = end - beg;
    if (n <= 256) {
        for (int i = tid; i < 256; i += 128) key[i] = (i < n) ? eorder[beg + i] : 0x7FFFFFFF;
        __syncthreads();
        for (int k = 2; k <= 256; k <<= 1) {
            for (int j = k >> 1; j > 0; j >>= 1) {
                int i = ((tid / j) * 2 * j) + (tid % j);
                int l = i + j;
                bool up = ((i & k) == 0);
                int a = key[i], b = key[l];
                if ((a > b) == up) { key[i] = b; key[l] = a; }
                __syncthreads();
            }
        }
        for (int i = tid; i < n; i += 128) eorder[beg + i] = key[i];
    } else if (tid == 0) {
        // safety fallback (never expected): serial insertion sort
        for (int i = beg + 1; i < end; ++i) {
            int kk = eorder[i];
            int j = i - 1;
            while (j >= beg && eorder[j] > kk) { eorder[j + 1] = eorder[j]; --j; }
            eorder[j + 1] = kk;
        }
    }
}

// ---------------- fused LN+mod + 4x GEMM (q,k,v,skip) ----------------
__global__ __launch_bounds__(256) void k_qkvs(const float* __restrict__ h,
    const float* __restrict__ ss,
    const float* __restrict__ Wq, const float* __restrict__ Wk,
    const float* __restrict__ Wv, const float* __restrict__ Wsk,
    const float* __restrict__ bq, const float* __restrict__ bk,
    const float* __restrict__ bv, const float* __restrict__ bsk,
    float* __restrict__ q, float* __restrict__ k, float* __restrict__ v, float* __restrict__ skp)
{
    __shared__ float a[16][128];
    __shared__ float mu_s[16], rs_s[16];
    int tid = threadIdx.x;
    int r0 = blockIdx.x * 16;
    for (int idx = tid; idx < 2048; idx += 256) a[idx >> 7][idx & 127] = h[r0 * 128 + idx];
    __syncthreads();
    if (tid < 16) {
        float s = 0.f, s2 = 0.f;
        for (int c = 0; c < 128; c++) { float xx = a[tid][c]; s += xx; s2 += xx * xx; }
        float mu = s * (1.f / 128.f);
        float var = s2 * (1.f / 128.f) - mu * mu;
        mu_s[tid] = mu; rs_s[tid] = rsqrtf(var + 1e-5f);
    }
    __syncthreads();
    const float* sh = ss; const float* sc = ss + 128;
    for (int idx = tid; idx < 2048; idx += 256) {
        int r = idx >> 7, c = idx & 127;
        a[r][c] = (a[r][c] - mu_s[r]) * rs_s[r] * (1.f + sc[c]) + sh[c];
    }
    __syncthreads();
    const float* W; const float* bias; float* out;
    switch (blockIdx.y) {
        case 0:  W = Wq;  bias = bq;  out = q;   break;
        case 1:  W = Wk;  bias = bk;  out = k;   break;
        case 2:  W = Wv;  bias = bv;  out = v;   break;
        default: W = Wsk; bias = bsk; out = skp; break;
    }
    int col = tid & 127, grp = tid >> 7;
    float acc[8] = {};
    for (int kk = 0; kk < 128; ++kk) {
        float bvv = W[kk * 128 + col];
#pragma unroll
        for (int rr = 0; rr < 8; rr++) acc[rr] += a[grp * 8 + rr][kk] * bvv;
    }
#pragma unroll
    for (int rr = 0; rr < 8; rr++)
        out[(r0 + grp * 8 + rr) * 128 + col] = acc[rr] + bias[col];
}

// ---------------- generic 16-row GEMM (optional LN front, gelu, add) ----------------
template <int K, int NCOL, bool LNF, bool GELU_ACT, bool ADD>
__global__ __launch_bounds__(256) void k_gemm(const float* __restrict__ A,
    const float* __restrict__ W, const float* __restrict__ bias, float* __restrict__ C,
    const float* __restrict__ sh, const float* __restrict__ sc)
{
    __shared__ float a[16][K];
    __shared__ float mu_s[16], rs_s[16];
    int tid = threadIdx.x;
    int r0 = blockIdx.x * 16;
    for (int idx = tid; idx < 16 * K; idx += 256) a[idx / K][idx % K] = A[r0 * K + idx];
    __syncthreads();
    if (LNF) {
        if (tid < 16) {
            float s = 0.f, s2 = 0.f;
            for (int c = 0; c < K; c++) { float xx = a[tid][c]; s += xx; s2 += xx * xx; }
            float mu = s * (1.f / K);
            float var = s2 * (1.f / K) - mu * mu;
            mu_s[tid] = mu; rs_s[tid] = rsqrtf(var + 1e-5f);
        }
        __syncthreads();
        for (int idx = tid; idx < 16 * K; idx += 256) {
            int r = idx / K, c = idx % K;
            a[r][c] = (a[r][c] - mu_s[r]) * rs_s[r] * (1.f + sc[c]) + sh[c];
        }
        __syncthreads();
    }
    constexpr int G = 256 / NCOL;
    constexpr int RPT = 16 / G;
    int col = tid % NCOL;
    int grp = tid / NCOL;
    float acc[RPT] = {};
    for (int kk = 0; kk < K; ++kk) {
        float bvv = W[kk * NCOL + col];
#pragma unroll
        for (int rr = 0; rr < RPT; rr++) acc[rr] += a[grp * RPT + rr][kk] * bvv;
    }
#pragma unroll
    for (int rr = 0; rr < RPT; rr++) {
        float y = acc[rr] + bias[col];
        if (GELU_ACT) y = 0.5f * y * (1.f + erff(y * 0.70710678118654752f));
        int r = r0 + grp * RPT + rr;
        if (ADD) C[r * NCOL + col] += y; else C[r * NCOL + col] = y;
    }
}

// ---------------- attention: one wave per dst node, online softmax over CSR edges -------
__global__ __launch_bounds__(64) void k_attn(const float* __restrict__ q,
    const float* __restrict__ k, const float* __restrict__ v,
    const float* __restrict__ skp, float* __restrict__ h,
    const int* __restrict__ ei, const float* __restrict__ ea,
    const float* __restrict__ We_l,
    const int* __restrict__ rowptr, const int* __restrict__ eorder)
{
    int node = blockIdx.x;
    int lane = threadIdx.x;
    int c0 = lane * 2;
    float q0 = q[node * 128 + c0], q1 = q[node * 128 + c0 + 1];
    float we0 = We_l[c0], we1 = We_l[c0 + 1];
    int beg = rowptr[node], end = rowptr[node + 1];
    float m = -INFINITY, s = 0.f, a0 = 0.f, a1 = 0.f;
    const float isc = 0.17677669529663687f;  // 1/sqrt(32)

    int t = beg;
    for (; t + 1 < end; t += 2) {
        // issue both edges' (independent) load chains before consuming
        int eA = eorder[t], eB = eorder[t + 1];
        int snA = ei[eA], snB = ei[eB];
        float eavA = ea[eA], eavB = ea[eB];
        float kA0 = k[snA * 128 + c0],     kB0 = k[snB * 128 + c0];
        float kA1 = k[snA * 128 + c0 + 1], kB1 = k[snB * 128 + c0 + 1];
        float vA0 = v[snA * 128 + c0],     vB0 = v[snB * 128 + c0];
        float vA1 = v[snA * 128 + c0 + 1], vB1 = v[snB * 128 + c0 + 1];
        kA0 += eavA * we0; kA1 += eavA * we1;
        kB0 += eavB * we0; kB1 += eavB * we1;
        float pA = q0 * kA0 + q1 * kA1;
        float pB = q0 * kB0 + q1 * kB1;
        pA += __shfl_xor(pA, 1, 16); pB += __shfl_xor(pB, 1, 16);
        pA += __shfl_xor(pA, 2, 16); pB += __shfl_xor(pB, 2, 16);
        pA += __shfl_xor(pA, 4, 16); pB += __shfl_xor(pB, 4, 16);
        pA += __shfl_xor(pA, 8, 16); pB += __shfl_xor(pB, 8, 16);
        float alA = pA * isc, alB = pB * isc;
        // update A
        {
            float mn = fmaxf(m, alA);
            float scale = expf(m - mn);
            float w = expf(alA - mn);
            s = s * scale + w;
            a0 = a0 * scale + w * (vA0 + eavA * we0);
            a1 = a1 * scale + w * (vA1 + eavA * we1);
            m = mn;
        }
        // update B
        {
            float mn = fmaxf(m, alB);
            float scale = expf(m - mn);
            float w = expf(alB - mn);
            s = s * scale + w;
            a0 = a0 * scale + w * (vB0 + eavB * we0);
            a1 = a1 * scale + w * (vB1 + eavB * we1);
            m = mn;
        }
    }
    for (; t < end; ++t) {
        int e = eorder[t];
        int sn = ei[e];
        float eav = ea[e];
        float k0 = k[sn * 128 + c0] + eav * we0;
        float k1 = k[sn * 128 + c0 + 1] + eav * we1;
        float part = q0 * k0 + q1 * k1;
        part += __shfl_xor(part, 1, 16);
        part += __shfl_xor(part, 2, 16);
        part += __shfl_xor(part, 4, 16);
        part += __shfl_xor(part, 8, 16);
        float alpha = part * isc;
        float mn = fmaxf(m, alpha);
        float scale = expf(m - mn);
        float w = expf(alpha - mn);
        s = s * scale + w;
        float v0 = v[sn * 128 + c0] + eav * we0;
        float v1 = v[sn * 128 + c0 + 1] + eav * we1;
        a0 = a0 * scale + w * v0;
        a1 = a1 * scale + w * v1;
        m = mn;
    }
    float inv = 1.f / (s + 1e-16f);
    int o = node * 128 + c0;
    h[o]     += skp[o]     + a0 * inv;
    h[o + 1] += skp[o + 1] + a1 * inv;
}

// ---------------- M[k][l][m] = sum_o Wb[o,k,l] * Wm1[o,m] ----------------
__global__ __launch_bounds__(256) void k_mprep(const float* __restrict__ Wb,
    const float* __restrict__ Wm1, float* __restrict__ M)
{
    __shared__ float wb_s[64][128];
    __shared__ float wm_s[64][128];
    int tid = threadIdx.x;
    int k = blockIdx.x;
    int mg = tid & 15, lg = tid >> 4;
    int m0 = mg * 8, l0 = lg * 8;
    float acc[8][8] = {};
    for (int oh = 0; oh < 2; ++oh) {
        __syncthreads();
        for (int idx = tid; idx < 8192; idx += 256) {
            int o = idx >> 7, c = idx & 127;
            wb_s[o][c] = Wb[(size_t)(oh * 64 + o) * 16384 + k * 128 + c];
            wm_s[o][c] = Wm1[(oh * 64 + o) * 128 + c];
        }
        __syncthreads();
        for (int o = 0; o < 64; o++) {
            float lv[8], mv[8];
#pragma unroll
            for (int i = 0; i < 8; i++) { lv[i] = wb_s[o][l0 + i]; mv[i] = wm_s[o][m0 + i]; }
#pragma unroll
            for (int li = 0; li < 8; li++)
#pragma unroll
                for (int mi = 0; mi < 8; mi++) acc[li][mi] += lv[li] * mv[mi];
        }
    }
    for (int li = 0; li < 8; li++)
        for (int mi = 0; mi < 8; mi++)
            M[(size_t)k * 16384 + (l0 + li) * 128 + (m0 + mi)] = acc[li][mi];
}

// ---------------- U[i][l][m] = sum_k h[i,k] * M[k][l][m] ----------------
__global__ __launch_bounds__(256) void k_phase1(const float* __restrict__ h,
    const float* __restrict__ M, float* __restrict__ U, int i0)
{
    __shared__ float a[16][128];
    int tid = threadIdx.x;
    int ib = i0 + blockIdx.y * 16;
    for (int idx = tid; idx < 2048; idx += 256) a[idx >> 7][idx & 127] = h[ib * 128 + idx];
    __syncthreads();
    int col = blockIdx.x * 256 + tid;
    float acc[16] = {};
    for (int kk = 0; kk < 128; kk++) {
        float bv = M[(size_t)kk * 16384 + col];
#pragma unroll
        for (int r = 0; r < 16; r++) acc[r] += a[r][kk] * bv;
    }
#pragma unroll
    for (int r = 0; r < 16; r++) U[(size_t)(blockIdx.y * 16 + r) * 16384 + col] = acc[r];
}

// ---------------- Y[j,m] = sum_l U[i][l][m]*h[j,l] + cvec; out = silu(Y)@Wm2+bm2 --------
__global__ __launch_bounds__(256) void k_phase2(const float* __restrict__ U,
    const float* __restrict__ h, const float* __restrict__ cvec,
    const float* __restrict__ Wm2, const float* __restrict__ bm2,
    float* __restrict__ out, int i0)
{
    __shared__ float Ut[64][132];   // [l-half][m] padded
    __shared__ float hs[64][68];    // [j][l-half] padded
    int tid = threadIdx.x;
    int ci = blockIdx.y;
    int gi = i0 + ci;
    int b = gi >> 8;
    int jb = blockIdx.x * 64;
    int mcol = tid & 31, jgrp = tid >> 5;
    int m0 = mcol * 4, j0 = jgrp * 8;
    float acc[8][4] = {};
    const float4* Usrc = (const float4*)(U + (size_t)ci * 16384);
    for (int lh = 0; lh < 2; ++lh) {
        __syncthreads();
        for (int idx = tid; idx < 2048; idx += 256) {
            int lr = idx >> 5;
            int mq = idx & 31;
            float4 uv = Usrc[(size_t)(lh * 64 + lr) * 32 + mq];
            *(float4*)&Ut[lr][mq * 4] = uv;
        }
        for (int idx = tid; idx < 1024; idx += 256) {
            int j = idx >> 4;
            int lq = idx & 15;
            float4 hv = *(const float4*)&h[(size_t)(b * 256 + jb + j) * 128 + lh * 64 + lq * 4];
            *(float4*)&hs[j][lq * 4] = hv;
        }
        __syncthreads();
        for (int ll = 0; ll < 64; ++ll) {
            float4 uv = *(const float4*)&Ut[ll][m0];
#pragma unroll
            for (int jj = 0; jj < 8; jj++) {
                float hv = hs[j0 + jj][ll];
                acc[jj][0] += hv * uv.x; acc[jj][1] += hv * uv.y;
                acc[jj][2] += hv * uv.z; acc[jj][3] += hv * uv.w;
            }
        }
    }
    // epilogue: Y=acc+cvec, silu, @Wm2, reduce over m (lanes), +bm2
    float w2[4][4];
#pragma unroll
    for (int r4 = 0; r4 < 4; r4++)
#pragma unroll
        for (int r = 0; r < 4; r++) w2[r4][r] = Wm2[(m0 + r4) * 4 + r];
    float cv[4];
#pragma unroll
    for (int r4 = 0; r4 < 4; r4++) cv[r4] = cvec[m0 + r4];
    float p[8][4];
#pragma unroll
    for (int jj = 0; jj < 8; jj++) {
#pragma unroll
        for (int r = 0; r < 4; r++) p[jj][r] = 0.f;
#pragma unroll
        for (int r4 = 0; r4 < 4; r4++) {
            float y = acc[jj][r4] + cv[r4];
            float sv = y / (1.f + expf(-y));
#pragma unroll
            for (int r = 0; r < 4; r++) p[jj][r] += sv * w2[r4][r];
        }
    }
#pragma unroll
    for (int jj = 0; jj < 8; jj++)
#pragma unroll
        for (int r = 0; r < 4; r++) {
            float vsum = p[jj][r];
            for (int off = 16; off >= 1; off >>= 1) vsum += __shfl_xor(vsum, off, 32);
            p[jj][r] = vsum;
        }
    if (mcol == 0) {
#pragma unroll
        for (int jj = 0; jj < 8; jj++) {
            float4 o4;
            o4.x = p[jj][0] + bm2[0]; o4.y = p[jj][1] + bm2[1];
            o4.z = p[jj][2] + bm2[2]; o4.w = p[jj][3] + bm2[3];
            *(float4*)&out[((size_t)gi * 256 + jb + j0 + jj) * 4] = o4;
        }
    }
}

extern "C" void kernel_launch(void* const* d_in, const int* in_sizes, int n_in,
                              void* d_out, int out_size, void* d_ws, size_t ws_size,
                              hipStream_t stream)
{
    const float* x   = (const float*)d_in[0];
    const int*   ei  = (const int*)d_in[1];
    const void*  tptr= d_in[3];
    const float* tm  = (const float*)d_in[4];
    const float* Wn  = (const float*)d_in[5];
    const float* bn  = (const float*)d_in[6];
    const float* Wee = (const float*)d_in[7];
    const float* bee = (const float*)d_in[8];
    const float* Wt1 = (const float*)d_in[9];
    const float* bt1 = (const float*)d_in[10];
    const float* Wt2 = (const float*)d_in[11];
    const float* bt2 = (const float*)d_in[12];
    const float* Wa  = (const float*)d_in[13];
    const float* ba  = (const float*)d_in[14];
    const float* Wq  = (const float*)d_in[15];
    const float* bq  = (const float*)d_in[16];
    const float* Wk  = (const float*)d_in[17];
    const float* bk  = (const float*)d_in[18];
    const float* Wv  = (const float*)d_in[19];
    const float* bv  = (const float*)d_in[20];
    const float* We  = (const float*)d_in[21];
    const float* Wsk = (const float*)d_in[22];
    const float* bsk = (const float*)d_in[23];
    const float* Wf1 = (const float*)d_in[24];
    const float* bf1 = (const float*)d_in[25];
    const float* Wf2 = (const float*)d_in[26];
    const float* bf2 = (const float*)d_in[27];
    const float* Wb  = (const float*)d_in[28];
    const float* bb  = (const float*)d_in[29];
    const float* Wm1 = (const float*)d_in[30];
    const float* bm1 = (const float*)d_in[31];
    const float* Wm2 = (const float*)d_in[32];
    const float* bm2 = (const float*)d_in[33];
    float* out = (float*)d_out;
    float* ws = (float*)d_ws;

    float* h    = ws + OFF_H;
    float* qb   = ws + OFF_Q;
    float* kb   = ws + OFF_K;
    float* vb   = ws + OFF_V;
    float* skp  = ws + OFF_SKP;
    float* g    = ws + OFF_G;
    float* ss   = ws + OFF_SS;
    float* ea   = ws + OFF_EA;
    float* cvec = ws + OFF_CVEC;
    int* iws    = (int*)(ws + OFF_INT);
    int* deg    = iws;
    int* cursor = iws + 1024;
    int* rowptr = iws + 2048;
    int* eorder = iws + 3073;
    float* Mst  = ws + OFF_M;
    float* U    = ws + OFF_U;

    hipMemsetAsync(deg, 0, 2048 * sizeof(int), stream);
    k_setup<<<1, 512, 0, stream>>>(tptr, Wt1, bt1, Wt2, bt2, Wa, ba, bb, Wm1, bm1, ss, cvec);
    k_input<<<512, 256, 0, stream>>>(x, Wn, bn, h);
    k_edge<<<256, 256, 0, stream>>>(ei, tm, Wee, bee, ea);
    k_count<<<256, 256, 0, stream>>>(ei, deg);
    k_scan<<<1, 1024, 0, stream>>>(deg, rowptr);
    k_scatter<<<256, 256, 0, stream>>>(ei, rowptr, cursor, eorder);
    k_sort2<<<1024, 128, 0, stream>>>(rowptr, eorder);

    for (int l = 0; l < LAYERS; l++) {
        const float* ssl = ss + l * 512;
        k_qkvs<<<dim3(64, 4), 256, 0, stream>>>(h, ssl,
            Wq + l * 16384, Wk + l * 16384, Wv + l * 16384, Wsk + l * 16384,
            bq + l * 128, bk + l * 128, bv + l * 128, bsk + l * 128,
            qb, kb, vb, skp);
        k_attn<<<1024, 64, 0, stream>>>(qb, kb, vb, skp, h, ei, ea, We + l * 128, rowptr, eorder);
        k_gemm<128, 256, true, true, false><<<64, 256, 0, stream>>>(
            h, Wf1 + l * 32768, bf1 + l * 256, g, ssl + 256, ssl + 384);
        k_gemm<256, 128, false, false, true><<<64, 256, 0, stream>>>(
            g, Wf2 + l * 32768, bf2 + l * 128, h, nullptr, nullptr);
    }

    k_mprep<<<128, 256, 0, stream>>>(Wb, Wm1, Mst);

    size_t ws_floats = ws_size / 4;
    int CH = 1024;
    while (CH > 16 && (size_t)OFF_U + (size_t)CH * 16384 > ws_floats) CH >>= 1;
    for (int i0 = 0; i0 < 1024; i0 += CH) {
        k_phase1<<<dim3(64, CH / 16), 256, 0, stream>>>(h, Mst, U, i0);
        k_phase2<<<dim3(4, CH), 256, 0, stream>>>(U, h, cvec, Wm2, bm2, out, i0);
    }
}

// Round 3
// 642.839 us; speedup vs baseline: 2.3534x; 1.2508x over previous
//
#include <hip/hip_runtime.h>
#include <math.h>

#define N_NODES 1024
#define HDIM 128
#define EDGES 65536
#define LAYERS 6

typedef __attribute__((ext_vector_type(8))) short bf16x8;
typedef __attribute__((ext_vector_type(4))) float f32x4;

// workspace float offsets
#define OFF_H     0
#define OFF_Q     131072
#define OFF_K     262144
#define OFF_V     393216
#define OFF_SKP   524288
#define OFF_G     655360
#define OFF_SS    917504
#define OFF_EA    920576
#define OFF_CVEC  986112
#define OFF_INT   986240
#define OFF_M     1054912      // fp32 M [128 k][16384 n], n = m*128 + l  (m-outer!)
#define OFF_U     3152064      // bf16 U [1024 i][16384 n]   (8,388,608 floats)
#define OFF_MT    11540672     // bf16 Mt [16384 n][128 k]   (1,048,576 floats)
#define OFF_HB    12589248     // bf16 hb [1024][128]        (65,536 floats)

__device__ __forceinline__ float silu_f(float x) { return x / (1.f + expf(-x)); }

__device__ __forceinline__ unsigned short f2bf(float f) {
    unsigned int u = __float_as_uint(f);
    u += 0x7FFFu + ((u >> 16) & 1u);
    return (unsigned short)(u >> 16);
}

// ---------------- setup: timestep embedding -> t_mod -> ss[6][512], cvec ---------------
__global__ __launch_bounds__(512) void k_setup(const void* tptr,
    const float* __restrict__ Wt1, const float* __restrict__ bt1,
    const float* __restrict__ Wt2, const float* __restrict__ bt2,
    const float* __restrict__ Wa, const float* __restrict__ ba,
    const float* __restrict__ bb, const float* __restrict__ Wm1, const float* __restrict__ bm1,
    float* __restrict__ ss_all, float* __restrict__ cvec)
{
    __shared__ float emb_s[256];
    __shared__ float tmp1_s[128];
    __shared__ float tmod_s[128];
    int tid = threadIdx.x;
    int iv = *(const int*)tptr;
    float fv = __int_as_float(iv);
    float tval = (iv > -1000000 && iv < 1000000) ? (float)iv : fv;
    if (tid < 128) {
        float fr = expf(-logf(10000.f) * (float)tid / 128.f);
        float ta = tval * fr;
        emb_s[tid] = cosf(ta);
        emb_s[128 + tid] = sinf(ta);
    }
    __syncthreads();
    if (tid < 128) {
        float a = bt1[tid];
        for (int i = 0; i < 256; i++) a += emb_s[i] * Wt1[i * 128 + tid];
        tmp1_s[tid] = silu_f(a);
    }
    __syncthreads();
    if (tid < 128) {
        float a = bt2[tid];
        for (int i = 0; i < 128; i++) a += tmp1_s[i] * Wt2[i * 128 + tid];
        tmod_s[tid] = silu_f(a);
    }
    __syncthreads();
    for (int idx = tid; idx < LAYERS * 512; idx += 512) {
        int l = idx >> 9, j = idx & 511;
        float a = ba[l * 512 + j];
        const float* w = Wa + l * 65536 + j;
        for (int k = 0; k < 128; k++) a += tmod_s[k] * w[k * 512];
        ss_all[idx] = a;
    }
    if (tid < 128) {
        float a = bm1[tid];
        for (int o = 0; o < 128; o++) a += bb[o] * Wm1[o * 128 + tid];
        cvec[tid] = a;
    }
}

// ---------------- h = x @ Wn + bn  (K=5) ----------------
__global__ __launch_bounds__(256) void k_input(const float* __restrict__ x,
    const float* __restrict__ Wn, const float* __restrict__ bn, float* __restrict__ h)
{
    int idx = blockIdx.x * 256 + threadIdx.x;  // < 131072
    int i = idx >> 7, j = idx & 127;
    float acc = bn[j];
#pragma unroll
    for (int kk = 0; kk < 5; kk++) acc += x[i * 5 + kk] * Wn[kk * 128 + j];
    h[idx] = acc;
}

// ---------------- edge_attr ----------------
__global__ __launch_bounds__(256) void k_edge(const int* __restrict__ ei,
    const float* __restrict__ tm, const float* __restrict__ Wee, const float* __restrict__ bee,
    float* __restrict__ ea)
{
    int e = blockIdx.x * 256 + threadIdx.x;
    int s = ei[e], d = ei[EDGES + e];
    ea[e] = tm[s * N_NODES + d] * Wee[0] + bee[0];
}

// ---------------- CSR build ----------------
__global__ __launch_bounds__(256) void k_count(const int* __restrict__ ei, int* __restrict__ deg)
{
    int e = blockIdx.x * 256 + threadIdx.x;
    atomicAdd(&deg[ei[EDGES + e]], 1);
}

__global__ __launch_bounds__(1024) void k_scan(const int* __restrict__ deg, int* __restrict__ rowptr)
{
    __shared__ int tmp[1024];
    int tid = threadIdx.x;
    tmp[tid] = deg[tid];
    __syncthreads();
    for (int off = 1; off < 1024; off <<= 1) {
        int vv = (tid >= off) ? tmp[tid - off] : 0;
        __syncthreads();
        tmp[tid] += vv;
        __syncthreads();
    }
    rowptr[tid + 1] = tmp[tid];
    if (tid == 0) rowptr[0] = 0;
}

__global__ __launch_bounds__(256) void k_scatter(const int* __restrict__ ei,
    const int* __restrict__ rowptr, int* __restrict__ cursor, int* __restrict__ eorder)
{
    int e = blockIdx.x * 256 + threadIdx.x;
    int d = ei[EDGES + e];
    int pos = atomicAdd(&cursor[d], 1);
    eorder[rowptr[d] + pos] = e;
}

// ---------------- per-node bitonic sort of edge ids in LDS ----------------
__global__ __launch_bounds__(128) void k_sort2(const int* __restrict__ rowptr,
                                               int* __restrict__ eorder)
{
    __shared__ int key[256];
    int node = blockIdx.x;
    int tid = threadIdx.x;
    int beg = rowptr[node], end = rowptr[node + 1];
    int n = end - beg;
    if (n <= 256) {
        for (int i = tid; i < 256; i += 128) key[i] = (i < n) ? eorder[beg + i] : 0x7FFFFFFF;
        __syncthreads();
        for (int k = 2; k <= 256; k <<= 1) {
            for (int j = k >> 1; j > 0; j >>= 1) {
                int i = ((tid / j) * 2 * j) + (tid % j);
                int l = i + j;
                bool up = ((i & k) == 0);
                int a = key[i], b = key[l];
                if ((a > b) == up) { key[i] = b; key[l] = a; }
                __syncthreads();
            }
        }
        for (int i = tid; i < n; i += 128) eorder[beg + i] = key[i];
    } else if (tid == 0) {
        for (int i = beg + 1; i < end; ++i) {
            int kk = eorder[i];
            int j = i - 1;
            while (j >= beg && eorder[j] > kk) { eorder[j + 1] = eorder[j]; --j; }
            eorder[j + 1] = kk;
        }
    }
}

// ---------------- fused LN+mod + 4x GEMM (q,k,v,skip) ----------------
__global__ __launch_bounds__(256) void k_qkvs(const float* __restrict__ h,
    const float* __restrict__ ss,
    const float* __restrict__ Wq, const float* __restrict__ Wk,
    const float* __restrict__ Wv, const float* __restrict__ Wsk,
    const float* __restrict__ bq, const float* __restrict__ bk,
    const float* __restrict__ bv, const float* __restrict__ bsk,
    float* __restrict__ q, float* __restrict__ k, float* __restrict__ v, float* __restrict__ skp)
{
    __shared__ float a[16][128];
    __shared__ float mu_s[16], rs_s[16];
    int tid = threadIdx.x;
    int r0 = blockIdx.x * 16;
    for (int idx = tid; idx < 2048; idx += 256) a[idx >> 7][idx & 127] = h[r0 * 128 + idx];
    __syncthreads();
    if (tid < 16) {
        float s = 0.f, s2 = 0.f;
        for (int c = 0; c < 128; c++) { float xx = a[tid][c]; s += xx; s2 += xx * xx; }
        float mu = s * (1.f / 128.f);
        float var = s2 * (1.f / 128.f) - mu * mu;
        mu_s[tid] = mu; rs_s[tid] = rsqrtf(var + 1e-5f);
    }
    __syncthreads();
    const float* sh = ss; const float* sc = ss + 128;
    for (int idx = tid; idx < 2048; idx += 256) {
        int r = idx >> 7, c = idx & 127;
        a[r][c] = (a[r][c] - mu_s[r]) * rs_s[r] * (1.f + sc[c]) + sh[c];
    }
    __syncthreads();
    const float* W; const float* bias; float* out;
    switch (blockIdx.y) {
        case 0:  W = Wq;  bias = bq;  out = q;   break;
        case 1:  W = Wk;  bias = bk;  out = k;   break;
        case 2:  W = Wv;  bias = bv;  out = v;   break;
        default: W = Wsk; bias = bsk; out = skp; break;
    }
    int col = tid & 127, grp = tid >> 7;
    float acc[8] = {};
    for (int kk = 0; kk < 128; ++kk) {
        float bvv = W[kk * 128 + col];
#pragma unroll
        for (int rr = 0; rr < 8; rr++) acc[rr] += a[grp * 8 + rr][kk] * bvv;
    }
#pragma unroll
    for (int rr = 0; rr < 8; rr++)
        out[(r0 + grp * 8 + rr) * 128 + col] = acc[rr] + bias[col];
}

// ---------------- generic 16-row GEMM (optional LN front, gelu, add) ----------------
template <int K, int NCOL, bool LNF, bool GELU_ACT, bool ADD>
__global__ __launch_bounds__(256) void k_gemm(const float* __restrict__ A,
    const float* __restrict__ W, const float* __restrict__ bias, float* __restrict__ C,
    const float* __restrict__ sh, const float* __restrict__ sc)
{
    __shared__ float a[16][K];
    __shared__ float mu_s[16], rs_s[16];
    int tid = threadIdx.x;
    int r0 = blockIdx.x * 16;
    for (int idx = tid; idx < 16 * K; idx += 256) a[idx / K][idx % K] = A[r0 * K + idx];
    __syncthreads();
    if (LNF) {
        if (tid < 16) {
            float s = 0.f, s2 = 0.f;
            for (int c = 0; c < K; c++) { float xx = a[tid][c]; s += xx; s2 += xx * xx; }
            float mu = s * (1.f / K);
            float var = s2 * (1.f / K) - mu * mu;
            mu_s[tid] = mu; rs_s[tid] = rsqrtf(var + 1e-5f);
        }
        __syncthreads();
        for (int idx = tid; idx < 16 * K; idx += 256) {
            int r = idx / K, c = idx % K;
            a[r][c] = (a[r][c] - mu_s[r]) * rs_s[r] * (1.f + sc[c]) + sh[c];
        }
        __syncthreads();
    }
    constexpr int G = 256 / NCOL;
    constexpr int RPT = 16 / G;
    int col = tid % NCOL;
    int grp = tid / NCOL;
    float acc[RPT] = {};
    for (int kk = 0; kk < K; ++kk) {
        float bvv = W[kk * NCOL + col];
#pragma unroll
        for (int rr = 0; rr < RPT; rr++) acc[rr] += a[grp * RPT + rr][kk] * bvv;
    }
#pragma unroll
    for (int rr = 0; rr < RPT; rr++) {
        float y = acc[rr] + bias[col];
        if (GELU_ACT) y = 0.5f * y * (1.f + erff(y * 0.70710678118654752f));
        int r = r0 + grp * RPT + rr;
        if (ADD) C[r * NCOL + col] += y; else C[r * NCOL + col] = y;
    }
}

// ---------------- attention: one wave per dst node, online softmax over CSR edges -------
__global__ __launch_bounds__(64) void k_attn(const float* __restrict__ q,
    const float* __restrict__ k, const float* __restrict__ v,
    const float* __restrict__ skp, float* __restrict__ h,
    const int* __restrict__ ei, const float* __restrict__ ea,
    const float* __restrict__ We_l,
    const int* __restrict__ rowptr, const int* __restrict__ eorder)
{
    int node = blockIdx.x;
    int lane = threadIdx.x;
    int c0 = lane * 2;
    float q0 = q[node * 128 + c0], q1 = q[node * 128 + c0 + 1];
    float we0 = We_l[c0], we1 = We_l[c0 + 1];
    int beg = rowptr[node], end = rowptr[node + 1];
    float m = -INFINITY, s = 0.f, a0 = 0.f, a1 = 0.f;
    const float isc = 0.17677669529663687f;  // 1/sqrt(32)

    int t = beg;
    for (; t + 1 < end; t += 2) {
        int eA = eorder[t], eB = eorder[t + 1];
        int snA = ei[eA], snB = ei[eB];
        float eavA = ea[eA], eavB = ea[eB];
        float kA0 = k[snA * 128 + c0],     kB0 = k[snB * 128 + c0];
        float kA1 = k[snA * 128 + c0 + 1], kB1 = k[snB * 128 + c0 + 1];
        float vA0 = v[snA * 128 + c0],     vB0 = v[snB * 128 + c0];
        float vA1 = v[snA * 128 + c0 + 1], vB1 = v[snB * 128 + c0 + 1];
        kA0 += eavA * we0; kA1 += eavA * we1;
        kB0 += eavB * we0; kB1 += eavB * we1;
        float pA = q0 * kA0 + q1 * kA1;
        float pB = q0 * kB0 + q1 * kB1;
        pA += __shfl_xor(pA, 1, 16); pB += __shfl_xor(pB, 1, 16);
        pA += __shfl_xor(pA, 2, 16); pB += __shfl_xor(pB, 2, 16);
        pA += __shfl_xor(pA, 4, 16); pB += __shfl_xor(pB, 4, 16);
        pA += __shfl_xor(pA, 8, 16); pB += __shfl_xor(pB, 8, 16);
        float alA = pA * isc, alB = pB * isc;
        {
            float mn = fmaxf(m, alA);
            float scale = expf(m - mn);
            float w = expf(alA - mn);
            s = s * scale + w;
            a0 = a0 * scale + w * (vA0 + eavA * we0);
            a1 = a1 * scale + w * (vA1 + eavA * we1);
            m = mn;
        }
        {
            float mn = fmaxf(m, alB);
            float scale = expf(m - mn);
            float w = expf(alB - mn);
            s = s * scale + w;
            a0 = a0 * scale + w * (vB0 + eavB * we0);
            a1 = a1 * scale + w * (vB1 + eavB * we1);
            m = mn;
        }
    }
    for (; t < end; ++t) {
        int e = eorder[t];
        int sn = ei[e];
        float eav = ea[e];
        float k0 = k[sn * 128 + c0] + eav * we0;
        float k1 = k[sn * 128 + c0 + 1] + eav * we1;
        float part = q0 * k0 + q1 * k1;
        part += __shfl_xor(part, 1, 16);
        part += __shfl_xor(part, 2, 16);
        part += __shfl_xor(part, 4, 16);
        part += __shfl_xor(part, 8, 16);
        float alpha = part * isc;
        float mn = fmaxf(m, alpha);
        float scale = expf(m - mn);
        float w = expf(alpha - mn);
        s = s * scale + w;
        float v0 = v[sn * 128 + c0] + eav * we0;
        float v1 = v[sn * 128 + c0 + 1] + eav * we1;
        a0 = a0 * scale + w * v0;
        a1 = a1 * scale + w * v1;
        m = mn;
    }
    float inv = 1.f / (s + 1e-16f);
    int o = node * 128 + c0;
    h[o]     += skp[o]     + a0 * inv;
    h[o + 1] += skp[o + 1] + a1 * inv;
}

// ---------------- M[k][m*128+l] = sum_o Wb[o,k,l] * Wm1[o,m]  (m-outer layout!) --------
__global__ __launch_bounds__(256) void k_mprep(const float* __restrict__ Wb,
    const float* __restrict__ Wm1, float* __restrict__ M)
{
    __shared__ float wb_s[64][128];
    __shared__ float wm_s[64][128];
    int tid = threadIdx.x;
    int k = blockIdx.x;
    int mg = tid & 15, lg = tid >> 4;
    int m0 = mg * 8, l0 = lg * 8;
    float acc[8][8] = {};
    for (int oh = 0; oh < 2; ++oh) {
        __syncthreads();
        for (int idx = tid; idx < 8192; idx += 256) {
            int o = idx >> 7, c = idx & 127;
            wb_s[o][c] = Wb[(size_t)(oh * 64 + o) * 16384 + k * 128 + c];
            wm_s[o][c] = Wm1[(oh * 64 + o) * 128 + c];
        }
        __syncthreads();
        for (int o = 0; o < 64; o++) {
            float lv[8], mv[8];
#pragma unroll
            for (int i = 0; i < 8; i++) { lv[i] = wb_s[o][l0 + i]; mv[i] = wm_s[o][m0 + i]; }
#pragma unroll
            for (int li = 0; li < 8; li++)
#pragma unroll
                for (int mi = 0; mi < 8; mi++) acc[li][mi] += lv[li] * mv[mi];
        }
    }
    for (int mi = 0; mi < 8; mi++)
        for (int li = 0; li < 8; li++)
            M[(size_t)k * 16384 + (m0 + mi) * 128 + (l0 + li)] = acc[li][mi];
}

// ---------------- Mt[n][k] (bf16) <- M[k][n] (fp32) ----------------
__global__ __launch_bounds__(256) void k_mtrans(const float* __restrict__ M,
                                                short* __restrict__ Mt)
{
    __shared__ __align__(16) short Ts[64][136];
    int tid = threadIdx.x;
    int n0 = blockIdx.x * 64;
    for (int p = 0; p < 32; p++) {
        int idx = p * 256 + tid;
        int k = idx >> 6, nn = idx & 63;
        Ts[nn][k] = (short)f2bf(M[(size_t)k * 16384 + n0 + nn]);
    }
    __syncthreads();
    for (int p = 0; p < 4; p++) {
        int idx = p * 256 + tid;
        int nn = idx >> 4, s = idx & 15;
        *(int4*)&Mt[(size_t)(n0 + nn) * 128 + s * 8] = *(const int4*)&Ts[nn][s * 8];
    }
}

// ---------------- hb (bf16) <- h (fp32) ----------------
__global__ __launch_bounds__(256) void k_convh(const float* __restrict__ h,
                                               short* __restrict__ hb)
{
    int idx = (blockIdx.x * 256 + threadIdx.x) * 4;
    float4 v = *(const float4*)&h[idx];
    short4 o;
    o.x = (short)f2bf(v.x); o.y = (short)f2bf(v.y);
    o.z = (short)f2bf(v.z); o.w = (short)f2bf(v.w);
    *(short4*)&hb[idx] = o;
}

// ---------------- phase1 MFMA: U[i][n] = sum_k hb[i,k] * Mt[n,k] ----------------
__global__ __launch_bounds__(256) void k_p1(const short* __restrict__ hb,
    const short* __restrict__ Mt, short* __restrict__ U)
{
    __shared__ __align__(16) short As[128][72];
    __shared__ __align__(16) short Bs[128][72];
    int tid = threadIdx.x;
    int n0 = blockIdx.x * 128;
    int i0 = blockIdx.y * 128;
    int w = tid >> 6, lane = tid & 63, c = lane & 15, g = lane >> 4;
    f32x4 acc[2][8] = {};
    for (int kh = 0; kh < 2; kh++) {
        __syncthreads();
        for (int idx = tid; idx < 1024; idx += 256) {
            int r = idx >> 3, s = idx & 7;
            *(int4*)&As[r][s * 8] = *(const int4*)&hb[(i0 + r) * 128 + kh * 64 + s * 8];
            *(int4*)&Bs[r][s * 8] = *(const int4*)&Mt[(size_t)(n0 + r) * 128 + kh * 64 + s * 8];
        }
        __syncthreads();
#pragma unroll
        for (int kk = 0; kk < 2; kk++) {
            int ko = kk * 32 + g * 8;
            bf16x8 a0 = *(const bf16x8*)&As[w * 32 + c][ko];
            bf16x8 a1 = *(const bf16x8*)&As[w * 32 + 16 + c][ko];
#pragma unroll
            for (int nt = 0; nt < 8; nt++) {
                bf16x8 b = *(const bf16x8*)&Bs[nt * 16 + c][ko];
                acc[0][nt] = __builtin_amdgcn_mfma_f32_16x16x32_bf16(a0, b, acc[0][nt], 0, 0, 0);
                acc[1][nt] = __builtin_amdgcn_mfma_f32_16x16x32_bf16(a1, b, acc[1][nt], 0, 0, 0);
            }
        }
    }
#pragma unroll
    for (int it = 0; it < 2; it++)
#pragma unroll
        for (int nt = 0; nt < 8; nt++)
#pragma unroll
            for (int r = 0; r < 4; r++) {
                int i = i0 + w * 32 + it * 16 + g * 4 + r;
                int n = n0 + nt * 16 + c;
                U[(size_t)i * 16384 + n] = (short)f2bf(acc[it][nt][r]);
            }
}

// ---------------- phase2 MFMA: Y_i = h_b @ U_i, fused silu/Wm2 epilogue ----------------
__global__ __launch_bounds__(256) void k_p2(const short* __restrict__ hb,
    const short* __restrict__ U, const float* __restrict__ cvec,
    const float* __restrict__ Wm2, const float* __restrict__ bm2,
    float* __restrict__ out)
{
    __shared__ __align__(16) short Hs[128][72];
    __shared__ __align__(16) short Us[128][72];
    int tid = threadIdx.x;
    int i = blockIdx.y;
    int jb = blockIdx.x;          // 0..1
    int b = i >> 8;
    int w = tid >> 6, lane = tid & 63, c = lane & 15, g = lane >> 4;
    f32x4 acc[2][8] = {};
    for (int kh = 0; kh < 2; kh++) {
        __syncthreads();
        for (int idx = tid; idx < 1024; idx += 256) {
            int r = idx >> 3, s = idx & 7;
            *(int4*)&Hs[r][s * 8] = *(const int4*)&hb[(b * 256 + jb * 128 + r) * 128 + kh * 64 + s * 8];
            *(int4*)&Us[r][s * 8] = *(const int4*)&U[(size_t)i * 16384 + r * 128 + kh * 64 + s * 8];
        }
        __syncthreads();
#pragma unroll
        for (int kk = 0; kk < 2; kk++) {
            int ko = kk * 32 + g * 8;
            bf16x8 a0 = *(const bf16x8*)&Hs[w * 32 + c][ko];
            bf16x8 a1 = *(const bf16x8*)&Hs[w * 32 + 16 + c][ko];
#pragma unroll
            for (int mt = 0; mt < 8; mt++) {
                bf16x8 bv = *(const bf16x8*)&Us[mt * 16 + c][ko];
                acc[0][mt] = __builtin_amdgcn_mfma_f32_16x16x32_bf16(a0, bv, acc[0][mt], 0, 0, 0);
                acc[1][mt] = __builtin_amdgcn_mfma_f32_16x16x32_bf16(a1, bv, acc[1][mt], 0, 0, 0);
            }
        }
    }
    // epilogue: Y = acc + cvec[m]; silu; @Wm2 (reduce m across 16 lanes); +bm2
    float cv[8]; float4 w2v[8];
#pragma unroll
    for (int mt = 0; mt < 8; mt++) {
        int m = mt * 16 + c;
        cv[mt] = cvec[m];
        w2v[mt] = *(const float4*)&Wm2[m * 4];
    }
    float4 bmv = *(const float4*)&bm2[0];
#pragma unroll
    for (int jt = 0; jt < 2; jt++) {
#pragma unroll
        for (int r = 0; r < 4; r++) {
            float px = 0.f, py = 0.f, pz = 0.f, pw = 0.f;
#pragma unroll
            for (int mt = 0; mt < 8; mt++) {
                float y = acc[jt][mt][r] + cv[mt];
                float sv = y / (1.f + expf(-y));
                px += sv * w2v[mt].x; py += sv * w2v[mt].y;
                pz += sv * w2v[mt].z; pw += sv * w2v[mt].w;
            }
#pragma unroll
            for (int off = 1; off < 16; off <<= 1) {
                px += __shfl_xor(px, off, 16);
                py += __shfl_xor(py, off, 16);
                pz += __shfl_xor(pz, off, 16);
                pw += __shfl_xor(pw, off, 16);
            }
            if (c == 0) {
                int j = w * 32 + jt * 16 + g * 4 + r;
                float4 o4 = { px + bmv.x, py + bmv.y, pz + bmv.z, pw + bmv.w };
                *(float4*)&out[((size_t)i * 256 + jb * 128 + j) * 4] = o4;
            }
        }
    }
}

extern "C" void kernel_launch(void* const* d_in, const int* in_sizes, int n_in,
                              void* d_out, int out_size, void* d_ws, size_t ws_size,
                              hipStream_t stream)
{
    const float* x   = (const float*)d_in[0];
    const int*   ei  = (const int*)d_in[1];
    const void*  tptr= d_in[3];
    const float* tm  = (const float*)d_in[4];
    const float* Wn  = (const float*)d_in[5];
    const float* bn  = (const float*)d_in[6];
    const float* Wee = (const float*)d_in[7];
    const float* bee = (const float*)d_in[8];
    const float* Wt1 = (const float*)d_in[9];
    const float* bt1 = (const float*)d_in[10];
    const float* Wt2 = (const float*)d_in[11];
    const float* bt2 = (const float*)d_in[12];
    const float* Wa  = (const float*)d_in[13];
    const float* ba  = (const float*)d_in[14];
    const float* Wq  = (const float*)d_in[15];
    const float* bq  = (const float*)d_in[16];
    const float* Wk  = (const float*)d_in[17];
    const float* bk  = (const float*)d_in[18];
    const float* Wv  = (const float*)d_in[19];
    const float* bv  = (const float*)d_in[20];
    const float* We  = (const float*)d_in[21];
    const float* Wsk = (const float*)d_in[22];
    const float* bsk = (const float*)d_in[23];
    const float* Wf1 = (const float*)d_in[24];
    const float* bf1 = (const float*)d_in[25];
    const float* Wf2 = (const float*)d_in[26];
    const float* bf2 = (const float*)d_in[27];
    const float* Wb  = (const float*)d_in[28];
    const float* bb  = (const float*)d_in[29];
    const float* Wm1 = (const float*)d_in[30];
    const float* bm1 = (const float*)d_in[31];
    const float* Wm2 = (const float*)d_in[32];
    const float* bm2 = (const float*)d_in[33];
    float* out = (float*)d_out;
    float* ws = (float*)d_ws;

    float* h    = ws + OFF_H;
    float* qb   = ws + OFF_Q;
    float* kb   = ws + OFF_K;
    float* vb   = ws + OFF_V;
    float* skp  = ws + OFF_SKP;
    float* g    = ws + OFF_G;
    float* ss   = ws + OFF_SS;
    float* ea   = ws + OFF_EA;
    float* cvec = ws + OFF_CVEC;
    int* iws    = (int*)(ws + OFF_INT);
    int* deg    = iws;
    int* cursor = iws + 1024;
    int* rowptr = iws + 2048;
    int* eorder = iws + 3073;
    float* Mst  = ws + OFF_M;
    short* Ub   = (short*)(ws + OFF_U);
    short* Mtb  = (short*)(ws + OFF_MT);
    short* hbb  = (short*)(ws + OFF_HB);

    hipMemsetAsync(deg, 0, 2048 * sizeof(int), stream);
    k_setup<<<1, 512, 0, stream>>>(tptr, Wt1, bt1, Wt2, bt2, Wa, ba, bb, Wm1, bm1, ss, cvec);
    k_input<<<512, 256, 0, stream>>>(x, Wn, bn, h);
    k_edge<<<256, 256, 0, stream>>>(ei, tm, Wee, bee, ea);
    k_count<<<256, 256, 0, stream>>>(ei, deg);
    k_scan<<<1, 1024, 0, stream>>>(deg, rowptr);
    k_scatter<<<256, 256, 0, stream>>>(ei, rowptr, cursor, eorder);
    k_sort2<<<1024, 128, 0, stream>>>(rowptr, eorder);

    for (int l = 0; l < LAYERS; l++) {
        const float* ssl = ss + l * 512;
        k_qkvs<<<dim3(64, 4), 256, 0, stream>>>(h, ssl,
            Wq + l * 16384, Wk + l * 16384, Wv + l * 16384, Wsk + l * 16384,
            bq + l * 128, bk + l * 128, bv + l * 128, bsk + l * 128,
            qb, kb, vb, skp);
        k_attn<<<1024, 64, 0, stream>>>(qb, kb, vb, skp, h, ei, ea, We + l * 128, rowptr, eorder);
        k_gemm<128, 256, true, true, false><<<64, 256, 0, stream>>>(
            h, Wf1 + l * 32768, bf1 + l * 256, g, ssl + 256, ssl + 384);
        k_gemm<256, 128, false, false, true><<<64, 256, 0, stream>>>(
            g, Wf2 + l * 32768, bf2 + l * 128, h, nullptr, nullptr);
    }

    k_mprep<<<128, 256, 0, stream>>>(Wb, Wm1, Mst);
    k_mtrans<<<256, 256, 0, stream>>>(Mst, Mtb);
    k_convh<<<128, 256, 0, stream>>>(h, hbb);
    k_p1<<<dim3(128, 8), 256, 0, stream>>>(hbb, Mtb, Ub);
    k_p2<<<dim3(2, 1024), 256, 0, stream>>>(hbb, Ub, cvec, Wm2, bm2, out);
}

// Round 4
// 600.299 us; speedup vs baseline: 2.5202x; 1.0709x over previous
//
#include <hip/hip_runtime.h>
#include <math.h>

#define N_NODES 1024
#define HDIM 128
#define EDGES 65536
#define LAYERS 6

typedef __attribute__((ext_vector_type(8))) short bf16x8;
typedef __attribute__((ext_vector_type(4))) float f32x4;

// workspace float offsets
#define OFF_H     0
#define OFF_Q     131072
#define OFF_K     262144
#define OFF_V     393216
#define OFF_SKP   524288
#define OFF_G     655360
#define OFF_SS    917504
#define OFF_EA    920576
#define OFF_CVEC  986112
#define OFF_INT   986240
#define OFF_M     1054912      // fp32 M [128 k][16384 n], n = m*128 + l  (m-outer!)
#define OFF_U     3152064      // bf16 U [1024 i][16384 n]   (8,388,608 floats)
#define OFF_MT    11540672     // bf16 Mt [16384 n][128 k]   (1,048,576 floats)
#define OFF_HB    12589248     // bf16 hb [1024][128]        (65,536 floats)

__device__ __forceinline__ float silu_f(float x) { return x / (1.f + expf(-x)); }
__device__ __forceinline__ float frcp(float x) { return __builtin_amdgcn_rcpf(x); }

__device__ __forceinline__ unsigned short f2bf(float f) {
    unsigned int u = __float_as_uint(f);
    u += 0x7FFFu + ((u >> 16) & 1u);
    return (unsigned short)(u >> 16);
}

// ---------------- setup: timestep embedding -> t_mod -> ss[6][512], cvec ---------------
__global__ __launch_bounds__(512) void k_setup(const void* tptr,
    const float* __restrict__ Wt1, const float* __restrict__ bt1,
    const float* __restrict__ Wt2, const float* __restrict__ bt2,
    const float* __restrict__ Wa, const float* __restrict__ ba,
    const float* __restrict__ bb, const float* __restrict__ Wm1, const float* __restrict__ bm1,
    float* __restrict__ ss_all, float* __restrict__ cvec)
{
    __shared__ float emb_s[256];
    __shared__ float tmp1_s[128];
    __shared__ float tmod_s[128];
    int tid = threadIdx.x;
    int iv = *(const int*)tptr;
    float fv = __int_as_float(iv);
    float tval = (iv > -1000000 && iv < 1000000) ? (float)iv : fv;
    if (tid < 128) {
        float fr = expf(-logf(10000.f) * (float)tid / 128.f);
        float ta = tval * fr;
        emb_s[tid] = cosf(ta);
        emb_s[128 + tid] = sinf(ta);
    }
    __syncthreads();
    if (tid < 128) {
        float a = bt1[tid];
        for (int i = 0; i < 256; i++) a += emb_s[i] * Wt1[i * 128 + tid];
        tmp1_s[tid] = silu_f(a);
    }
    __syncthreads();
    if (tid < 128) {
        float a = bt2[tid];
        for (int i = 0; i < 128; i++) a += tmp1_s[i] * Wt2[i * 128 + tid];
        tmod_s[tid] = silu_f(a);
    }
    __syncthreads();
    for (int idx = tid; idx < LAYERS * 512; idx += 512) {
        int l = idx >> 9, j = idx & 511;
        float a = ba[l * 512 + j];
        const float* w = Wa + l * 65536 + j;
        for (int k = 0; k < 128; k++) a += tmod_s[k] * w[k * 512];
        ss_all[idx] = a;
    }
    if (tid < 128) {
        float a = bm1[tid];
        for (int o = 0; o < 128; o++) a += bb[o] * Wm1[o * 128 + tid];
        cvec[tid] = a;
    }
}

// ---------------- h = x @ Wn + bn  (K=5) ----------------
__global__ __launch_bounds__(256) void k_input(const float* __restrict__ x,
    const float* __restrict__ Wn, const float* __restrict__ bn, float* __restrict__ h)
{
    int idx = blockIdx.x * 256 + threadIdx.x;  // < 131072
    int i = idx >> 7, j = idx & 127;
    float acc = bn[j];
#pragma unroll
    for (int kk = 0; kk < 5; kk++) acc += x[i * 5 + kk] * Wn[kk * 128 + j];
    h[idx] = acc;
}

// ---------------- edge_attr ----------------
__global__ __launch_bounds__(256) void k_edge(const int* __restrict__ ei,
    const float* __restrict__ tm, const float* __restrict__ Wee, const float* __restrict__ bee,
    float* __restrict__ ea)
{
    int e = blockIdx.x * 256 + threadIdx.x;
    int s = ei[e], d = ei[EDGES + e];
    ea[e] = tm[s * N_NODES + d] * Wee[0] + bee[0];
}

// ---------------- CSR build ----------------
__global__ __launch_bounds__(256) void k_count(const int* __restrict__ ei, int* __restrict__ deg)
{
    int e = blockIdx.x * 256 + threadIdx.x;
    atomicAdd(&deg[ei[EDGES + e]], 1);
}

__global__ __launch_bounds__(1024) void k_scan(const int* __restrict__ deg, int* __restrict__ rowptr)
{
    __shared__ int tmp[1024];
    int tid = threadIdx.x;
    tmp[tid] = deg[tid];
    __syncthreads();
    for (int off = 1; off < 1024; off <<= 1) {
        int vv = (tid >= off) ? tmp[tid - off] : 0;
        __syncthreads();
        tmp[tid] += vv;
        __syncthreads();
    }
    rowptr[tid + 1] = tmp[tid];
    if (tid == 0) rowptr[0] = 0;
}

__global__ __launch_bounds__(256) void k_scatter(const int* __restrict__ ei,
    const int* __restrict__ rowptr, int* __restrict__ cursor, int* __restrict__ eorder)
{
    int e = blockIdx.x * 256 + threadIdx.x;
    int d = ei[EDGES + e];
    int pos = atomicAdd(&cursor[d], 1);
    eorder[rowptr[d] + pos] = e;
}

// ---------------- per-node bitonic sort of edge ids in LDS ----------------
__global__ __launch_bounds__(128) void k_sort2(const int* __restrict__ rowptr,
                                               int* __restrict__ eorder)
{
    __shared__ int key[256];
    int node = blockIdx.x;
    int tid = threadIdx.x;
    int beg = rowptr[node], end = rowptr[node + 1];
    int n = end - beg;
    if (n <= 256) {
        for (int i = tid; i < 256; i += 128) key[i] = (i < n) ? eorder[beg + i] : 0x7FFFFFFF;
        __syncthreads();
        for (int k = 2; k <= 256; k <<= 1) {
            for (int j = k >> 1; j > 0; j >>= 1) {
                int i = ((tid / j) * 2 * j) + (tid % j);
                int l = i + j;
                bool up = ((i & k) == 0);
                int a = key[i], b = key[l];
                if ((a > b) == up) { key[i] = b; key[l] = a; }
                __syncthreads();
            }
        }
        for (int i = tid; i < n; i += 128) eorder[beg + i] = key[i];
    } else if (tid == 0) {
        for (int i = beg + 1; i < end; ++i) {
            int kk = eorder[i];
            int j = i - 1;
            while (j >= beg && eorder[j] > kk) { eorder[j + 1] = eorder[j]; --j; }
            eorder[j + 1] = kk;
        }
    }
}

// ---------------- fused LN+mod + 4x GEMM (q,k,v,skip) ----------------
__global__ __launch_bounds__(256) void k_qkvs(const float* __restrict__ h,
    const float* __restrict__ ss,
    const float* __restrict__ Wq, const float* __restrict__ Wk,
    const float* __restrict__ Wv, const float* __restrict__ Wsk,
    const float* __restrict__ bq, const float* __restrict__ bk,
    const float* __restrict__ bv, const float* __restrict__ bsk,
    float* __restrict__ q, float* __restrict__ k, float* __restrict__ v, float* __restrict__ skp)
{
    __shared__ float a[16][128];
    __shared__ float mu_s[16], rs_s[16];
    int tid = threadIdx.x;
    int r0 = blockIdx.x * 16;
    for (int idx = tid; idx < 2048; idx += 256) a[idx >> 7][idx & 127] = h[r0 * 128 + idx];
    __syncthreads();
    if (tid < 16) {
        float s = 0.f, s2 = 0.f;
        for (int c = 0; c < 128; c++) { float xx = a[tid][c]; s += xx; s2 += xx * xx; }
        float mu = s * (1.f / 128.f);
        float var = s2 * (1.f / 128.f) - mu * mu;
        mu_s[tid] = mu; rs_s[tid] = rsqrtf(var + 1e-5f);
    }
    __syncthreads();
    const float* sh = ss; const float* sc = ss + 128;
    for (int idx = tid; idx < 2048; idx += 256) {
        int r = idx >> 7, c = idx & 127;
        a[r][c] = (a[r][c] - mu_s[r]) * rs_s[r] * (1.f + sc[c]) + sh[c];
    }
    __syncthreads();
    const float* W; const float* bias; float* out;
    switch (blockIdx.y) {
        case 0:  W = Wq;  bias = bq;  out = q;   break;
        case 1:  W = Wk;  bias = bk;  out = k;   break;
        case 2:  W = Wv;  bias = bv;  out = v;   break;
        default: W = Wsk; bias = bsk; out = skp; break;
    }
    int col = tid & 127, grp = tid >> 7;
    float acc[8] = {};
    for (int kk = 0; kk < 128; ++kk) {
        float bvv = W[kk * 128 + col];
#pragma unroll
        for (int rr = 0; rr < 8; rr++) acc[rr] += a[grp * 8 + rr][kk] * bvv;
    }
#pragma unroll
    for (int rr = 0; rr < 8; rr++)
        out[(r0 + grp * 8 + rr) * 128 + col] = acc[rr] + bias[col];
}

// ---------------- generic 16-row GEMM (optional LN front, gelu, add) ----------------
template <int K, int NCOL, bool LNF, bool GELU_ACT, bool ADD>
__global__ __launch_bounds__(256) void k_gemm(const float* __restrict__ A,
    const float* __restrict__ W, const float* __restrict__ bias, float* __restrict__ C,
    const float* __restrict__ sh, const float* __restrict__ sc)
{
    __shared__ float a[16][K];
    __shared__ float mu_s[16], rs_s[16];
    int tid = threadIdx.x;
    int r0 = blockIdx.x * 16;
    for (int idx = tid; idx < 16 * K; idx += 256) a[idx / K][idx % K] = A[r0 * K + idx];
    __syncthreads();
    if (LNF) {
        if (tid < 16) {
            float s = 0.f, s2 = 0.f;
            for (int c = 0; c < K; c++) { float xx = a[tid][c]; s += xx; s2 += xx * xx; }
            float mu = s * (1.f / K);
            float var = s2 * (1.f / K) - mu * mu;
            mu_s[tid] = mu; rs_s[tid] = rsqrtf(var + 1e-5f);
        }
        __syncthreads();
        for (int idx = tid; idx < 16 * K; idx += 256) {
            int r = idx / K, c = idx % K;
            a[r][c] = (a[r][c] - mu_s[r]) * rs_s[r] * (1.f + sc[c]) + sh[c];
        }
        __syncthreads();
    }
    constexpr int G = 256 / NCOL;
    constexpr int RPT = 16 / G;
    int col = tid % NCOL;
    int grp = tid / NCOL;
    float acc[RPT] = {};
    for (int kk = 0; kk < K; ++kk) {
        float bvv = W[kk * NCOL + col];
#pragma unroll
        for (int rr = 0; rr < RPT; rr++) acc[rr] += a[grp * RPT + rr][kk] * bvv;
    }
#pragma unroll
    for (int rr = 0; rr < RPT; rr++) {
        float y = acc[rr] + bias[col];
        if (GELU_ACT) y = 0.5f * y * (1.f + erff(y * 0.70710678118654752f));
        int r = r0 + grp * RPT + rr;
        if (ADD) C[r * NCOL + col] += y; else C[r * NCOL + col] = y;
    }
}

// ---------------- attention: one wave per dst node, online softmax over CSR edges -------
__global__ __launch_bounds__(64) void k_attn(const float* __restrict__ q,
    const float* __restrict__ k, const float* __restrict__ v,
    const float* __restrict__ skp, float* __restrict__ h,
    const int* __restrict__ ei, const float* __restrict__ ea,
    const float* __restrict__ We_l,
    const int* __restrict__ rowptr, const int* __restrict__ eorder)
{
    int node = blockIdx.x;
    int lane = threadIdx.x;
    int c0 = lane * 2;
    float q0 = q[node * 128 + c0], q1 = q[node * 128 + c0 + 1];
    float we0 = We_l[c0], we1 = We_l[c0 + 1];
    int beg = rowptr[node], end = rowptr[node + 1];
    float m = -INFINITY, s = 0.f, a0 = 0.f, a1 = 0.f;
    const float isc = 0.17677669529663687f;  // 1/sqrt(32)

    int t = beg;
    for (; t + 1 < end; t += 2) {
        int eA = eorder[t], eB = eorder[t + 1];
        int snA = ei[eA], snB = ei[eB];
        float eavA = ea[eA], eavB = ea[eB];
        float kA0 = k[snA * 128 + c0],     kB0 = k[snB * 128 + c0];
        float kA1 = k[snA * 128 + c0 + 1], kB1 = k[snB * 128 + c0 + 1];
        float vA0 = v[snA * 128 + c0],     vB0 = v[snB * 128 + c0];
        float vA1 = v[snA * 128 + c0 + 1], vB1 = v[snB * 128 + c0 + 1];
        kA0 += eavA * we0; kA1 += eavA * we1;
        kB0 += eavB * we0; kB1 += eavB * we1;
        float pA = q0 * kA0 + q1 * kA1;
        float pB = q0 * kB0 + q1 * kB1;
        pA += __shfl_xor(pA, 1, 16); pB += __shfl_xor(pB, 1, 16);
        pA += __shfl_xor(pA, 2, 16); pB += __shfl_xor(pB, 2, 16);
        pA += __shfl_xor(pA, 4, 16); pB += __shfl_xor(pB, 4, 16);
        pA += __shfl_xor(pA, 8, 16); pB += __shfl_xor(pB, 8, 16);
        float alA = pA * isc, alB = pB * isc;
        {
            float mn = fmaxf(m, alA);
            float scale = __expf(m - mn);
            float w = __expf(alA - mn);
            s = s * scale + w;
            a0 = a0 * scale + w * (vA0 + eavA * we0);
            a1 = a1 * scale + w * (vA1 + eavA * we1);
            m = mn;
        }
        {
            float mn = fmaxf(m, alB);
            float scale = __expf(m - mn);
            float w = __expf(alB - mn);
            s = s * scale + w;
            a0 = a0 * scale + w * (vB0 + eavB * we0);
            a1 = a1 * scale + w * (vB1 + eavB * we1);
            m = mn;
        }
    }
    for (; t < end; ++t) {
        int e = eorder[t];
        int sn = ei[e];
        float eav = ea[e];
        float k0 = k[sn * 128 + c0] + eav * we0;
        float k1 = k[sn * 128 + c0 + 1] + eav * we1;
        float part = q0 * k0 + q1 * k1;
        part += __shfl_xor(part, 1, 16);
        part += __shfl_xor(part, 2, 16);
        part += __shfl_xor(part, 4, 16);
        part += __shfl_xor(part, 8, 16);
        float alpha = part * isc;
        float mn = fmaxf(m, alpha);
        float scale = __expf(m - mn);
        float w = __expf(alpha - mn);
        s = s * scale + w;
        float v0 = v[sn * 128 + c0] + eav * we0;
        float v1 = v[sn * 128 + c0 + 1] + eav * we1;
        a0 = a0 * scale + w * v0;
        a1 = a1 * scale + w * v1;
        m = mn;
    }
    float inv = 1.f / (s + 1e-16f);
    int o = node * 128 + c0;
    h[o]     += skp[o]     + a0 * inv;
    h[o + 1] += skp[o + 1] + a1 * inv;
}

// ---------------- M[k][m*128+l] = sum_o Wb[o,k,l] * Wm1[o,m]  (m-outer layout!) --------
__global__ __launch_bounds__(256) void k_mprep(const float* __restrict__ Wb,
    const float* __restrict__ Wm1, float* __restrict__ M)
{
    __shared__ float wb_s[64][128];
    __shared__ float wm_s[64][128];
    int tid = threadIdx.x;
    int k = blockIdx.x;
    int mg = tid & 15, lg = tid >> 4;
    int m0 = mg * 8, l0 = lg * 8;
    float acc[8][8] = {};
    for (int oh = 0; oh < 2; ++oh) {
        __syncthreads();
        for (int idx = tid; idx < 8192; idx += 256) {
            int o = idx >> 7, c = idx & 127;
            wb_s[o][c] = Wb[(size_t)(oh * 64 + o) * 16384 + k * 128 + c];
            wm_s[o][c] = Wm1[(oh * 64 + o) * 128 + c];
        }
        __syncthreads();
        for (int o = 0; o < 64; o++) {
            float lv[8], mv[8];
#pragma unroll
            for (int i = 0; i < 8; i++) { lv[i] = wb_s[o][l0 + i]; mv[i] = wm_s[o][m0 + i]; }
#pragma unroll
            for (int li = 0; li < 8; li++)
#pragma unroll
                for (int mi = 0; mi < 8; mi++) acc[li][mi] += lv[li] * mv[mi];
        }
    }
    for (int mi = 0; mi < 8; mi++)
        for (int li = 0; li < 8; li++)
            M[(size_t)k * 16384 + (m0 + mi) * 128 + (l0 + li)] = acc[li][mi];
}

// ---------------- Mt[n][k] (bf16) <- M[k][n] (fp32) ----------------
__global__ __launch_bounds__(256) void k_mtrans(const float* __restrict__ M,
                                                short* __restrict__ Mt)
{
    __shared__ __align__(16) short Ts[64][136];
    int tid = threadIdx.x;
    int n0 = blockIdx.x * 64;
    for (int p = 0; p < 32; p++) {
        int idx = p * 256 + tid;
        int k = idx >> 6, nn = idx & 63;
        Ts[nn][k] = (short)f2bf(M[(size_t)k * 16384 + n0 + nn]);
    }
    __syncthreads();
    for (int p = 0; p < 4; p++) {
        int idx = p * 256 + tid;
        int nn = idx >> 4, s = idx & 15;
        *(int4*)&Mt[(size_t)(n0 + nn) * 128 + s * 8] = *(const int4*)&Ts[nn][s * 8];
    }
}

// ---------------- hb (bf16) <- h (fp32) ----------------
__global__ __launch_bounds__(256) void k_convh(const float* __restrict__ h,
                                               short* __restrict__ hb)
{
    int idx = (blockIdx.x * 256 + threadIdx.x) * 4;
    float4 v = *(const float4*)&h[idx];
    short4 o;
    o.x = (short)f2bf(v.x); o.y = (short)f2bf(v.y);
    o.z = (short)f2bf(v.z); o.w = (short)f2bf(v.w);
    *(short4*)&hb[idx] = o;
}

// ---------------- phase1 MFMA: U[i][n] = sum_k hb[i,k] * Mt[n,k] ----------------
__global__ __launch_bounds__(256) void k_p1(const short* __restrict__ hb,
    const short* __restrict__ Mt, short* __restrict__ U)
{
    __shared__ __align__(16) short As[128][72];
    __shared__ __align__(16) short Bs[128][72];
    int tid = threadIdx.x;
    int n0 = blockIdx.x * 128;
    int i0 = blockIdx.y * 128;
    int w = tid >> 6, lane = tid & 63, c = lane & 15, g = lane >> 4;
    f32x4 acc[2][8] = {};
    for (int kh = 0; kh < 2; kh++) {
        __syncthreads();
        for (int idx = tid; idx < 1024; idx += 256) {
            int r = idx >> 3, s = idx & 7;
            *(int4*)&As[r][s * 8] = *(const int4*)&hb[(i0 + r) * 128 + kh * 64 + s * 8];
            *(int4*)&Bs[r][s * 8] = *(const int4*)&Mt[(size_t)(n0 + r) * 128 + kh * 64 + s * 8];
        }
        __syncthreads();
#pragma unroll
        for (int kk = 0; kk < 2; kk++) {
            int ko = kk * 32 + g * 8;
            bf16x8 a0 = *(const bf16x8*)&As[w * 32 + c][ko];
            bf16x8 a1 = *(const bf16x8*)&As[w * 32 + 16 + c][ko];
#pragma unroll
            for (int nt = 0; nt < 8; nt++) {
                bf16x8 b = *(const bf16x8*)&Bs[nt * 16 + c][ko];
                acc[0][nt] = __builtin_amdgcn_mfma_f32_16x16x32_bf16(a0, b, acc[0][nt], 0, 0, 0);
                acc[1][nt] = __builtin_amdgcn_mfma_f32_16x16x32_bf16(a1, b, acc[1][nt], 0, 0, 0);
            }
        }
    }
#pragma unroll
    for (int it = 0; it < 2; it++)
#pragma unroll
        for (int nt = 0; nt < 8; nt++)
#pragma unroll
            for (int r = 0; r < 4; r++) {
                int i = i0 + w * 32 + it * 16 + g * 4 + r;
                int n = n0 + nt * 16 + c;
                U[(size_t)i * 16384 + n] = (short)f2bf(acc[it][nt][r]);
            }
}

// ---------------- phase2 MFMA (swapped operands): D[m][j] = sum_l U[m,l] H[j,l] ----------
// lane-local m => Wm2 contraction needs only 2 shfl stages (across g groups)
__global__ __launch_bounds__(256) void k_p2(const short* __restrict__ hb,
    const short* __restrict__ U, const float* __restrict__ cvec,
    const float* __restrict__ Wm2, const float* __restrict__ bm2,
    float* __restrict__ out)
{
    __shared__ __align__(16) short Hs[128][72];
    __shared__ __align__(16) short Us[128][72];
    __shared__ float cvs[128];
    __shared__ float w2s[128][4];
    int tid = threadIdx.x;
    int i = blockIdx.y;
    int jb = blockIdx.x;          // 0..1
    int b = i >> 8;
    int w = tid >> 6, lane = tid & 63, c = lane & 15, g = lane >> 4;
    if (tid < 128) {
        cvs[tid] = cvec[tid];
        *(float4*)&w2s[tid][0] = *(const float4*)&Wm2[tid * 4];
    }
    f32x4 acc[2][8] = {};
    for (int kh = 0; kh < 2; kh++) {
        __syncthreads();
        for (int idx = tid; idx < 1024; idx += 256) {
            int r = idx >> 3, s = idx & 7;
            *(int4*)&Hs[r][s * 8] = *(const int4*)&hb[(b * 256 + jb * 128 + r) * 128 + kh * 64 + s * 8];
            *(int4*)&Us[r][s * 8] = *(const int4*)&U[(size_t)i * 16384 + r * 128 + kh * 64 + s * 8];
        }
        __syncthreads();
#pragma unroll
        for (int kk = 0; kk < 2; kk++) {
            int ko = kk * 32 + g * 8;
            bf16x8 h0 = *(const bf16x8*)&Hs[w * 32 + c][ko];
            bf16x8 h1 = *(const bf16x8*)&Hs[w * 32 + 16 + c][ko];
#pragma unroll
            for (int mt = 0; mt < 8; mt++) {
                bf16x8 uv = *(const bf16x8*)&Us[mt * 16 + c][ko];
                acc[0][mt] = __builtin_amdgcn_mfma_f32_16x16x32_bf16(uv, h0, acc[0][mt], 0, 0, 0);
                acc[1][mt] = __builtin_amdgcn_mfma_f32_16x16x32_bf16(uv, h1, acc[1][mt], 0, 0, 0);
            }
        }
    }
    // lane holds: j = w*32 + jt*16 + c (fixed per jt), m = mt*16 + g*4 + r
    float4 bmv = *(const float4*)&bm2[0];
#pragma unroll
    for (int jt = 0; jt < 2; jt++) {
        float p0 = 0.f, p1 = 0.f, p2 = 0.f, p3 = 0.f;
#pragma unroll
        for (int mt = 0; mt < 8; mt++) {
#pragma unroll
            for (int r = 0; r < 4; r++) {
                int m = mt * 16 + g * 4 + r;
                float y = acc[jt][mt][r] + cvs[m];
                float sv = y * frcp(1.f + __expf(-y));
                p0 += sv * w2s[m][0]; p1 += sv * w2s[m][1];
                p2 += sv * w2s[m][2]; p3 += sv * w2s[m][3];
            }
        }
        // reduce across g groups (lane bits 4-5)
        p0 += __shfl_xor(p0, 16, 64); p1 += __shfl_xor(p1, 16, 64);
        p2 += __shfl_xor(p2, 16, 64); p3 += __shfl_xor(p3, 16, 64);
        p0 += __shfl_xor(p0, 32, 64); p1 += __shfl_xor(p1, 32, 64);
        p2 += __shfl_xor(p2, 32, 64); p3 += __shfl_xor(p3, 32, 64);
        if (g == 0) {
            int j = w * 32 + jt * 16 + c;
            float4 o4 = { p0 + bmv.x, p1 + bmv.y, p2 + bmv.z, p3 + bmv.w };
            *(float4*)&out[((size_t)i * 256 + jb * 128 + j) * 4] = o4;
        }
    }
}

extern "C" void kernel_launch(void* const* d_in, const int* in_sizes, int n_in,
                              void* d_out, int out_size, void* d_ws, size_t ws_size,
                              hipStream_t stream)
{
    const float* x   = (const float*)d_in[0];
    const int*   ei  = (const int*)d_in[1];
    const void*  tptr= d_in[3];
    const float* tm  = (const float*)d_in[4];
    const float* Wn  = (const float*)d_in[5];
    const float* bn  = (const float*)d_in[6];
    const float* Wee = (const float*)d_in[7];
    const float* bee = (const float*)d_in[8];
    const float* Wt1 = (const float*)d_in[9];
    const float* bt1 = (const float*)d_in[10];
    const float* Wt2 = (const float*)d_in[11];
    const float* bt2 = (const float*)d_in[12];
    const float* Wa  = (const float*)d_in[13];
    const float* ba  = (const float*)d_in[14];
    const float* Wq  = (const float*)d_in[15];
    const float* bq  = (const float*)d_in[16];
    const float* Wk  = (const float*)d_in[17];
    const float* bk  = (const float*)d_in[18];
    const float* Wv  = (const float*)d_in[19];
    const float* bv  = (const float*)d_in[20];
    const float* We  = (const float*)d_in[21];
    const float* Wsk = (const float*)d_in[22];
    const float* bsk = (const float*)d_in[23];
    const float* Wf1 = (const float*)d_in[24];
    const float* bf1 = (const float*)d_in[25];
    const float* Wf2 = (const float*)d_in[26];
    const float* bf2 = (const float*)d_in[27];
    const float* Wb  = (const float*)d_in[28];
    const float* bb  = (const float*)d_in[29];
    const float* Wm1 = (const float*)d_in[30];
    const float* bm1 = (const float*)d_in[31];
    const float* Wm2 = (const float*)d_in[32];
    const float* bm2 = (const float*)d_in[33];
    float* out = (float*)d_out;
    float* ws = (float*)d_ws;

    float* h    = ws + OFF_H;
    float* qb   = ws + OFF_Q;
    float* kb   = ws + OFF_K;
    float* vb   = ws + OFF_V;
    float* skp  = ws + OFF_SKP;
    float* g    = ws + OFF_G;
    float* ss   = ws + OFF_SS;
    float* ea   = ws + OFF_EA;
    float* cvec = ws + OFF_CVEC;
    int* iws    = (int*)(ws + OFF_INT);
    int* deg    = iws;
    int* cursor = iws + 1024;
    int* rowptr = iws + 2048;
    int* eorder = iws + 3073;
    float* Mst  = ws + OFF_M;
    short* Ub   = (short*)(ws + OFF_U);
    short* Mtb  = (short*)(ws + OFF_MT);
    short* hbb  = (short*)(ws + OFF_HB);

    hipMemsetAsync(deg, 0, 2048 * sizeof(int), stream);
    k_setup<<<1, 512, 0, stream>>>(tptr, Wt1, bt1, Wt2, bt2, Wa, ba, bb, Wm1, bm1, ss, cvec);
    k_input<<<512, 256, 0, stream>>>(x, Wn, bn, h);
    k_edge<<<256, 256, 0, stream>>>(ei, tm, Wee, bee, ea);
    k_count<<<256, 256, 0, stream>>>(ei, deg);
    k_scan<<<1, 1024, 0, stream>>>(deg, rowptr);
    k_scatter<<<256, 256, 0, stream>>>(ei, rowptr, cursor, eorder);
    k_sort2<<<1024, 128, 0, stream>>>(rowptr, eorder);

    for (int l = 0; l < LAYERS; l++) {
        const float* ssl = ss + l * 512;
        k_qkvs<<<dim3(64, 4), 256, 0, stream>>>(h, ssl,
            Wq + l * 16384, Wk + l * 16384, Wv + l * 16384, Wsk + l * 16384,
            bq + l * 128, bk + l * 128, bv + l * 128, bsk + l * 128,
            qb, kb, vb, skp);
        k_attn<<<1024, 64, 0, stream>>>(qb, kb, vb, skp, h, ei, ea, We + l * 128, rowptr, eorder);
        k_gemm<128, 256, true, true, false><<<64, 256, 0, stream>>>(
            h, Wf1 + l * 32768, bf1 + l * 256, g, ssl + 256, ssl + 384);
        k_gemm<256, 128, false, false, true><<<64, 256, 0, stream>>>(
            g, Wf2 + l * 32768, bf2 + l * 128, h, nullptr, nullptr);
    }

    k_mprep<<<128, 256, 0, stream>>>(Wb, Wm1, Mst);
    k_mtrans<<<256, 256, 0, stream>>>(Mst, Mtb);
    k_convh<<<128, 256, 0, stream>>>(h, hbb);
    k_p1<<<dim3(128, 8), 256, 0, stream>>>(hbb, Mtb, Ub);
    k_p2<<<dim3(2, 1024), 256, 0, stream>>>(hbb, Ub, cvec, Wm2, bm2, out);
}

// Round 6
// 549.013 us; speedup vs baseline: 2.7556x; 1.0934x over previous
//
#include <hip/hip_runtime.h>
#include <math.h>

#define N_NODES 1024
#define HDIM 128
#define EDGES 65536
#define LAYERS 6

typedef __attribute__((ext_vector_type(8))) short bf16x8;
typedef __attribute__((ext_vector_type(4))) float f32x4;

// workspace float offsets
#define OFF_H     0
#define OFF_Q     131072
#define OFF_K     262144
#define OFF_V     393216
#define OFF_SKP   524288
#define OFF_G     655360
#define OFF_SS    917504
#define OFF_EA    920576
#define OFF_CVEC  986112
#define OFF_INT   986240
#define OFF_M     1054912      // fp32 M [128 k][16384 n], n = m*128 + l  (m-outer!)
#define OFF_U     3152064      // bf16 U [1024 i][16384 n]   (8,388,608 floats)
#define OFF_MT    11540672     // bf16 Mt [16384 n][128 k]   (1,048,576 floats)
#define OFF_HB    12589248     // bf16 hb [1024][128]        (65,536 floats)
#define OFF_TMOD  12654784     // fp32 tmod [128]

__device__ __forceinline__ float silu_f(float x) { return x / (1.f + expf(-x)); }
__device__ __forceinline__ float frcp(float x) { return __builtin_amdgcn_rcpf(x); }

__device__ __forceinline__ unsigned short f2bf(float f) {
    unsigned int u = __float_as_uint(f);
    u += 0x7FFFu + ((u >> 16) & 1u);
    return (unsigned short)(u >> 16);
}

// ---------------- tiny serial setup: emb -> t_mod, cvec ----------------
__global__ __launch_bounds__(128) void k_tmod(const void* tptr,
    const float* __restrict__ Wt1, const float* __restrict__ bt1,
    const float* __restrict__ Wt2, const float* __restrict__ bt2,
    const float* __restrict__ bb, const float* __restrict__ Wm1, const float* __restrict__ bm1,
    float* __restrict__ tmod_g, float* __restrict__ cvec)
{
    __shared__ float emb_s[256];
    __shared__ float tmp1_s[128];
    int tid = threadIdx.x;
    int iv = *(const int*)tptr;
    float fv = __int_as_float(iv);
    float tval = (iv > -1000000 && iv < 1000000) ? (float)iv : fv;
    {
        float fr = expf(-logf(10000.f) * (float)tid / 128.f);
        float ta = tval * fr;
        emb_s[tid] = cosf(ta);
        emb_s[128 + tid] = sinf(ta);
    }
    __syncthreads();
    {
        float a = bt1[tid];
#pragma unroll 4
        for (int i = 0; i < 256; i++) a += emb_s[i] * Wt1[i * 128 + tid];
        tmp1_s[tid] = silu_f(a);
    }
    __syncthreads();
    {
        float a = bt2[tid];
#pragma unroll 4
        for (int i = 0; i < 128; i++) a += tmp1_s[i] * Wt2[i * 128 + tid];
        tmod_g[tid] = silu_f(a);   // t_mod = silu(t_emb)  (R5 bug was double-silu here)
    }
    {
        float a = bm1[tid];
#pragma unroll 4
        for (int o = 0; o < 128; o++) a += bb[o] * Wm1[o * 128 + tid];
        cvec[tid] = a;
    }
}

// ---------------- parallel ss projection: ss[l][j] = tmod @ Wa[l][:,j] + ba ------------
__global__ __launch_bounds__(256) void k_ss(const float* __restrict__ tmod_g,
    const float* __restrict__ Wa, const float* __restrict__ ba, float* __restrict__ ss_all)
{
    __shared__ float tm_s[128];
    int tid = threadIdx.x;
    if (tid < 128) tm_s[tid] = tmod_g[tid];
    __syncthreads();
    int idx = blockIdx.x * 256 + tid;       // < 3072
    int l = idx >> 9, j = idx & 511;
    float a = ba[l * 512 + j];
    const float* w = Wa + l * 65536 + j;
#pragma unroll 4
    for (int k = 0; k < 128; k++) a += tm_s[k] * w[k * 512];
    ss_all[idx] = a;
}

// ---------------- h = x @ Wn + bn  (K=5) ----------------
__global__ __launch_bounds__(256) void k_input(const float* __restrict__ x,
    const float* __restrict__ Wn, const float* __restrict__ bn, float* __restrict__ h)
{
    int idx = blockIdx.x * 256 + threadIdx.x;  // < 131072
    int i = idx >> 7, j = idx & 127;
    float acc = bn[j];
#pragma unroll
    for (int kk = 0; kk < 5; kk++) acc += x[i * 5 + kk] * Wn[kk * 128 + j];
    h[idx] = acc;
}

// ---------------- edge_attr ----------------
__global__ __launch_bounds__(256) void k_edge(const int* __restrict__ ei,
    const float* __restrict__ tm, const float* __restrict__ Wee, const float* __restrict__ bee,
    float* __restrict__ ea)
{
    int e = blockIdx.x * 256 + threadIdx.x;
    int s = ei[e], d = ei[EDGES + e];
    ea[e] = tm[s * N_NODES + d] * Wee[0] + bee[0];
}

// ---------------- CSR build ----------------
__global__ __launch_bounds__(256) void k_count(const int* __restrict__ ei, int* __restrict__ deg)
{
    int e = blockIdx.x * 256 + threadIdx.x;
    atomicAdd(&deg[ei[EDGES + e]], 1);
}

__global__ __launch_bounds__(1024) void k_scan(const int* __restrict__ deg, int* __restrict__ rowptr)
{
    __shared__ int tmp[1024];
    int tid = threadIdx.x;
    tmp[tid] = deg[tid];
    __syncthreads();
    for (int off = 1; off < 1024; off <<= 1) {
        int vv = (tid >= off) ? tmp[tid - off] : 0;
        __syncthreads();
        tmp[tid] += vv;
        __syncthreads();
    }
    rowptr[tid + 1] = tmp[tid];
    if (tid == 0) rowptr[0] = 0;
}

__global__ __launch_bounds__(256) void k_scatter(const int* __restrict__ ei,
    const int* __restrict__ rowptr, int* __restrict__ cursor, int* __restrict__ eorder)
{
    int e = blockIdx.x * 256 + threadIdx.x;
    int d = ei[EDGES + e];
    int pos = atomicAdd(&cursor[d], 1);
    eorder[rowptr[d] + pos] = e;
}

// ---------------- per-node bitonic sort of edge ids in LDS ----------------
__global__ __launch_bounds__(128) void k_sort2(const int* __restrict__ rowptr,
                                               int* __restrict__ eorder)
{
    __shared__ int key[256];
    int node = blockIdx.x;
    int tid = threadIdx.x;
    int beg = rowptr[node], end = rowptr[node + 1];
    int n = end - beg;
    if (n <= 256) {
        for (int i = tid; i < 256; i += 128) key[i] = (i < n) ? eorder[beg + i] : 0x7FFFFFFF;
        __syncthreads();
        for (int k = 2; k <= 256; k <<= 1) {
            for (int j = k >> 1; j > 0; j >>= 1) {
                int i = ((tid / j) * 2 * j) + (tid % j);
                int l = i + j;
                bool up = ((i & k) == 0);
                int a = key[i], b = key[l];
                if ((a > b) == up) { key[i] = b; key[l] = a; }
                __syncthreads();
            }
        }
        for (int i = tid; i < n; i += 128) eorder[beg + i] = key[i];
    } else if (tid == 0) {
        for (int i = beg + 1; i < end; ++i) {
            int kk = eorder[i];
            int j = i - 1;
            while (j >= beg && eorder[j] > kk) { eorder[j + 1] = eorder[j]; --j; }
            eorder[j + 1] = kk;
        }
    }
}

// ---------------- fused LN+mod + 4x GEMM (q,k,v,skip) ----------------
__global__ __launch_bounds__(256) void k_qkvs(const float* __restrict__ h,
    const float* __restrict__ ss,
    const float* __restrict__ Wq, const float* __restrict__ Wk,
    const float* __restrict__ Wv, const float* __restrict__ Wsk,
    const float* __restrict__ bq, const float* __restrict__ bk,
    const float* __restrict__ bv, const float* __restrict__ bsk,
    float* __restrict__ q, float* __restrict__ k, float* __restrict__ v, float* __restrict__ skp)
{
    __shared__ float a[16][128];
    __shared__ float mu_s[16], rs_s[16];
    int tid = threadIdx.x;
    int r0 = blockIdx.x * 16;
    for (int idx = tid; idx < 2048; idx += 256) a[idx >> 7][idx & 127] = h[r0 * 128 + idx];
    __syncthreads();
    if (tid < 16) {
        float s = 0.f, s2 = 0.f;
        for (int c = 0; c < 128; c++) { float xx = a[tid][c]; s += xx; s2 += xx * xx; }
        float mu = s * (1.f / 128.f);
        float var = s2 * (1.f / 128.f) - mu * mu;
        mu_s[tid] = mu; rs_s[tid] = rsqrtf(var + 1e-5f);
    }
    __syncthreads();
    const float* sh = ss; const float* sc = ss + 128;
    for (int idx = tid; idx < 2048; idx += 256) {
        int r = idx >> 7, c = idx & 127;
        a[r][c] = (a[r][c] - mu_s[r]) * rs_s[r] * (1.f + sc[c]) + sh[c];
    }
    __syncthreads();
    const float* W; const float* bias; float* out;
    switch (blockIdx.y) {
        case 0:  W = Wq;  bias = bq;  out = q;   break;
        case 1:  W = Wk;  bias = bk;  out = k;   break;
        case 2:  W = Wv;  bias = bv;  out = v;   break;
        default: W = Wsk; bias = bsk; out = skp; break;
    }
    int col = tid & 127, grp = tid >> 7;
    float acc[8] = {};
    for (int kk = 0; kk < 128; ++kk) {
        float bvv = W[kk * 128 + col];
#pragma unroll
        for (int rr = 0; rr < 8; rr++) acc[rr] += a[grp * 8 + rr][kk] * bvv;
    }
#pragma unroll
    for (int rr = 0; rr < 8; rr++)
        out[(r0 + grp * 8 + rr) * 128 + col] = acc[rr] + bias[col];
}

// ---------------- fused FFN: LN+mod -> f1 -> gelu -> f2 -> residual add ----------------
__global__ __launch_bounds__(512) void k_ffn(float* __restrict__ h,
    const float* __restrict__ Wf1, const float* __restrict__ bf1,
    const float* __restrict__ Wf2, const float* __restrict__ bf2,
    const float* __restrict__ sh, const float* __restrict__ sc)
{
    __shared__ float a[16][128];
    __shared__ float gbuf[16][257];
    __shared__ float mu_s[16], rs_s[16];
    int tid = threadIdx.x;
    int r0 = blockIdx.x * 16;
    for (int idx = tid; idx < 2048; idx += 512) a[idx >> 7][idx & 127] = h[r0 * 128 + idx];
    __syncthreads();
    if (tid < 16) {
        float s = 0.f, s2 = 0.f;
        for (int c = 0; c < 128; c++) { float xx = a[tid][c]; s += xx; s2 += xx * xx; }
        float mu = s * (1.f / 128.f);
        float var = s2 * (1.f / 128.f) - mu * mu;
        mu_s[tid] = mu; rs_s[tid] = rsqrtf(var + 1e-5f);
    }
    __syncthreads();
    for (int idx = tid; idx < 2048; idx += 512) {
        int r = idx >> 7, c = idx & 127;
        a[r][c] = (a[r][c] - mu_s[r]) * rs_s[r] * (1.f + sc[c]) + sh[c];
    }
    __syncthreads();
    {   // f1 + gelu: 16 rows x 256 cols, 512 threads -> 8 rows per thread-group
        int col = tid & 255, grp = tid >> 8;   // grp 0..1
        float acc[8] = {};
        for (int k = 0; k < 128; ++k) {
            float wv = Wf1[k * 256 + col];
#pragma unroll
            for (int rr = 0; rr < 8; rr++) acc[rr] += a[grp * 8 + rr][k] * wv;
        }
        float bv = bf1[col];
#pragma unroll
        for (int rr = 0; rr < 8; rr++) {
            float y = acc[rr] + bv;
            gbuf[grp * 8 + rr][col] = 0.5f * y * (1.f + erff(y * 0.70710678118654752f));
        }
    }
    __syncthreads();
    {   // f2 + residual: 16 rows x 128 cols, 512 threads -> 4 rows per thread-group
        int col = tid & 127, grp = tid >> 7;   // grp 0..3
        float acc[4] = {};
        for (int k = 0; k < 256; ++k) {
            float wv = Wf2[k * 128 + col];
#pragma unroll
            for (int rr = 0; rr < 4; rr++) acc[rr] += gbuf[grp * 4 + rr][k] * wv;
        }
        float bv = bf2[col];
#pragma unroll
        for (int rr = 0; rr < 4; rr++)
            h[(r0 + grp * 4 + rr) * 128 + col] += acc[rr] + bv;
    }
}

// ---------------- attention: one wave per dst node, online softmax over CSR edges -------
__global__ __launch_bounds__(64) void k_attn(const float* __restrict__ q,
    const float* __restrict__ k, const float* __restrict__ v,
    const float* __restrict__ skp, float* __restrict__ h,
    const int* __restrict__ ei, const float* __restrict__ ea,
    const float* __restrict__ We_l,
    const int* __restrict__ rowptr, const int* __restrict__ eorder)
{
    int node = blockIdx.x;
    int lane = threadIdx.x;
    int c0 = lane * 2;
    float q0 = q[node * 128 + c0], q1 = q[node * 128 + c0 + 1];
    float we0 = We_l[c0], we1 = We_l[c0 + 1];
    int beg = rowptr[node], end = rowptr[node + 1];
    float m = -INFINITY, s = 0.f, a0 = 0.f, a1 = 0.f;
    const float isc = 0.17677669529663687f;  // 1/sqrt(32)

    int t = beg;
    for (; t + 1 < end; t += 2) {
        int eA = eorder[t], eB = eorder[t + 1];
        int snA = ei[eA], snB = ei[eB];
        float eavA = ea[eA], eavB = ea[eB];
        float kA0 = k[snA * 128 + c0],     kB0 = k[snB * 128 + c0];
        float kA1 = k[snA * 128 + c0 + 1], kB1 = k[snB * 128 + c0 + 1];
        float vA0 = v[snA * 128 + c0],     vB0 = v[snB * 128 + c0];
        float vA1 = v[snA * 128 + c0 + 1], vB1 = v[snB * 128 + c0 + 1];
        kA0 += eavA * we0; kA1 += eavA * we1;
        kB0 += eavB * we0; kB1 += eavB * we1;
        float pA = q0 * kA0 + q1 * kA1;
        float pB = q0 * kB0 + q1 * kB1;
        pA += __shfl_xor(pA, 1, 16); pB += __shfl_xor(pB, 1, 16);
        pA += __shfl_xor(pA, 2, 16); pB += __shfl_xor(pB, 2, 16);
        pA += __shfl_xor(pA, 4, 16); pB += __shfl_xor(pB, 4, 16);
        pA += __shfl_xor(pA, 8, 16); pB += __shfl_xor(pB, 8, 16);
        float alA = pA * isc, alB = pB * isc;
        {
            float mn = fmaxf(m, alA);
            float scale = __expf(m - mn);
            float w = __expf(alA - mn);
            s = s * scale + w;
            a0 = a0 * scale + w * (vA0 + eavA * we0);
            a1 = a1 * scale + w * (vA1 + eavA * we1);
            m = mn;
        }
        {
            float mn = fmaxf(m, alB);
            float scale = __expf(m - mn);
            float w = __expf(alB - mn);
            s = s * scale + w;
            a0 = a0 * scale + w * (vB0 + eavB * we0);
            a1 = a1 * scale + w * (vB1 + eavB * we1);
            m = mn;
        }
    }
    for (; t < end; ++t) {
        int e = eorder[t];
        int sn = ei[e];
        float eav = ea[e];
        float k0 = k[sn * 128 + c0] + eav * we0;
        float k1 = k[sn * 128 + c0 + 1] + eav * we1;
        float part = q0 * k0 + q1 * k1;
        part += __shfl_xor(part, 1, 16);
        part += __shfl_xor(part, 2, 16);
        part += __shfl_xor(part, 4, 16);
        part += __shfl_xor(part, 8, 16);
        float alpha = part * isc;
        float mn = fmaxf(m, alpha);
        float scale = __expf(m - mn);
        float w = __expf(alpha - mn);
        s = s * scale + w;
        float v0 = v[sn * 128 + c0] + eav * we0;
        float v1 = v[sn * 128 + c0 + 1] + eav * we1;
        a0 = a0 * scale + w * v0;
        a1 = a1 * scale + w * v1;
        m = mn;
    }
    float inv = 1.f / (s + 1e-16f);
    int o = node * 128 + c0;
    h[o]     += skp[o]     + a0 * inv;
    h[o + 1] += skp[o + 1] + a1 * inv;
}

// ---------------- M[k][m*128+l] = sum_o Wb[o,k,l] * Wm1[o,m]  (m-outer layout!) --------
__global__ __launch_bounds__(256) void k_mprep(const float* __restrict__ Wb,
    const float* __restrict__ Wm1, float* __restrict__ M)
{
    __shared__ float wb_s[64][128];
    __shared__ float wm_s[64][128];
    int tid = threadIdx.x;
    int k = blockIdx.x;
    int mg = tid & 15, lg = tid >> 4;
    int m0 = mg * 8, l0 = lg * 8;
    float acc[8][8] = {};
    for (int oh = 0; oh < 2; ++oh) {
        __syncthreads();
        for (int idx = tid; idx < 8192; idx += 256) {
            int o = idx >> 7, c = idx & 127;
            wb_s[o][c] = Wb[(size_t)(oh * 64 + o) * 16384 + k * 128 + c];
            wm_s[o][c] = Wm1[(oh * 64 + o) * 128 + c];
        }
        __syncthreads();
        for (int o = 0; o < 64; o++) {
            float lv[8], mv[8];
#pragma unroll
            for (int i = 0; i < 8; i++) { lv[i] = wb_s[o][l0 + i]; mv[i] = wm_s[o][m0 + i]; }
#pragma unroll
            for (int li = 0; li < 8; li++)
#pragma unroll
                for (int mi = 0; mi < 8; mi++) acc[li][mi] += lv[li] * mv[mi];
        }
    }
    for (int mi = 0; mi < 8; mi++)
        for (int li = 0; li < 8; li++)
            M[(size_t)k * 16384 + (m0 + mi) * 128 + (l0 + li)] = acc[li][mi];
}

// ---------------- Mt[n][k] (bf16) <- M[k][n] (fp32) ----------------
__global__ __launch_bounds__(256) void k_mtrans(const float* __restrict__ M,
                                                short* __restrict__ Mt)
{
    __shared__ __align__(16) short Ts[64][136];
    int tid = threadIdx.x;
    int n0 = blockIdx.x * 64;
    for (int p = 0; p < 32; p++) {
        int idx = p * 256 + tid;
        int k = idx >> 6, nn = idx & 63;
        Ts[nn][k] = (short)f2bf(M[(size_t)k * 16384 + n0 + nn]);
    }
    __syncthreads();
    for (int p = 0; p < 4; p++) {
        int idx = p * 256 + tid;
        int nn = idx >> 4, s = idx & 15;
        *(int4*)&Mt[(size_t)(n0 + nn) * 128 + s * 8] = *(const int4*)&Ts[nn][s * 8];
    }
}

// ---------------- hb (bf16) <- h (fp32) ----------------
__global__ __launch_bounds__(256) void k_convh(const float* __restrict__ h,
                                               short* __restrict__ hb)
{
    int idx = (blockIdx.x * 256 + threadIdx.x) * 4;
    float4 v = *(const float4*)&h[idx];
    short4 o;
    o.x = (short)f2bf(v.x); o.y = (short)f2bf(v.y);
    o.z = (short)f2bf(v.z); o.w = (short)f2bf(v.w);
    *(short4*)&hb[idx] = o;
}

// ---------------- phase1 MFMA: U[i][n] = sum_k hb[i,k] * Mt[n,k] ----------------
__global__ __launch_bounds__(256) void k_p1(const short* __restrict__ hb,
    const short* __restrict__ Mt, short* __restrict__ U)
{
    __shared__ __align__(16) short As[128][72];
    __shared__ __align__(16) short Bs[128][72];
    int tid = threadIdx.x;
    int n0 = blockIdx.x * 128;
    int i0 = blockIdx.y * 128;
    int w = tid >> 6, lane = tid & 63, c = lane & 15, g = lane >> 4;
    f32x4 acc[2][8] = {};
    for (int kh = 0; kh < 2; kh++) {
        __syncthreads();
        for (int idx = tid; idx < 1024; idx += 256) {
            int r = idx >> 3, s = idx & 7;
            *(int4*)&As[r][s * 8] = *(const int4*)&hb[(i0 + r) * 128 + kh * 64 + s * 8];
            *(int4*)&Bs[r][s * 8] = *(const int4*)&Mt[(size_t)(n0 + r) * 128 + kh * 64 + s * 8];
        }
        __syncthreads();
#pragma unroll
        for (int kk = 0; kk < 2; kk++) {
            int ko = kk * 32 + g * 8;
            bf16x8 a0 = *(const bf16x8*)&As[w * 32 + c][ko];
            bf16x8 a1 = *(const bf16x8*)&As[w * 32 + 16 + c][ko];
#pragma unroll
            for (int nt = 0; nt < 8; nt++) {
                bf16x8 b = *(const bf16x8*)&Bs[nt * 16 + c][ko];
                acc[0][nt] = __builtin_amdgcn_mfma_f32_16x16x32_bf16(a0, b, acc[0][nt], 0, 0, 0);
                acc[1][nt] = __builtin_amdgcn_mfma_f32_16x16x32_bf16(a1, b, acc[1][nt], 0, 0, 0);
            }
        }
    }
#pragma unroll
    for (int it = 0; it < 2; it++)
#pragma unroll
        for (int nt = 0; nt < 8; nt++)
#pragma unroll
            for (int r = 0; r < 4; r++) {
                int i = i0 + w * 32 + it * 16 + g * 4 + r;
                int n = n0 + nt * 16 + c;
                U[(size_t)i * 16384 + n] = (short)f2bf(acc[it][nt][r]);
            }
}

// ---------------- phase2 MFMA (merged j): D[m][j] = sum_l U[m,l] H[j,l], all 256 j ------
__global__ __launch_bounds__(256) void k_p2(const short* __restrict__ hb,
    const short* __restrict__ U, const float* __restrict__ cvec,
    const float* __restrict__ Wm2, const float* __restrict__ bm2,
    float* __restrict__ out)
{
    __shared__ __align__(16) short Hs[256][72];
    __shared__ __align__(16) short Us[128][72];
    __shared__ float cvs[128];
    __shared__ float w2s[128][4];
    int tid = threadIdx.x;
    int i = blockIdx.x;
    int b = i >> 8;
    int w = tid >> 6, lane = tid & 63, c = lane & 15, g = lane >> 4;
    if (tid < 128) {
        cvs[tid] = cvec[tid];
        *(float4*)&w2s[tid][0] = *(const float4*)&Wm2[tid * 4];
    }
    f32x4 acc[4][8] = {};
    for (int kh = 0; kh < 2; kh++) {
        __syncthreads();
        for (int idx = tid; idx < 2048; idx += 256) {
            int r = idx >> 3, s = idx & 7;
            *(int4*)&Hs[r][s * 8] = *(const int4*)&hb[(b * 256 + r) * 128 + kh * 64 + s * 8];
        }
        for (int idx = tid; idx < 1024; idx += 256) {
            int r = idx >> 3, s = idx & 7;
            *(int4*)&Us[r][s * 8] = *(const int4*)&U[(size_t)i * 16384 + r * 128 + kh * 64 + s * 8];
        }
        __syncthreads();
#pragma unroll
        for (int kk = 0; kk < 2; kk++) {
            int ko = kk * 32 + g * 8;
            bf16x8 hj[4];
#pragma unroll
            for (int jt = 0; jt < 4; jt++)
                hj[jt] = *(const bf16x8*)&Hs[w * 64 + jt * 16 + c][ko];
#pragma unroll
            for (int mt = 0; mt < 8; mt++) {
                bf16x8 uv = *(const bf16x8*)&Us[mt * 16 + c][ko];
#pragma unroll
                for (int jt = 0; jt < 4; jt++)
                    acc[jt][mt] = __builtin_amdgcn_mfma_f32_16x16x32_bf16(uv, hj[jt], acc[jt][mt], 0, 0, 0);
            }
        }
    }
    // lane holds: j = w*64 + jt*16 + c, m = mt*16 + g*4 + r
    float4 bmv = *(const float4*)&bm2[0];
#pragma unroll
    for (int jt = 0; jt < 4; jt++) {
        float p0 = 0.f, p1 = 0.f, p2 = 0.f, p3 = 0.f;
#pragma unroll
        for (int mt = 0; mt < 8; mt++) {
#pragma unroll
            for (int r = 0; r < 4; r++) {
                int m = mt * 16 + g * 4 + r;
                float y = acc[jt][mt][r] + cvs[m];
                float sv = y * frcp(1.f + __expf(-y));
                p0 += sv * w2s[m][0]; p1 += sv * w2s[m][1];
                p2 += sv * w2s[m][2]; p3 += sv * w2s[m][3];
            }
        }
        p0 += __shfl_xor(p0, 16, 64); p1 += __shfl_xor(p1, 16, 64);
        p2 += __shfl_xor(p2, 16, 64); p3 += __shfl_xor(p3, 16, 64);
        p0 += __shfl_xor(p0, 32, 64); p1 += __shfl_xor(p1, 32, 64);
        p2 += __shfl_xor(p2, 32, 64); p3 += __shfl_xor(p3, 32, 64);
        if (g == 0) {
            int j = w * 64 + jt * 16 + c;
            float4 o4 = { p0 + bmv.x, p1 + bmv.y, p2 + bmv.z, p3 + bmv.w };
            *(float4*)&out[((size_t)i * 256 + j) * 4] = o4;
        }
    }
}

extern "C" void kernel_launch(void* const* d_in, const int* in_sizes, int n_in,
                              void* d_out, int out_size, void* d_ws, size_t ws_size,
                              hipStream_t stream)
{
    const float* x   = (const float*)d_in[0];
    const int*   ei  = (const int*)d_in[1];
    const void*  tptr= d_in[3];
    const float* tm  = (const float*)d_in[4];
    const float* Wn  = (const float*)d_in[5];
    const float* bn  = (const float*)d_in[6];
    const float* Wee = (const float*)d_in[7];
    const float* bee = (const float*)d_in[8];
    const float* Wt1 = (const float*)d_in[9];
    const float* bt1 = (const float*)d_in[10];
    const float* Wt2 = (const float*)d_in[11];
    const float* bt2 = (const float*)d_in[12];
    const float* Wa  = (const float*)d_in[13];
    const float* ba  = (const float*)d_in[14];
    const float* Wq  = (const float*)d_in[15];
    const float* bq  = (const float*)d_in[16];
    const float* Wk  = (const float*)d_in[17];
    const float* bk  = (const float*)d_in[18];
    const float* Wv  = (const float*)d_in[19];
    const float* bv  = (const float*)d_in[20];
    const float* We  = (const float*)d_in[21];
    const float* Wsk = (const float*)d_in[22];
    const float* bsk = (const float*)d_in[23];
    const float* Wf1 = (const float*)d_in[24];
    const float* bf1 = (const float*)d_in[25];
    const float* Wf2 = (const float*)d_in[26];
    const float* bf2 = (const float*)d_in[27];
    const float* Wb  = (const float*)d_in[28];
    const float* bb  = (const float*)d_in[29];
    const float* Wm1 = (const float*)d_in[30];
    const float* bm1 = (const float*)d_in[31];
    const float* Wm2 = (const float*)d_in[32];
    const float* bm2 = (const float*)d_in[33];
    float* out = (float*)d_out;
    float* ws = (float*)d_ws;

    float* h    = ws + OFF_H;
    float* qb   = ws + OFF_Q;
    float* kb   = ws + OFF_K;
    float* vb   = ws + OFF_V;
    float* skp  = ws + OFF_SKP;
    float* ss   = ws + OFF_SS;
    float* ea   = ws + OFF_EA;
    float* cvec = ws + OFF_CVEC;
    int* iws    = (int*)(ws + OFF_INT);
    int* deg    = iws;
    int* cursor = iws + 1024;
    int* rowptr = iws + 2048;
    int* eorder = iws + 3073;
    float* Mst  = ws + OFF_M;
    short* Ub   = (short*)(ws + OFF_U);
    short* Mtb  = (short*)(ws + OFF_MT);
    short* hbb  = (short*)(ws + OFF_HB);
    float* tmod = ws + OFF_TMOD;

    hipMemsetAsync(deg, 0, 2048 * sizeof(int), stream);
    k_tmod<<<1, 128, 0, stream>>>(tptr, Wt1, bt1, Wt2, bt2, bb, Wm1, bm1, tmod, cvec);
    k_ss<<<12, 256, 0, stream>>>(tmod, Wa, ba, ss);
    k_input<<<512, 256, 0, stream>>>(x, Wn, bn, h);
    k_edge<<<256, 256, 0, stream>>>(ei, tm, Wee, bee, ea);
    k_count<<<256, 256, 0, stream>>>(ei, deg);
    k_scan<<<1, 1024, 0, stream>>>(deg, rowptr);
    k_scatter<<<256, 256, 0, stream>>>(ei, rowptr, cursor, eorder);
    k_sort2<<<1024, 128, 0, stream>>>(rowptr, eorder);

    for (int l = 0; l < LAYERS; l++) {
        const float* ssl = ss + l * 512;
        k_qkvs<<<dim3(64, 4), 256, 0, stream>>>(h, ssl,
            Wq + l * 16384, Wk + l * 16384, Wv + l * 16384, Wsk + l * 16384,
            bq + l * 128, bk + l * 128, bv + l * 128, bsk + l * 128,
            qb, kb, vb, skp);
        k_attn<<<1024, 64, 0, stream>>>(qb, kb, vb, skp, h, ei, ea, We + l * 128, rowptr, eorder);
        k_ffn<<<64, 512, 0, stream>>>(h, Wf1 + l * 32768, bf1 + l * 256,
                                      Wf2 + l * 32768, bf2 + l * 128, ssl + 256, ssl + 384);
    }

    k_mprep<<<128, 256, 0, stream>>>(Wb, Wm1, Mst);
    k_mtrans<<<256, 256, 0, stream>>>(Mst, Mtb);
    k_convh<<<128, 256, 0, stream>>>(h, hbb);
    k_p1<<<dim3(128, 8), 256, 0, stream>>>(hbb, Mtb, Ub);
    k_p2<<<1024, 256, 0, stream>>>(hbb, Ub, cvec, Wm2, bm2, out);
}

// Round 7
// 475.847 us; speedup vs baseline: 3.1793x; 1.1538x over previous
//
#include <hip/hip_runtime.h>
#include <math.h>

#define N_NODES 1024
#define HDIM 128
#define EDGES 65536
#define LAYERS 6

typedef __attribute__((ext_vector_type(8))) short bf16x8;
typedef __attribute__((ext_vector_type(4))) float f32x4;

// workspace float offsets
#define OFF_H     0
#define OFF_Q     131072
#define OFF_K     262144
#define OFF_V     393216
#define OFF_SKP   524288
#define OFF_G     655360       // reused: src_csr (int E) + ea_csr (float E)
#define OFF_SS    917504
#define OFF_EA    920576
#define OFF_CVEC  986112
#define OFF_INT   986240
#define OFF_M     1054912      // fp32 M [128 k][16384 n], n = m*128 + l  (m-outer!)
#define OFF_U     3152064      // bf16 U [1024 i][16384 n]   (8,388,608 floats)
#define OFF_MT    11540672     // bf16 Mt [16384 n][128 k]   (1,048,576 floats)
#define OFF_HB    12589248     // bf16 hb [1024][128]        (65,536 floats)
#define OFF_TMOD  12654784     // fp32 tmod [128]

__device__ __forceinline__ float silu_f(float x) { return x / (1.f + expf(-x)); }
__device__ __forceinline__ float frcp(float x) { return __builtin_amdgcn_rcpf(x); }

__device__ __forceinline__ unsigned short f2bf(float f) {
    unsigned int u = __float_as_uint(f);
    u += 0x7FFFu + ((u >> 16) & 1u);
    return (unsigned short)(u >> 16);
}

// ---------------- tiny serial setup: emb -> t_mod, cvec ----------------
__global__ __launch_bounds__(128) void k_tmod(const void* tptr,
    const float* __restrict__ Wt1, const float* __restrict__ bt1,
    const float* __restrict__ Wt2, const float* __restrict__ bt2,
    const float* __restrict__ bb, const float* __restrict__ Wm1, const float* __restrict__ bm1,
    float* __restrict__ tmod_g, float* __restrict__ cvec)
{
    __shared__ float emb_s[256];
    __shared__ float tmp1_s[128];
    int tid = threadIdx.x;
    int iv = *(const int*)tptr;
    float fv = __int_as_float(iv);
    float tval = (iv > -1000000 && iv < 1000000) ? (float)iv : fv;
    {
        float fr = expf(-logf(10000.f) * (float)tid / 128.f);
        float ta = tval * fr;
        emb_s[tid] = cosf(ta);
        emb_s[128 + tid] = sinf(ta);
    }
    __syncthreads();
    {
        float a = bt1[tid];
#pragma unroll 4
        for (int i = 0; i < 256; i++) a += emb_s[i] * Wt1[i * 128 + tid];
        tmp1_s[tid] = silu_f(a);
    }
    __syncthreads();
    {
        float a = bt2[tid];
#pragma unroll 4
        for (int i = 0; i < 128; i++) a += tmp1_s[i] * Wt2[i * 128 + tid];
        tmod_g[tid] = silu_f(a);   // t_mod = silu(t_emb)
    }
    {
        float a = bm1[tid];
#pragma unroll 4
        for (int o = 0; o < 128; o++) a += bb[o] * Wm1[o * 128 + tid];
        cvec[tid] = a;
    }
}

// ---------------- parallel ss projection ----------------
__global__ __launch_bounds__(256) void k_ss(const float* __restrict__ tmod_g,
    const float* __restrict__ Wa, const float* __restrict__ ba, float* __restrict__ ss_all)
{
    __shared__ float tm_s[128];
    int tid = threadIdx.x;
    if (tid < 128) tm_s[tid] = tmod_g[tid];
    __syncthreads();
    int idx = blockIdx.x * 256 + tid;       // < 3072
    int l = idx >> 9, j = idx & 511;
    float a = ba[l * 512 + j];
    const float* w = Wa + l * 65536 + j;
#pragma unroll 4
    for (int k = 0; k < 128; k++) a += tm_s[k] * w[k * 512];
    ss_all[idx] = a;
}

// ---------------- h = x @ Wn + bn  (K=5) ----------------
__global__ __launch_bounds__(256) void k_input(const float* __restrict__ x,
    const float* __restrict__ Wn, const float* __restrict__ bn, float* __restrict__ h)
{
    int idx = blockIdx.x * 256 + threadIdx.x;  // < 131072
    int i = idx >> 7, j = idx & 127;
    float acc = bn[j];
#pragma unroll
    for (int kk = 0; kk < 5; kk++) acc += x[i * 5 + kk] * Wn[kk * 128 + j];
    h[idx] = acc;
}

// ---------------- edge_attr ----------------
__global__ __launch_bounds__(256) void k_edge(const int* __restrict__ ei,
    const float* __restrict__ tm, const float* __restrict__ Wee, const float* __restrict__ bee,
    float* __restrict__ ea)
{
    int e = blockIdx.x * 256 + threadIdx.x;
    int s = ei[e], d = ei[EDGES + e];
    ea[e] = tm[s * N_NODES + d] * Wee[0] + bee[0];
}

// ---------------- CSR build ----------------
__global__ __launch_bounds__(256) void k_count(const int* __restrict__ ei, int* __restrict__ deg)
{
    int e = blockIdx.x * 256 + threadIdx.x;
    atomicAdd(&deg[ei[EDGES + e]], 1);
}

__global__ __launch_bounds__(1024) void k_scan(const int* __restrict__ deg, int* __restrict__ rowptr)
{
    __shared__ int tmp[1024];
    int tid = threadIdx.x;
    tmp[tid] = deg[tid];
    __syncthreads();
    for (int off = 1; off < 1024; off <<= 1) {
        int vv = (tid >= off) ? tmp[tid - off] : 0;
        __syncthreads();
        tmp[tid] += vv;
        __syncthreads();
    }
    rowptr[tid + 1] = tmp[tid];
    if (tid == 0) rowptr[0] = 0;
}

__global__ __launch_bounds__(256) void k_scatter(const int* __restrict__ ei,
    const int* __restrict__ rowptr, int* __restrict__ cursor, int* __restrict__ eorder)
{
    int e = blockIdx.x * 256 + threadIdx.x;
    int d = ei[EDGES + e];
    int pos = atomicAdd(&cursor[d], 1);
    eorder[rowptr[d] + pos] = e;
}

// ---------------- per-node bitonic sort of edge ids in LDS ----------------
__global__ __launch_bounds__(128) void k_sort2(const int* __restrict__ rowptr,
                                               int* __restrict__ eorder)
{
    __shared__ int key[256];
    int node = blockIdx.x;
    int tid = threadIdx.x;
    int beg = rowptr[node], end = rowptr[node + 1];
    int n = end - beg;
    if (n <= 256) {
        for (int i = tid; i < 256; i += 128) key[i] = (i < n) ? eorder[beg + i] : 0x7FFFFFFF;
        __syncthreads();
        for (int k = 2; k <= 256; k <<= 1) {
            for (int j = k >> 1; j > 0; j >>= 1) {
                int i = ((tid / j) * 2 * j) + (tid % j);
                int l = i + j;
                bool up = ((i & k) == 0);
                int a = key[i], b = key[l];
                if ((a > b) == up) { key[i] = b; key[l] = a; }
                __syncthreads();
            }
        }
        for (int i = tid; i < n; i += 128) eorder[beg + i] = key[i];
    } else if (tid == 0) {
        for (int i = beg + 1; i < end; ++i) {
            int kk = eorder[i];
            int j = i - 1;
            while (j >= beg && eorder[j] > kk) { eorder[j + 1] = eorder[j]; --j; }
            eorder[j + 1] = kk;
        }
    }
}

// ---------------- flatten CSR gather arrays: src_csr[t], ea_csr[t] ----------------
__global__ __launch_bounds__(256) void k_flat(const int* __restrict__ ei,
    const float* __restrict__ ea, const int* __restrict__ eorder,
    int* __restrict__ src_csr, float* __restrict__ ea_csr)
{
    int t = blockIdx.x * 256 + threadIdx.x;
    int e = eorder[t];
    src_csr[t] = ei[e];
    ea_csr[t] = ea[e];
}

// ---------------- fused LN+mod + 4x GEMM (q,k,v,skip) ----------------
__global__ __launch_bounds__(256) void k_qkvs(const float* __restrict__ h,
    const float* __restrict__ ss,
    const float* __restrict__ Wq, const float* __restrict__ Wk,
    const float* __restrict__ Wv, const float* __restrict__ Wsk,
    const float* __restrict__ bq, const float* __restrict__ bk,
    const float* __restrict__ bv, const float* __restrict__ bsk,
    float* __restrict__ q, float* __restrict__ k, float* __restrict__ v, float* __restrict__ skp)
{
    __shared__ float a[16][128];
    __shared__ float mu_s[16], rs_s[16];
    int tid = threadIdx.x;
    int r0 = blockIdx.x * 16;
    for (int idx = tid; idx < 2048; idx += 256) a[idx >> 7][idx & 127] = h[r0 * 128 + idx];
    __syncthreads();
    if (tid < 16) {
        float s = 0.f, s2 = 0.f;
        for (int c = 0; c < 128; c++) { float xx = a[tid][c]; s += xx; s2 += xx * xx; }
        float mu = s * (1.f / 128.f);
        float var = s2 * (1.f / 128.f) - mu * mu;
        mu_s[tid] = mu; rs_s[tid] = rsqrtf(var + 1e-5f);
    }
    __syncthreads();
    const float* sh = ss; const float* sc = ss + 128;
    for (int idx = tid; idx < 2048; idx += 256) {
        int r = idx >> 7, c = idx & 127;
        a[r][c] = (a[r][c] - mu_s[r]) * rs_s[r] * (1.f + sc[c]) + sh[c];
    }
    __syncthreads();
    const float* W; const float* bias; float* out;
    switch (blockIdx.y) {
        case 0:  W = Wq;  bias = bq;  out = q;   break;
        case 1:  W = Wk;  bias = bk;  out = k;   break;
        case 2:  W = Wv;  bias = bv;  out = v;   break;
        default: W = Wsk; bias = bsk; out = skp; break;
    }
    int col = tid & 127, grp = tid >> 7;
    float acc[8] = {};
    for (int kk = 0; kk < 128; ++kk) {
        float bvv = W[kk * 128 + col];
#pragma unroll
        for (int rr = 0; rr < 8; rr++) acc[rr] += a[grp * 8 + rr][kk] * bvv;
    }
#pragma unroll
    for (int rr = 0; rr < 8; rr++)
        out[(r0 + grp * 8 + rr) * 128 + col] = acc[rr] + bias[col];
}

// ---------------- fused FFN: LN+mod -> f1 -> gelu -> f2 -> residual add ----------------
__global__ __launch_bounds__(512) void k_ffn(float* __restrict__ h,
    const float* __restrict__ Wf1, const float* __restrict__ bf1,
    const float* __restrict__ Wf2, const float* __restrict__ bf2,
    const float* __restrict__ sh, const float* __restrict__ sc)
{
    __shared__ float a[16][128];
    __shared__ float gbuf[16][257];
    __shared__ float mu_s[16], rs_s[16];
    int tid = threadIdx.x;
    int r0 = blockIdx.x * 16;
    for (int idx = tid; idx < 2048; idx += 512) a[idx >> 7][idx & 127] = h[r0 * 128 + idx];
    __syncthreads();
    if (tid < 16) {
        float s = 0.f, s2 = 0.f;
        for (int c = 0; c < 128; c++) { float xx = a[tid][c]; s += xx; s2 += xx * xx; }
        float mu = s * (1.f / 128.f);
        float var = s2 * (1.f / 128.f) - mu * mu;
        mu_s[tid] = mu; rs_s[tid] = rsqrtf(var + 1e-5f);
    }
    __syncthreads();
    for (int idx = tid; idx < 2048; idx += 512) {
        int r = idx >> 7, c = idx & 127;
        a[r][c] = (a[r][c] - mu_s[r]) * rs_s[r] * (1.f + sc[c]) + sh[c];
    }
    __syncthreads();
    {   // f1 + gelu
        int col = tid & 255, grp = tid >> 8;   // grp 0..1
        float acc[8] = {};
        for (int k = 0; k < 128; ++k) {
            float wv = Wf1[k * 256 + col];
#pragma unroll
            for (int rr = 0; rr < 8; rr++) acc[rr] += a[grp * 8 + rr][k] * wv;
        }
        float bv = bf1[col];
#pragma unroll
        for (int rr = 0; rr < 8; rr++) {
            float y = acc[rr] + bv;
            gbuf[grp * 8 + rr][col] = 0.5f * y * (1.f + erff(y * 0.70710678118654752f));
        }
    }
    __syncthreads();
    {   // f2 + residual
        int col = tid & 127, grp = tid >> 7;   // grp 0..3
        float acc[4] = {};
        for (int k = 0; k < 256; ++k) {
            float wv = Wf2[k * 128 + col];
#pragma unroll
            for (int rr = 0; rr < 4; rr++) acc[rr] += gbuf[grp * 4 + rr][k] * wv;
        }
        float bv = bf2[col];
#pragma unroll
        for (int rr = 0; rr < 4; rr++)
            h[(r0 + grp * 4 + rr) * 128 + col] += acc[rr] + bv;
    }
}

// ---------------- attention: one wave per dst node, 4-wide unrolled online softmax -----
__global__ __launch_bounds__(64) void k_attn(const float* __restrict__ q,
    const float* __restrict__ k, const float* __restrict__ v,
    const float* __restrict__ skp, float* __restrict__ h,
    const int* __restrict__ src_csr, const float* __restrict__ ea_csr,
    const float* __restrict__ We_l, const int* __restrict__ rowptr)
{
    int node = blockIdx.x;
    int lane = threadIdx.x;
    int c0 = lane * 2;
    float2 q2 = *(const float2*)&q[node * 128 + c0];
    float we0 = We_l[c0], we1 = We_l[c0 + 1];
    int beg = rowptr[node], end = rowptr[node + 1];
    float m = -INFINITY, s = 0.f, a0 = 0.f, a1 = 0.f;
    const float isc = 0.17677669529663687f;  // 1/sqrt(32)

    int t = beg;
    for (; t + 3 < end; t += 4) {
        int sn0 = src_csr[t],     sn1 = src_csr[t + 1];
        int sn2 = src_csr[t + 2], sn3 = src_csr[t + 3];
        float e0 = ea_csr[t],     e1 = ea_csr[t + 1];
        float e2 = ea_csr[t + 2], e3 = ea_csr[t + 3];
        float2 k0 = *(const float2*)&k[sn0 * 128 + c0];
        float2 k1 = *(const float2*)&k[sn1 * 128 + c0];
        float2 k2 = *(const float2*)&k[sn2 * 128 + c0];
        float2 k3 = *(const float2*)&k[sn3 * 128 + c0];
        float2 v0 = *(const float2*)&v[sn0 * 128 + c0];
        float2 v1 = *(const float2*)&v[sn1 * 128 + c0];
        float2 v2 = *(const float2*)&v[sn2 * 128 + c0];
        float2 v3 = *(const float2*)&v[sn3 * 128 + c0];
        float p0 = q2.x * (k0.x + e0 * we0) + q2.y * (k0.y + e0 * we1);
        float p1 = q2.x * (k1.x + e1 * we0) + q2.y * (k1.y + e1 * we1);
        float p2 = q2.x * (k2.x + e2 * we0) + q2.y * (k2.y + e2 * we1);
        float p3 = q2.x * (k3.x + e3 * we0) + q2.y * (k3.y + e3 * we1);
        p0 += __shfl_xor(p0, 1, 16); p1 += __shfl_xor(p1, 1, 16);
        p2 += __shfl_xor(p2, 1, 16); p3 += __shfl_xor(p3, 1, 16);
        p0 += __shfl_xor(p0, 2, 16); p1 += __shfl_xor(p1, 2, 16);
        p2 += __shfl_xor(p2, 2, 16); p3 += __shfl_xor(p3, 2, 16);
        p0 += __shfl_xor(p0, 4, 16); p1 += __shfl_xor(p1, 4, 16);
        p2 += __shfl_xor(p2, 4, 16); p3 += __shfl_xor(p3, 4, 16);
        p0 += __shfl_xor(p0, 8, 16); p1 += __shfl_xor(p1, 8, 16);
        p2 += __shfl_xor(p2, 8, 16); p3 += __shfl_xor(p3, 8, 16);
        {
            float al = p0 * isc;
            float mn = fmaxf(m, al);
            float scale = __expf(m - mn);
            float wq = __expf(al - mn);
            s = s * scale + wq;
            a0 = a0 * scale + wq * (v0.x + e0 * we0);
            a1 = a1 * scale + wq * (v0.y + e0 * we1);
            m = mn;
        }
        {
            float al = p1 * isc;
            float mn = fmaxf(m, al);
            float scale = __expf(m - mn);
            float wq = __expf(al - mn);
            s = s * scale + wq;
            a0 = a0 * scale + wq * (v1.x + e1 * we0);
            a1 = a1 * scale + wq * (v1.y + e1 * we1);
            m = mn;
        }
        {
            float al = p2 * isc;
            float mn = fmaxf(m, al);
            float scale = __expf(m - mn);
            float wq = __expf(al - mn);
            s = s * scale + wq;
            a0 = a0 * scale + wq * (v2.x + e2 * we0);
            a1 = a1 * scale + wq * (v2.y + e2 * we1);
            m = mn;
        }
        {
            float al = p3 * isc;
            float mn = fmaxf(m, al);
            float scale = __expf(m - mn);
            float wq = __expf(al - mn);
            s = s * scale + wq;
            a0 = a0 * scale + wq * (v3.x + e3 * we0);
            a1 = a1 * scale + wq * (v3.y + e3 * we1);
            m = mn;
        }
    }
    for (; t < end; ++t) {
        int sn = src_csr[t];
        float eav = ea_csr[t];
        float2 kv = *(const float2*)&k[sn * 128 + c0];
        float2 vv = *(const float2*)&v[sn * 128 + c0];
        float part = q2.x * (kv.x + eav * we0) + q2.y * (kv.y + eav * we1);
        part += __shfl_xor(part, 1, 16);
        part += __shfl_xor(part, 2, 16);
        part += __shfl_xor(part, 4, 16);
        part += __shfl_xor(part, 8, 16);
        float alpha = part * isc;
        float mn = fmaxf(m, alpha);
        float scale = __expf(m - mn);
        float wq = __expf(alpha - mn);
        s = s * scale + wq;
        a0 = a0 * scale + wq * (vv.x + eav * we0);
        a1 = a1 * scale + wq * (vv.y + eav * we1);
        m = mn;
    }
    float inv = 1.f / (s + 1e-16f);
    int o = node * 128 + c0;
    h[o]     += skp[o]     + a0 * inv;
    h[o + 1] += skp[o + 1] + a1 * inv;
}

// ---------------- M[k][m*128+l] = sum_o Wb[o,k,l] * Wm1[o,m]  (m-outer layout!) --------
__global__ __launch_bounds__(256) void k_mprep(const float* __restrict__ Wb,
    const float* __restrict__ Wm1, float* __restrict__ M)
{
    __shared__ float wb_s[64][128];
    __shared__ float wm_s[64][128];
    int tid = threadIdx.x;
    int k = blockIdx.x;
    int mg = tid & 15, lg = tid >> 4;
    int m0 = mg * 8, l0 = lg * 8;
    float acc[8][8] = {};
    for (int oh = 0; oh < 2; ++oh) {
        __syncthreads();
        for (int idx = tid; idx < 8192; idx += 256) {
            int o = idx >> 7, c = idx & 127;
            wb_s[o][c] = Wb[(size_t)(oh * 64 + o) * 16384 + k * 128 + c];
            wm_s[o][c] = Wm1[(oh * 64 + o) * 128 + c];
        }
        __syncthreads();
        for (int o = 0; o < 64; o++) {
            float lv[8], mv[8];
#pragma unroll
            for (int i = 0; i < 8; i++) { lv[i] = wb_s[o][l0 + i]; mv[i] = wm_s[o][m0 + i]; }
#pragma unroll
            for (int li = 0; li < 8; li++)
#pragma unroll
                for (int mi = 0; mi < 8; mi++) acc[li][mi] += lv[li] * mv[mi];
        }
    }
    for (int mi = 0; mi < 8; mi++)
        for (int li = 0; li < 8; li++)
            M[(size_t)k * 16384 + (m0 + mi) * 128 + (l0 + li)] = acc[li][mi];
}

// ---------------- Mt[n][k] (bf16) <- M[k][n] (fp32) ----------------
__global__ __launch_bounds__(256) void k_mtrans(const float* __restrict__ M,
                                                short* __restrict__ Mt)
{
    __shared__ __align__(16) short Ts[64][136];
    int tid = threadIdx.x;
    int n0 = blockIdx.x * 64;
    for (int p = 0; p < 32; p++) {
        int idx = p * 256 + tid;
        int k = idx >> 6, nn = idx & 63;
        Ts[nn][k] = (short)f2bf(M[(size_t)k * 16384 + n0 + nn]);
    }
    __syncthreads();
    for (int p = 0; p < 4; p++) {
        int idx = p * 256 + tid;
        int nn = idx >> 4, s = idx & 15;
        *(int4*)&Mt[(size_t)(n0 + nn) * 128 + s * 8] = *(const int4*)&Ts[nn][s * 8];
    }
}

// ---------------- hb (bf16) <- h (fp32) ----------------
__global__ __launch_bounds__(256) void k_convh(const float* __restrict__ h,
                                               short* __restrict__ hb)
{
    int idx = (blockIdx.x * 256 + threadIdx.x) * 4;
    float4 v = *(const float4*)&h[idx];
    short4 o;
    o.x = (short)f2bf(v.x); o.y = (short)f2bf(v.y);
    o.z = (short)f2bf(v.z); o.w = (short)f2bf(v.w);
    *(short4*)&hb[idx] = o;
}

// ---------------- phase1 MFMA: U[i][n] = sum_k hb[i,k] * Mt[n,k] ----------------
__global__ __launch_bounds__(256) void k_p1(const short* __restrict__ hb,
    const short* __restrict__ Mt, short* __restrict__ U)
{
    __shared__ __align__(16) short As[128][72];
    __shared__ __align__(16) short Bs[128][72];
    int tid = threadIdx.x;
    int n0 = blockIdx.x * 128;
    int i0 = blockIdx.y * 128;
    int w = tid >> 6, lane = tid & 63, c = lane & 15, g = lane >> 4;
    f32x4 acc[2][8] = {};
    for (int kh = 0; kh < 2; kh++) {
        __syncthreads();
        for (int idx = tid; idx < 1024; idx += 256) {
            int r = idx >> 3, s = idx & 7;
            *(int4*)&As[r][s * 8] = *(const int4*)&hb[(i0 + r) * 128 + kh * 64 + s * 8];
            *(int4*)&Bs[r][s * 8] = *(const int4*)&Mt[(size_t)(n0 + r) * 128 + kh * 64 + s * 8];
        }
        __syncthreads();
#pragma unroll
        for (int kk = 0; kk < 2; kk++) {
            int ko = kk * 32 + g * 8;
            bf16x8 a0 = *(const bf16x8*)&As[w * 32 + c][ko];
            bf16x8 a1 = *(const bf16x8*)&As[w * 32 + 16 + c][ko];
#pragma unroll
            for (int nt = 0; nt < 8; nt++) {
                bf16x8 b = *(const bf16x8*)&Bs[nt * 16 + c][ko];
                acc[0][nt] = __builtin_amdgcn_mfma_f32_16x16x32_bf16(a0, b, acc[0][nt], 0, 0, 0);
                acc[1][nt] = __builtin_amdgcn_mfma_f32_16x16x32_bf16(a1, b, acc[1][nt], 0, 0, 0);
            }
        }
    }
#pragma unroll
    for (int it = 0; it < 2; it++)
#pragma unroll
        for (int nt = 0; nt < 8; nt++)
#pragma unroll
            for (int r = 0; r < 4; r++) {
                int i = i0 + w * 32 + it * 16 + g * 4 + r;
                int n = n0 + nt * 16 + c;
                U[(size_t)i * 16384 + n] = (short)f2bf(acc[it][nt][r]);
            }
}

// ---------------- phase2 MFMA: block = (i, j-half); U_i staged once; H frags from L2 ---
__global__ __launch_bounds__(256) void k_p2(const short* __restrict__ hb,
    const short* __restrict__ U, const float* __restrict__ cvec,
    const float* __restrict__ Wm2, const float* __restrict__ bm2,
    float* __restrict__ out)
{
    __shared__ __align__(16) short Us[128][136];
    __shared__ float cvs[128];
    __shared__ float w2s[128][4];
    int tid = threadIdx.x;
    int i = blockIdx.x;
    int jb = blockIdx.y;          // 0..1
    int b = i >> 8;
    int w = tid >> 6, lane = tid & 63, c = lane & 15, g = lane >> 4;
    if (tid < 128) {
        cvs[tid] = cvec[tid];
        *(float4*)&w2s[tid][0] = *(const float4*)&Wm2[tid * 4];
    }
    // preload the 8 H fragments this wave needs (hb is L2-resident, 256KB)
    bf16x8 hf[2][4];
    {
        const short* hrow = hb + (size_t)(b * 256 + jb * 128 + w * 32 + c) * 128;
#pragma unroll
        for (int jt = 0; jt < 2; jt++)
#pragma unroll
            for (int kq = 0; kq < 4; kq++)
                hf[jt][kq] = *(const bf16x8*)(hrow + jt * 16 * 128 + kq * 32 + g * 8);
    }
    // stage full U_i once: [128 m][128 l]
    for (int idx = tid; idx < 2048; idx += 256) {
        int r = idx >> 4, s = idx & 15;
        *(int4*)&Us[r][s * 8] = *(const int4*)&U[(size_t)i * 16384 + r * 128 + s * 8];
    }
    __syncthreads();
    f32x4 acc[2][8] = {};
#pragma unroll
    for (int kq = 0; kq < 4; kq++) {
        int ko = kq * 32 + g * 8;
#pragma unroll
        for (int mt = 0; mt < 8; mt++) {
            bf16x8 uv = *(const bf16x8*)&Us[mt * 16 + c][ko];
            acc[0][mt] = __builtin_amdgcn_mfma_f32_16x16x32_bf16(uv, hf[0][kq], acc[0][mt], 0, 0, 0);
            acc[1][mt] = __builtin_amdgcn_mfma_f32_16x16x32_bf16(uv, hf[1][kq], acc[1][mt], 0, 0, 0);
        }
    }
    // lane holds: j = jb*128 + w*32 + jt*16 + c, m = mt*16 + g*4 + r
    float4 bmv = *(const float4*)&bm2[0];
#pragma unroll
    for (int jt = 0; jt < 2; jt++) {
        float p0 = 0.f, p1 = 0.f, p2 = 0.f, p3 = 0.f;
#pragma unroll
        for (int mt = 0; mt < 8; mt++) {
#pragma unroll
            for (int r = 0; r < 4; r++) {
                int m = mt * 16 + g * 4 + r;
                float y = acc[jt][mt][r] + cvs[m];
                float sv = y * frcp(1.f + __expf(-y));
                p0 += sv * w2s[m][0]; p1 += sv * w2s[m][1];
                p2 += sv * w2s[m][2]; p3 += sv * w2s[m][3];
            }
        }
        p0 += __shfl_xor(p0, 16, 64); p1 += __shfl_xor(p1, 16, 64);
        p2 += __shfl_xor(p2, 16, 64); p3 += __shfl_xor(p3, 16, 64);
        p0 += __shfl_xor(p0, 32, 64); p1 += __shfl_xor(p1, 32, 64);
        p2 += __shfl_xor(p2, 32, 64); p3 += __shfl_xor(p3, 32, 64);
        if (g == 0) {
            int j = jb * 128 + w * 32 + jt * 16 + c;
            float4 o4 = { p0 + bmv.x, p1 + bmv.y, p2 + bmv.z, p3 + bmv.w };
            *(float4*)&out[((size_t)i * 256 + j) * 4] = o4;
        }
    }
}

extern "C" void kernel_launch(void* const* d_in, const int* in_sizes, int n_in,
                              void* d_out, int out_size, void* d_ws, size_t ws_size,
                              hipStream_t stream)
{
    const float* x   = (const float*)d_in[0];
    const int*   ei  = (const int*)d_in[1];
    const void*  tptr= d_in[3];
    const float* tm  = (const float*)d_in[4];
    const float* Wn  = (const float*)d_in[5];
    const float* bn  = (const float*)d_in[6];
    const float* Wee = (const float*)d_in[7];
    const float* bee = (const float*)d_in[8];
    const float* Wt1 = (const float*)d_in[9];
    const float* bt1 = (const float*)d_in[10];
    const float* Wt2 = (const float*)d_in[11];
    const float* bt2 = (const float*)d_in[12];
    const float* Wa  = (const float*)d_in[13];
    const float* ba  = (const float*)d_in[14];
    const float* Wq  = (const float*)d_in[15];
    const float* bq  = (const float*)d_in[16];
    const float* Wk  = (const float*)d_in[17];
    const float* bk  = (const float*)d_in[18];
    const float* Wv  = (const float*)d_in[19];
    const float* bv  = (const float*)d_in[20];
    const float* We  = (const float*)d_in[21];
    const float* Wsk = (const float*)d_in[22];
    const float* bsk = (const float*)d_in[23];
    const float* Wf1 = (const float*)d_in[24];
    const float* bf1 = (const float*)d_in[25];
    const float* Wf2 = (const float*)d_in[26];
    const float* bf2 = (const float*)d_in[27];
    const float* Wb  = (const float*)d_in[28];
    const float* bb  = (const float*)d_in[29];
    const float* Wm1 = (const float*)d_in[30];
    const float* bm1 = (const float*)d_in[31];
    const float* Wm2 = (const float*)d_in[32];
    const float* bm2 = (const float*)d_in[33];
    float* out = (float*)d_out;
    float* ws = (float*)d_ws;

    float* h    = ws + OFF_H;
    float* qb   = ws + OFF_Q;
    float* kb   = ws + OFF_K;
    float* vb   = ws + OFF_V;
    float* skp  = ws + OFF_SKP;
    float* ss   = ws + OFF_SS;
    float* ea   = ws + OFF_EA;
    float* cvec = ws + OFF_CVEC;
    int* iws    = (int*)(ws + OFF_INT);
    int* deg    = iws;
    int* cursor = iws + 1024;
    int* rowptr = iws + 2048;
    int* eorder = iws + 3073;
    int* src_csr   = (int*)(ws + OFF_G);
    float* ea_csr  = ws + OFF_G + 65536;
    float* Mst  = ws + OFF_M;
    short* Ub   = (short*)(ws + OFF_U);
    short* Mtb  = (short*)(ws + OFF_MT);
    short* hbb  = (short*)(ws + OFF_HB);
    float* tmod = ws + OFF_TMOD;

    hipMemsetAsync(deg, 0, 2048 * sizeof(int), stream);
    k_tmod<<<1, 128, 0, stream>>>(tptr, Wt1, bt1, Wt2, bt2, bb, Wm1, bm1, tmod, cvec);
    k_ss<<<12, 256, 0, stream>>>(tmod, Wa, ba, ss);
    k_input<<<512, 256, 0, stream>>>(x, Wn, bn, h);
    k_edge<<<256, 256, 0, stream>>>(ei, tm, Wee, bee, ea);
    k_count<<<256, 256, 0, stream>>>(ei, deg);
    k_scan<<<1, 1024, 0, stream>>>(deg, rowptr);
    k_scatter<<<256, 256, 0, stream>>>(ei, rowptr, cursor, eorder);
    k_sort2<<<1024, 128, 0, stream>>>(rowptr, eorder);
    k_flat<<<256, 256, 0, stream>>>(ei, ea, eorder, src_csr, ea_csr);

    for (int l = 0; l < LAYERS; l++) {
        const float* ssl = ss + l * 512;
        k_qkvs<<<dim3(64, 4), 256, 0, stream>>>(h, ssl,
            Wq + l * 16384, Wk + l * 16384, Wv + l * 16384, Wsk + l * 16384,
            bq + l * 128, bk + l * 128, bv + l * 128, bsk + l * 128,
            qb, kb, vb, skp);
        k_attn<<<1024, 64, 0, stream>>>(qb, kb, vb, skp, h, src_csr, ea_csr,
                                        We + l * 128, rowptr);
        k_ffn<<<64, 512, 0, stream>>>(h, Wf1 + l * 32768, bf1 + l * 256,
                                      Wf2 + l * 32768, bf2 + l * 128, ssl + 256, ssl + 384);
    }

    k_mprep<<<128, 256, 0, stream>>>(Wb, Wm1, Mst);
    k_mtrans<<<256, 256, 0, stream>>>(Mst, Mtb);
    k_convh<<<128, 256, 0, stream>>>(h, hbb);
    k_p1<<<dim3(128, 8), 256, 0, stream>>>(hbb, Mtb, Ub);
    k_p2<<<dim3(1024, 2), 256, 0, stream>>>(hbb, Ub, cvec, Wm2, bm2, out);
}

// Round 8
// 382.252 us; speedup vs baseline: 3.9578x; 1.2449x over previous
//
#include <hip/hip_runtime.h>
#include <math.h>

#define N_NODES 1024
#define HDIM 128
#define EDGES 65536
#define LAYERS 6

typedef __attribute__((ext_vector_type(8))) short bf16x8;
typedef __attribute__((ext_vector_type(4))) float f32x4;

// workspace float offsets
#define OFF_H     0
#define OFF_Q     131072
#define OFF_K     262144
#define OFF_V     393216
#define OFF_SKP   524288
#define OFF_G     655360       // reused: src_csr (int E) + ea_csr (float E)
#define OFF_SS    917504
#define OFF_EA    920576
#define OFF_CVEC  986112
#define OFF_INT   986240
#define OFF_M     1054912      // fp32 M [128 k][16384 n], n = m*128 + l  (m-outer!)
#define OFF_U     3152064      // bf16 U [1024 i][16384 n]
#define OFF_MT    11540672     // bf16 Mt [16384 n][128 k]
#define OFF_HB    12589248     // bf16 hb [1024][128]
#define OFF_TMOD  12654784     // fp32 tmod [128]

__device__ __forceinline__ float silu_f(float x) { return x / (1.f + expf(-x)); }
__device__ __forceinline__ float frcp(float x) { return __builtin_amdgcn_rcpf(x); }

__device__ __forceinline__ unsigned short f2bf(float f) {
    unsigned int u = __float_as_uint(f);
    u += 0x7FFFu + ((u >> 16) & 1u);
    return (unsigned short)(u >> 16);
}

// ---------------- setup: emb -> t_mod, cvec (1024 thr, split-K) ----------------
__global__ __launch_bounds__(1024) void k_tmod(const void* tptr,
    const float* __restrict__ Wt1, const float* __restrict__ bt1,
    const float* __restrict__ Wt2, const float* __restrict__ bt2,
    const float* __restrict__ bb, const float* __restrict__ Wm1, const float* __restrict__ bm1,
    float* __restrict__ tmod_g, float* __restrict__ cvec)
{
    __shared__ float emb_s[256];
    __shared__ float part[8][128];
    __shared__ float tmp1_s[128];
    int tid = threadIdx.x;
    int iv = *(const int*)tptr;
    float fv = __int_as_float(iv);
    float tval = (iv > -1000000 && iv < 1000000) ? (float)iv : fv;
    if (tid < 256) {
        int fi = tid & 127;
        float fr = expf(-logf(10000.f) * (float)fi / 128.f);
        float ta = tval * fr;
        emb_s[tid] = (tid < 128) ? cosf(ta) : sinf(ta);
    }
    __syncthreads();
    {   // GEMV1: 128 cols, K=256, 8 slices x 32
        int col = tid & 127, sl = tid >> 7;
        float p = 0.f;
#pragma unroll 8
        for (int i = sl * 32; i < sl * 32 + 32; i++) p += emb_s[i] * Wt1[i * 128 + col];
        part[sl][col] = p;
    }
    __syncthreads();
    if (tid < 128) {
        float a = bt1[tid];
#pragma unroll
        for (int s = 0; s < 8; s++) a += part[s][tid];
        tmp1_s[tid] = silu_f(a);
    }
    __syncthreads();
    {   // GEMV2: K=128, 8 slices x 16
        int col = tid & 127, sl = tid >> 7;
        float p = 0.f;
#pragma unroll 8
        for (int i = sl * 16; i < sl * 16 + 16; i++) p += tmp1_s[i] * Wt2[i * 128 + col];
        part[sl][col] = p;
    }
    __syncthreads();
    if (tid < 128) {
        float a = bt2[tid];
#pragma unroll
        for (int s = 0; s < 8; s++) a += part[s][tid];
        tmod_g[tid] = silu_f(a);
    }
    __syncthreads();
    {   // cvec GEMV: K=128
        int col = tid & 127, sl = tid >> 7;
        float p = 0.f;
#pragma unroll 8
        for (int i = sl * 16; i < sl * 16 + 16; i++) p += bb[i] * Wm1[i * 128 + col];
        part[sl][col] = p;
    }
    __syncthreads();
    if (tid < 128) {
        float a = bm1[tid];
#pragma unroll
        for (int s = 0; s < 8; s++) a += part[s][tid];
        cvec[tid] = a;
    }
}

// ---------------- parallel ss projection ----------------
__global__ __launch_bounds__(256) void k_ss(const float* __restrict__ tmod_g,
    const float* __restrict__ Wa, const float* __restrict__ ba, float* __restrict__ ss_all)
{
    __shared__ float tm_s[128];
    int tid = threadIdx.x;
    if (tid < 128) tm_s[tid] = tmod_g[tid];
    __syncthreads();
    int idx = blockIdx.x * 256 + tid;       // < 3072
    int l = idx >> 9, j = idx & 511;
    float a = ba[l * 512 + j];
    const float* w = Wa + l * 65536 + j;
#pragma unroll 4
    for (int k = 0; k < 128; k++) a += tm_s[k] * w[k * 512];
    ss_all[idx] = a;
}

// ---------------- h = x @ Wn + bn  (K=5) ----------------
__global__ __launch_bounds__(256) void k_input(const float* __restrict__ x,
    const float* __restrict__ Wn, const float* __restrict__ bn, float* __restrict__ h)
{
    int idx = blockIdx.x * 256 + threadIdx.x;  // < 131072
    int i = idx >> 7, j = idx & 127;
    float acc = bn[j];
#pragma unroll
    for (int kk = 0; kk < 5; kk++) acc += x[i * 5 + kk] * Wn[kk * 128 + j];
    h[idx] = acc;
}

// ---------------- edge_attr ----------------
__global__ __launch_bounds__(256) void k_edge(const int* __restrict__ ei,
    const float* __restrict__ tm, const float* __restrict__ Wee, const float* __restrict__ bee,
    float* __restrict__ ea)
{
    int e = blockIdx.x * 256 + threadIdx.x;
    int s = ei[e], d = ei[EDGES + e];
    ea[e] = tm[s * N_NODES + d] * Wee[0] + bee[0];
}

// ---------------- CSR build ----------------
__global__ __launch_bounds__(256) void k_count(const int* __restrict__ ei, int* __restrict__ deg)
{
    int e = blockIdx.x * 256 + threadIdx.x;
    atomicAdd(&deg[ei[EDGES + e]], 1);
}

__global__ __launch_bounds__(1024) void k_scan(const int* __restrict__ deg, int* __restrict__ rowptr)
{
    __shared__ int tmp[1024];
    int tid = threadIdx.x;
    tmp[tid] = deg[tid];
    __syncthreads();
    for (int off = 1; off < 1024; off <<= 1) {
        int vv = (tid >= off) ? tmp[tid - off] : 0;
        __syncthreads();
        tmp[tid] += vv;
        __syncthreads();
    }
    rowptr[tid + 1] = tmp[tid];
    if (tid == 0) rowptr[0] = 0;
}

__global__ __launch_bounds__(256) void k_scatter(const int* __restrict__ ei,
    const int* __restrict__ rowptr, int* __restrict__ cursor, int* __restrict__ eorder)
{
    int e = blockIdx.x * 256 + threadIdx.x;
    int d = ei[EDGES + e];
    int pos = atomicAdd(&cursor[d], 1);
    eorder[rowptr[d] + pos] = e;
}

// ---------------- per-node bitonic sort of edge ids in LDS ----------------
__global__ __launch_bounds__(128) void k_sort2(const int* __restrict__ rowptr,
                                               int* __restrict__ eorder)
{
    __shared__ int key[256];
    int node = blockIdx.x;
    int tid = threadIdx.x;
    int beg = rowptr[node], end = rowptr[node + 1];
    int n = end - beg;
    if (n <= 256) {
        for (int i = tid; i < 256; i += 128) key[i] = (i < n) ? eorder[beg + i] : 0x7FFFFFFF;
        __syncthreads();
        for (int k = 2; k <= 256; k <<= 1) {
            for (int j = k >> 1; j > 0; j >>= 1) {
                int i = ((tid / j) * 2 * j) + (tid % j);
                int l = i + j;
                bool up = ((i & k) == 0);
                int a = key[i], b = key[l];
                if ((a > b) == up) { key[i] = b; key[l] = a; }
                __syncthreads();
            }
        }
        for (int i = tid; i < n; i += 128) eorder[beg + i] = key[i];
    } else if (tid == 0) {
        for (int i = beg + 1; i < end; ++i) {
            int kk = eorder[i];
            int j = i - 1;
            while (j >= beg && eorder[j] > kk) { eorder[j + 1] = eorder[j]; --j; }
            eorder[j + 1] = kk;
        }
    }
}

// ---------------- flatten CSR gather arrays ----------------
__global__ __launch_bounds__(256) void k_flat(const int* __restrict__ ei,
    const float* __restrict__ ea, const int* __restrict__ eorder,
    int* __restrict__ src_csr, float* __restrict__ ea_csr)
{
    int t = blockIdx.x * 256 + threadIdx.x;
    int e = eorder[t];
    src_csr[t] = ei[e];
    ea_csr[t] = ea[e];
}

// ---------------- fused LN+mod + 4x GEMM (q,k,v,skip) ----------------
__global__ __launch_bounds__(256) void k_qkvs(const float* __restrict__ h,
    const float* __restrict__ ss,
    const float* __restrict__ Wq, const float* __restrict__ Wk,
    const float* __restrict__ Wv, const float* __restrict__ Wsk,
    const float* __restrict__ bq, const float* __restrict__ bk,
    const float* __restrict__ bv, const float* __restrict__ bsk,
    float* __restrict__ q, float* __restrict__ k, float* __restrict__ v, float* __restrict__ skp)
{
    __shared__ float a[16][128];
    __shared__ float mu_s[16], rs_s[16];
    int tid = threadIdx.x;
    int r0 = blockIdx.x * 16;
    for (int idx = tid; idx < 2048; idx += 256) a[idx >> 7][idx & 127] = h[r0 * 128 + idx];
    __syncthreads();
    {   // wave-parallel LN: 16 lanes per row
        int row = tid >> 4, ln = tid & 15;
        float s = 0.f, s2 = 0.f;
#pragma unroll
        for (int j = 0; j < 8; j++) {
            float xx = a[row][ln + 16 * j];
            s += xx; s2 += xx * xx;
        }
        s += __shfl_xor(s, 1, 16); s2 += __shfl_xor(s2, 1, 16);
        s += __shfl_xor(s, 2, 16); s2 += __shfl_xor(s2, 2, 16);
        s += __shfl_xor(s, 4, 16); s2 += __shfl_xor(s2, 4, 16);
        s += __shfl_xor(s, 8, 16); s2 += __shfl_xor(s2, 8, 16);
        if (ln == 0) {
            float mu = s * (1.f / 128.f);
            float var = s2 * (1.f / 128.f) - mu * mu;
            mu_s[row] = mu; rs_s[row] = rsqrtf(var + 1e-5f);
        }
    }
    __syncthreads();
    const float* sh = ss; const float* sc = ss + 128;
    for (int idx = tid; idx < 2048; idx += 256) {
        int r = idx >> 7, c = idx & 127;
        a[r][c] = (a[r][c] - mu_s[r]) * rs_s[r] * (1.f + sc[c]) + sh[c];
    }
    __syncthreads();
    const float* W; const float* bias; float* out;
    switch (blockIdx.y) {
        case 0:  W = Wq;  bias = bq;  out = q;   break;
        case 1:  W = Wk;  bias = bk;  out = k;   break;
        case 2:  W = Wv;  bias = bv;  out = v;   break;
        default: W = Wsk; bias = bsk; out = skp; break;
    }
    int col = tid & 127, grp = tid >> 7;
    float acc[8] = {};
    for (int kk = 0; kk < 128; ++kk) {
        float bvv = W[kk * 128 + col];
#pragma unroll
        for (int rr = 0; rr < 8; rr++) acc[rr] += a[grp * 8 + rr][kk] * bvv;
    }
#pragma unroll
    for (int rr = 0; rr < 8; rr++)
        out[(r0 + grp * 8 + rr) * 128 + col] = acc[rr] + bias[col];
}

// ---------------- fused FFN: 4 rows/block, grid 256 ----------------
__global__ __launch_bounds__(256) void k_ffn(float* __restrict__ h,
    const float* __restrict__ Wf1, const float* __restrict__ bf1,
    const float* __restrict__ Wf2, const float* __restrict__ bf2,
    const float* __restrict__ sh, const float* __restrict__ sc)
{
    __shared__ float a[4][128];
    __shared__ float gbuf[4][260];
    __shared__ float mu_s[4], rs_s[4];
    int tid = threadIdx.x;
    int r0 = blockIdx.x * 4;
    for (int idx = tid; idx < 512; idx += 256) a[idx >> 7][idx & 127] = h[r0 * 128 + idx];
    __syncthreads();
    {   // LN: wave w handles row w
        int w = tid >> 6, lane = tid & 63;
        float x0 = a[w][lane], x1 = a[w][lane + 64];
        float s = x0 + x1, s2 = x0 * x0 + x1 * x1;
#pragma unroll
        for (int off = 1; off < 64; off <<= 1) {
            s += __shfl_xor(s, off, 64);
            s2 += __shfl_xor(s2, off, 64);
        }
        if (lane == 0) {
            float mu = s * (1.f / 128.f);
            float var = s2 * (1.f / 128.f) - mu * mu;
            mu_s[w] = mu; rs_s[w] = rsqrtf(var + 1e-5f);
        }
    }
    __syncthreads();
    for (int idx = tid; idx < 512; idx += 256) {
        int r = idx >> 7, c = idx & 127;
        a[r][c] = (a[r][c] - mu_s[r]) * rs_s[r] * (1.f + sc[c]) + sh[c];
    }
    __syncthreads();
    {   // f1 + gelu: col = tid (256 cols), 4 rows
        float acc[4] = {};
        for (int k = 0; k < 128; ++k) {
            float wv = Wf1[k * 256 + tid];
#pragma unroll
            for (int r = 0; r < 4; r++) acc[r] += a[r][k] * wv;
        }
        float bv = bf1[tid];
#pragma unroll
        for (int r = 0; r < 4; r++) {
            float y = acc[r] + bv;
            gbuf[r][tid] = 0.5f * y * (1.f + erff(y * 0.70710678118654752f));
        }
    }
    __syncthreads();
    {   // f2 + residual: 2 grps x 2 rows
        int col = tid & 127, grp = tid >> 7;
        float acc0 = 0.f, acc1 = 0.f;
        for (int k = 0; k < 256; ++k) {
            float wv = Wf2[k * 128 + col];
            acc0 += gbuf[grp * 2][k] * wv;
            acc1 += gbuf[grp * 2 + 1][k] * wv;
        }
        float bv = bf2[col];
        h[(r0 + grp * 2) * 128 + col]     += acc0 + bv;
        h[(r0 + grp * 2 + 1) * 128 + col] += acc1 + bv;
    }
}

// ---------------- attention: 2 waves per node, online-softmax halves + merge ----------
__global__ __launch_bounds__(256) void k_attn(const float* __restrict__ q,
    const float* __restrict__ k, const float* __restrict__ v,
    const float* __restrict__ skp, float* __restrict__ h,
    const int* __restrict__ src_csr, const float* __restrict__ ea_csr,
    const float* __restrict__ We_l, const int* __restrict__ rowptr)
{
    __shared__ float ms[2][64], ssb[2][64], a0s[2][64], a1s[2][64];
    int tid = threadIdx.x;
    int wid = tid >> 6;            // 0..3
    int lane = tid & 63;
    int nslot = wid >> 1;          // 0..1
    int half = wid & 1;
    int node = blockIdx.x * 2 + nslot;
    int c0 = lane * 2;
    float2 q2 = *(const float2*)&q[node * 128 + c0];
    float we0 = We_l[c0], we1 = We_l[c0 + 1];
    int beg = rowptr[node], end = rowptr[node + 1];
    int n = end - beg;
    int mid = beg + ((n + 1) >> 1);
    int tb = half ? mid : beg;
    int te = half ? end : mid;
    float m = -INFINITY, s = 0.f, a0 = 0.f, a1 = 0.f;
    const float isc = 0.17677669529663687f;  // 1/sqrt(32)

    int t = tb;
    for (; t + 3 < te; t += 4) {
        int sn0 = src_csr[t],     sn1 = src_csr[t + 1];
        int sn2 = src_csr[t + 2], sn3 = src_csr[t + 3];
        float e0 = ea_csr[t],     e1 = ea_csr[t + 1];
        float e2 = ea_csr[t + 2], e3 = ea_csr[t + 3];
        float2 k0 = *(const float2*)&k[sn0 * 128 + c0];
        float2 k1 = *(const float2*)&k[sn1 * 128 + c0];
        float2 k2 = *(const float2*)&k[sn2 * 128 + c0];
        float2 k3 = *(const float2*)&k[sn3 * 128 + c0];
        float2 v0 = *(const float2*)&v[sn0 * 128 + c0];
        float2 v1 = *(const float2*)&v[sn1 * 128 + c0];
        float2 v2 = *(const float2*)&v[sn2 * 128 + c0];
        float2 v3 = *(const float2*)&v[sn3 * 128 + c0];
        float p0 = q2.x * (k0.x + e0 * we0) + q2.y * (k0.y + e0 * we1);
        float p1 = q2.x * (k1.x + e1 * we0) + q2.y * (k1.y + e1 * we1);
        float p2 = q2.x * (k2.x + e2 * we0) + q2.y * (k2.y + e2 * we1);
        float p3 = q2.x * (k3.x + e3 * we0) + q2.y * (k3.y + e3 * we1);
        p0 += __shfl_xor(p0, 1, 16); p1 += __shfl_xor(p1, 1, 16);
        p2 += __shfl_xor(p2, 1, 16); p3 += __shfl_xor(p3, 1, 16);
        p0 += __shfl_xor(p0, 2, 16); p1 += __shfl_xor(p1, 2, 16);
        p2 += __shfl_xor(p2, 2, 16); p3 += __shfl_xor(p3, 2, 16);
        p0 += __shfl_xor(p0, 4, 16); p1 += __shfl_xor(p1, 4, 16);
        p2 += __shfl_xor(p2, 4, 16); p3 += __shfl_xor(p3, 4, 16);
        p0 += __shfl_xor(p0, 8, 16); p1 += __shfl_xor(p1, 8, 16);
        p2 += __shfl_xor(p2, 8, 16); p3 += __shfl_xor(p3, 8, 16);
        {
            float al = p0 * isc;
            float mn = fmaxf(m, al);
            float scale = __expf(m - mn), wq = __expf(al - mn);
            s = s * scale + wq;
            a0 = a0 * scale + wq * (v0.x + e0 * we0);
            a1 = a1 * scale + wq * (v0.y + e0 * we1);
            m = mn;
        }
        {
            float al = p1 * isc;
            float mn = fmaxf(m, al);
            float scale = __expf(m - mn), wq = __expf(al - mn);
            s = s * scale + wq;
            a0 = a0 * scale + wq * (v1.x + e1 * we0);
            a1 = a1 * scale + wq * (v1.y + e1 * we1);
            m = mn;
        }
        {
            float al = p2 * isc;
            float mn = fmaxf(m, al);
            float scale = __expf(m - mn), wq = __expf(al - mn);
            s = s * scale + wq;
            a0 = a0 * scale + wq * (v2.x + e2 * we0);
            a1 = a1 * scale + wq * (v2.y + e2 * we1);
            m = mn;
        }
        {
            float al = p3 * isc;
            float mn = fmaxf(m, al);
            float scale = __expf(m - mn), wq = __expf(al - mn);
            s = s * scale + wq;
            a0 = a0 * scale + wq * (v3.x + e3 * we0);
            a1 = a1 * scale + wq * (v3.y + e3 * we1);
            m = mn;
        }
    }
    for (; t < te; ++t) {
        int sn = src_csr[t];
        float eav = ea_csr[t];
        float2 kv = *(const float2*)&k[sn * 128 + c0];
        float2 vv = *(const float2*)&v[sn * 128 + c0];
        float part = q2.x * (kv.x + eav * we0) + q2.y * (kv.y + eav * we1);
        part += __shfl_xor(part, 1, 16);
        part += __shfl_xor(part, 2, 16);
        part += __shfl_xor(part, 4, 16);
        part += __shfl_xor(part, 8, 16);
        float alpha = part * isc;
        float mn = fmaxf(m, alpha);
        float scale = __expf(m - mn), wq = __expf(alpha - mn);
        s = s * scale + wq;
        a0 = a0 * scale + wq * (vv.x + eav * we0);
        a1 = a1 * scale + wq * (vv.y + eav * we1);
        m = mn;
    }
    if (half == 1) {
        ms[nslot][lane] = m; ssb[nslot][lane] = s;
        a0s[nslot][lane] = a0; a1s[nslot][lane] = a1;
    }
    __syncthreads();
    if (half == 0) {
        float mB = ms[nslot][lane], sB = ssb[nslot][lane];
        float b0 = a0s[nslot][lane], b1 = a1s[nslot][lane];
        float mm = fmaxf(m, mB);
        float eA = (m  > -1e30f) ? __expf(m  - mm) : 0.f;
        float eB = (mB > -1e30f) ? __expf(mB - mm) : 0.f;
        float sT = s * eA + sB * eB;
        float o0 = a0 * eA + b0 * eB;
        float o1 = a1 * eA + b1 * eB;
        float inv = (sT > 0.f) ? 1.f / (sT + 1e-16f) : 0.f;
        int o = node * 128 + c0;
        h[o]     += skp[o]     + o0 * inv;
        h[o + 1] += skp[o + 1] + o1 * inv;
    }
}

// ---------------- M[k][m*128+l] = sum_o Wb[o,k,l] * Wm1[o,m]  (m-outer layout!) --------
__global__ __launch_bounds__(256) void k_mprep(const float* __restrict__ Wb,
    const float* __restrict__ Wm1, float* __restrict__ M)
{
    __shared__ float wb_s[64][128];
    __shared__ float wm_s[64][128];
    int tid = threadIdx.x;
    int k = blockIdx.x;
    int mg = tid & 15, lg = tid >> 4;
    int m0 = mg * 8, l0 = lg * 8;
    float acc[8][8] = {};
    for (int oh = 0; oh < 2; ++oh) {
        __syncthreads();
        for (int idx = tid; idx < 8192; idx += 256) {
            int o = idx >> 7, c = idx & 127;
            wb_s[o][c] = Wb[(size_t)(oh * 64 + o) * 16384 + k * 128 + c];
            wm_s[o][c] = Wm1[(oh * 64 + o) * 128 + c];
        }
        __syncthreads();
        for (int o = 0; o < 64; o++) {
            float lv[8], mv[8];
#pragma unroll
            for (int i = 0; i < 8; i++) { lv[i] = wb_s[o][l0 + i]; mv[i] = wm_s[o][m0 + i]; }
#pragma unroll
            for (int li = 0; li < 8; li++)
#pragma unroll
                for (int mi = 0; mi < 8; mi++) acc[li][mi] += lv[li] * mv[mi];
        }
    }
    for (int mi = 0; mi < 8; mi++)
        for (int li = 0; li < 8; li++)
            M[(size_t)k * 16384 + (m0 + mi) * 128 + (l0 + li)] = acc[li][mi];
}

// ---------------- Mt[n][k] (bf16) <- M[k][n] (fp32) ----------------
__global__ __launch_bounds__(256) void k_mtrans(const float* __restrict__ M,
                                                short* __restrict__ Mt)
{
    __shared__ __align__(16) short Ts[64][136];
    int tid = threadIdx.x;
    int n0 = blockIdx.x * 64;
    for (int p = 0; p < 32; p++) {
        int idx = p * 256 + tid;
        int k = idx >> 6, nn = idx & 63;
        Ts[nn][k] = (short)f2bf(M[(size_t)k * 16384 + n0 + nn]);
    }
    __syncthreads();
    for (int p = 0; p < 4; p++) {
        int idx = p * 256 + tid;
        int nn = idx >> 4, s = idx & 15;
        *(int4*)&Mt[(size_t)(n0 + nn) * 128 + s * 8] = *(const int4*)&Ts[nn][s * 8];
    }
}

// ---------------- hb (bf16) <- h (fp32) ----------------
__global__ __launch_bounds__(256) void k_convh(const float* __restrict__ h,
                                               short* __restrict__ hb)
{
    int idx = (blockIdx.x * 256 + threadIdx.x) * 4;
    float4 v = *(const float4*)&h[idx];
    short4 o;
    o.x = (short)f2bf(v.x); o.y = (short)f2bf(v.y);
    o.z = (short)f2bf(v.z); o.w = (short)f2bf(v.w);
    *(short4*)&hb[idx] = o;
}

// ---------------- phase1 MFMA: U[i][n] = sum_k hb[i,k] * Mt[n,k] ----------------
__global__ __launch_bounds__(256) void k_p1(const short* __restrict__ hb,
    const short* __restrict__ Mt, short* __restrict__ U)
{
    __shared__ __align__(16) short As[128][72];
    __shared__ __align__(16) short Bs[128][72];
    int tid = threadIdx.x;
    int n0 = blockIdx.x * 128;
    int i0 = blockIdx.y * 128;
    int w = tid >> 6, lane = tid & 63, c = lane & 15, g = lane >> 4;
    f32x4 acc[2][8] = {};
    for (int kh = 0; kh < 2; kh++) {
        __syncthreads();
        for (int idx = tid; idx < 1024; idx += 256) {
            int r = idx >> 3, s = idx & 7;
            *(int4*)&As[r][s * 8] = *(const int4*)&hb[(i0 + r) * 128 + kh * 64 + s * 8];
            *(int4*)&Bs[r][s * 8] = *(const int4*)&Mt[(size_t)(n0 + r) * 128 + kh * 64 + s * 8];
        }
        __syncthreads();
#pragma unroll
        for (int kk = 0; kk < 2; kk++) {
            int ko = kk * 32 + g * 8;
            bf16x8 a0 = *(const bf16x8*)&As[w * 32 + c][ko];
            bf16x8 a1 = *(const bf16x8*)&As[w * 32 + 16 + c][ko];
#pragma unroll
            for (int nt = 0; nt < 8; nt++) {
                bf16x8 b = *(const bf16x8*)&Bs[nt * 16 + c][ko];
                acc[0][nt] = __builtin_amdgcn_mfma_f32_16x16x32_bf16(a0, b, acc[0][nt], 0, 0, 0);
                acc[1][nt] = __builtin_amdgcn_mfma_f32_16x16x32_bf16(a1, b, acc[1][nt], 0, 0, 0);
            }
        }
    }
#pragma unroll
    for (int it = 0; it < 2; it++)
#pragma unroll
        for (int nt = 0; nt < 8; nt++)
#pragma unroll
            for (int r = 0; r < 4; r++) {
                int i = i0 + w * 32 + it * 16 + g * 4 + r;
                int n = n0 + nt * 16 + c;
                U[(size_t)i * 16384 + n] = (short)f2bf(acc[it][nt][r]);
            }
}

// ---------------- phase2 MFMA: block = (i, j-half); U_i staged once; H frags from L2 ---
__global__ __launch_bounds__(256) void k_p2(const short* __restrict__ hb,
    const short* __restrict__ U, const float* __restrict__ cvec,
    const float* __restrict__ Wm2, const float* __restrict__ bm2,
    float* __restrict__ out)
{
    __shared__ __align__(16) short Us[128][136];
    __shared__ float cvs[128];
    __shared__ float w2s[128][4];
    int tid = threadIdx.x;
    int i = blockIdx.x;
    int jb = blockIdx.y;          // 0..1
    int b = i >> 8;
    int w = tid >> 6, lane = tid & 63, c = lane & 15, g = lane >> 4;
    if (tid < 128) {
        cvs[tid] = cvec[tid];
        *(float4*)&w2s[tid][0] = *(const float4*)&Wm2[tid * 4];
    }
    bf16x8 hf[2][4];
    {
        const short* hrow = hb + (size_t)(b * 256 + jb * 128 + w * 32 + c) * 128;
#pragma unroll
        for (int jt = 0; jt < 2; jt++)
#pragma unroll
            for (int kq = 0; kq < 4; kq++)
                hf[jt][kq] = *(const bf16x8*)(hrow + jt * 16 * 128 + kq * 32 + g * 8);
    }
    for (int idx = tid; idx < 2048; idx += 256) {
        int r = idx >> 4, s = idx & 15;
        *(int4*)&Us[r][s * 8] = *(const int4*)&U[(size_t)i * 16384 + r * 128 + s * 8];
    }
    __syncthreads();
    f32x4 acc[2][8] = {};
#pragma unroll
    for (int kq = 0; kq < 4; kq++) {
        int ko = kq * 32 + g * 8;
#pragma unroll
        for (int mt = 0; mt < 8; mt++) {
            bf16x8 uv = *(const bf16x8*)&Us[mt * 16 + c][ko];
            acc[0][mt] = __builtin_amdgcn_mfma_f32_16x16x32_bf16(uv, hf[0][kq], acc[0][mt], 0, 0, 0);
            acc[1][mt] = __builtin_amdgcn_mfma_f32_16x16x32_bf16(uv, hf[1][kq], acc[1][mt], 0, 0, 0);
        }
    }
    float4 bmv = *(const float4*)&bm2[0];
#pragma unroll
    for (int jt = 0; jt < 2; jt++) {
        float p0 = 0.f, p1 = 0.f, p2 = 0.f, p3 = 0.f;
#pragma unroll
        for (int mt = 0; mt < 8; mt++) {
#pragma unroll
            for (int r = 0; r < 4; r++) {
                int m = mt * 16 + g * 4 + r;
                float y = acc[jt][mt][r] + cvs[m];
                float sv = y * frcp(1.f + __expf(-y));
                p0 += sv * w2s[m][0]; p1 += sv * w2s[m][1];
                p2 += sv * w2s[m][2]; p3 += sv * w2s[m][3];
            }
        }
        p0 += __shfl_xor(p0, 16, 64); p1 += __shfl_xor(p1, 16, 64);
        p2 += __shfl_xor(p2, 16, 64); p3 += __shfl_xor(p3, 16, 64);
        p0 += __shfl_xor(p0, 32, 64); p1 += __shfl_xor(p1, 32, 64);
        p2 += __shfl_xor(p2, 32, 64); p3 += __shfl_xor(p3, 32, 64);
        if (g == 0) {
            int j = jb * 128 + w * 32 + jt * 16 + c;
            float4 o4 = { p0 + bmv.x, p1 + bmv.y, p2 + bmv.z, p3 + bmv.w };
            *(float4*)&out[((size_t)i * 256 + j) * 4] = o4;
        }
    }
}

extern "C" void kernel_launch(void* const* d_in, const int* in_sizes, int n_in,
                              void* d_out, int out_size, void* d_ws, size_t ws_size,
                              hipStream_t stream)
{
    const float* x   = (const float*)d_in[0];
    const int*   ei  = (const int*)d_in[1];
    const void*  tptr= d_in[3];
    const float* tm  = (const float*)d_in[4];
    const float* Wn  = (const float*)d_in[5];
    const float* bn  = (const float*)d_in[6];
    const float* Wee = (const float*)d_in[7];
    const float* bee = (const float*)d_in[8];
    const float* Wt1 = (const float*)d_in[9];
    const float* bt1 = (const float*)d_in[10];
    const float* Wt2 = (const float*)d_in[11];
    const float* bt2 = (const float*)d_in[12];
    const float* Wa  = (const float*)d_in[13];
    const float* ba  = (const float*)d_in[14];
    const float* Wq  = (const float*)d_in[15];
    const float* bq  = (const float*)d_in[16];
    const float* Wk  = (const float*)d_in[17];
    const float* bk  = (const float*)d_in[18];
    const float* Wv  = (const float*)d_in[19];
    const float* bv  = (const float*)d_in[20];
    const float* We  = (const float*)d_in[21];
    const float* Wsk = (const float*)d_in[22];
    const float* bsk = (const float*)d_in[23];
    const float* Wf1 = (const float*)d_in[24];
    const float* bf1 = (const float*)d_in[25];
    const float* Wf2 = (const float*)d_in[26];
    const float* bf2 = (const float*)d_in[27];
    const float* Wb  = (const float*)d_in[28];
    const float* bb  = (const float*)d_in[29];
    const float* Wm1 = (const float*)d_in[30];
    const float* bm1 = (const float*)d_in[31];
    const float* Wm2 = (const float*)d_in[32];
    const float* bm2 = (const float*)d_in[33];
    float* out = (float*)d_out;
    float* ws = (float*)d_ws;

    float* h    = ws + OFF_H;
    float* qb   = ws + OFF_Q;
    float* kb   = ws + OFF_K;
    float* vb   = ws + OFF_V;
    float* skp  = ws + OFF_SKP;
    float* ss   = ws + OFF_SS;
    float* ea   = ws + OFF_EA;
    float* cvec = ws + OFF_CVEC;
    int* iws    = (int*)(ws + OFF_INT);
    int* deg    = iws;
    int* cursor = iws + 1024;
    int* rowptr = iws + 2048;
    int* eorder = iws + 3073;
    int* src_csr   = (int*)(ws + OFF_G);
    float* ea_csr  = ws + OFF_G + 65536;
    float* Mst  = ws + OFF_M;
    short* Ub   = (short*)(ws + OFF_U);
    short* Mtb  = (short*)(ws + OFF_MT);
    short* hbb  = (short*)(ws + OFF_HB);
    float* tmod = ws + OFF_TMOD;

    hipMemsetAsync(deg, 0, 2048 * sizeof(int), stream);
    k_tmod<<<1, 1024, 0, stream>>>(tptr, Wt1, bt1, Wt2, bt2, bb, Wm1, bm1, tmod, cvec);
    k_ss<<<12, 256, 0, stream>>>(tmod, Wa, ba, ss);
    k_input<<<512, 256, 0, stream>>>(x, Wn, bn, h);
    k_edge<<<256, 256, 0, stream>>>(ei, tm, Wee, bee, ea);
    k_count<<<256, 256, 0, stream>>>(ei, deg);
    k_scan<<<1, 1024, 0, stream>>>(deg, rowptr);
    k_scatter<<<256, 256, 0, stream>>>(ei, rowptr, cursor, eorder);
    k_sort2<<<1024, 128, 0, stream>>>(rowptr, eorder);
    k_flat<<<256, 256, 0, stream>>>(ei, ea, eorder, src_csr, ea_csr);

    for (int l = 0; l < LAYERS; l++) {
        const float* ssl = ss + l * 512;
        k_qkvs<<<dim3(64, 4), 256, 0, stream>>>(h, ssl,
            Wq + l * 16384, Wk + l * 16384, Wv + l * 16384, Wsk + l * 16384,
            bq + l * 128, bk + l * 128, bv + l * 128, bsk + l * 128,
            qb, kb, vb, skp);
        k_attn<<<512, 256, 0, stream>>>(qb, kb, vb, skp, h, src_csr, ea_csr,
                                        We + l * 128, rowptr);
        k_ffn<<<256, 256, 0, stream>>>(h, Wf1 + l * 32768, bf1 + l * 256,
                                       Wf2 + l * 32768, bf2 + l * 128, ssl + 256, ssl + 384);
    }

    k_mprep<<<128, 256, 0, stream>>>(Wb, Wm1, Mst);
    k_mtrans<<<256, 256, 0, stream>>>(Mst, Mtb);
    k_convh<<<128, 256, 0, stream>>>(h, hbb);
    k_p1<<<dim3(128, 8), 256, 0, stream>>>(hbb, Mtb, Ub);
    k_p2<<<dim3(1024, 2), 256, 0, stream>>>(hbb, Ub, cvec, Wm2, bm2, out);
}

// Round 9
// 353.755 us; speedup vs baseline: 4.2766x; 1.0806x over previous
//
#include <hip/hip_runtime.h>
#include <math.h>

#define N_NODES 1024
#define HDIM 128
#define EDGES 65536
#define LAYERS 6

typedef __attribute__((ext_vector_type(8))) short bf16x8;
typedef __attribute__((ext_vector_type(4))) float f32x4;

// workspace float offsets
#define OFF_H     0
#define OFF_Q     131072
#define OFF_K     262144
#define OFF_V     393216
#define OFF_SKP   524288
#define OFF_G     655360       // reused: src_csr (int E) + ea_csr (float E)
#define OFF_SS    917504
#define OFF_EA    920576
#define OFF_CVEC  986112
#define OFF_INT   986240
#define OFF_M     1054912      // fp32 M [128 k][16384 n], n = m*128 + l  (m-outer!)
#define OFF_U     3152064      // bf16 U [1024 i][16384 n]
#define OFF_MT    11540672     // bf16 Mt [16384 n][128 k]
#define OFF_HB    12589248     // bf16 hb [1024][128]
#define OFF_TMOD  12654784     // fp32 tmod [128]
#define OFF_WB    12654912     // bf16 transposed layer weights (786432 shorts)

__device__ __forceinline__ float silu_f(float x) { return x / (1.f + expf(-x)); }
__device__ __forceinline__ float frcp(float x) { return __builtin_amdgcn_rcpf(x); }

__device__ __forceinline__ unsigned short f2bf(float f) {
    unsigned int u = __float_as_uint(f);
    u += 0x7FFFu + ((u >> 16) & 1u);
    return (unsigned short)(u >> 16);
}

// ---------------- setup: emb -> t_mod, cvec (1024 thr, split-K) ----------------
__global__ __launch_bounds__(1024) void k_tmod(const void* tptr,
    const float* __restrict__ Wt1, const float* __restrict__ bt1,
    const float* __restrict__ Wt2, const float* __restrict__ bt2,
    const float* __restrict__ bb, const float* __restrict__ Wm1, const float* __restrict__ bm1,
    float* __restrict__ tmod_g, float* __restrict__ cvec)
{
    __shared__ float emb_s[256];
    __shared__ float part[8][128];
    __shared__ float tmp1_s[128];
    int tid = threadIdx.x;
    int iv = *(const int*)tptr;
    float fv = __int_as_float(iv);
    float tval = (iv > -1000000 && iv < 1000000) ? (float)iv : fv;
    if (tid < 256) {
        int fi = tid & 127;
        float fr = expf(-logf(10000.f) * (float)fi / 128.f);
        float ta = tval * fr;
        emb_s[tid] = (tid < 128) ? cosf(ta) : sinf(ta);
    }
    __syncthreads();
    {
        int col = tid & 127, sl = tid >> 7;
        float p = 0.f;
#pragma unroll 8
        for (int i = sl * 32; i < sl * 32 + 32; i++) p += emb_s[i] * Wt1[i * 128 + col];
        part[sl][col] = p;
    }
    __syncthreads();
    if (tid < 128) {
        float a = bt1[tid];
#pragma unroll
        for (int s = 0; s < 8; s++) a += part[s][tid];
        tmp1_s[tid] = silu_f(a);
    }
    __syncthreads();
    {
        int col = tid & 127, sl = tid >> 7;
        float p = 0.f;
#pragma unroll 8
        for (int i = sl * 16; i < sl * 16 + 16; i++) p += tmp1_s[i] * Wt2[i * 128 + col];
        part[sl][col] = p;
    }
    __syncthreads();
    if (tid < 128) {
        float a = bt2[tid];
#pragma unroll
        for (int s = 0; s < 8; s++) a += part[s][tid];
        tmod_g[tid] = silu_f(a);
    }
    __syncthreads();
    {
        int col = tid & 127, sl = tid >> 7;
        float p = 0.f;
#pragma unroll 8
        for (int i = sl * 16; i < sl * 16 + 16; i++) p += bb[i] * Wm1[i * 128 + col];
        part[sl][col] = p;
    }
    __syncthreads();
    if (tid < 128) {
        float a = bm1[tid];
#pragma unroll
        for (int s = 0; s < 8; s++) a += part[s][tid];
        cvec[tid] = a;
    }
}

// ---------------- parallel ss projection ----------------
__global__ __launch_bounds__(256) void k_ss(const float* __restrict__ tmod_g,
    const float* __restrict__ Wa, const float* __restrict__ ba, float* __restrict__ ss_all)
{
    __shared__ float tm_s[128];
    int tid = threadIdx.x;
    if (tid < 128) tm_s[tid] = tmod_g[tid];
    __syncthreads();
    int idx = blockIdx.x * 256 + tid;       // < 3072
    int l = idx >> 9, j = idx & 511;
    float a = ba[l * 512 + j];
    const float* w = Wa + l * 65536 + j;
#pragma unroll 4
    for (int k = 0; k < 128; k++) a += tm_s[k] * w[k * 512];
    ss_all[idx] = a;
}

// ---------------- weight transpose+bf16: 192 tiles of 64x64 ----------------
__global__ __launch_bounds__(256) void k_wtrans(
    const float* __restrict__ Wq, const float* __restrict__ Wk,
    const float* __restrict__ Wv, const float* __restrict__ Wsk,
    const float* __restrict__ Wf1, const float* __restrict__ Wf2,
    short* __restrict__ WT)
{
    __shared__ __align__(16) short T[64][80];
    int t = blockIdx.x;
    int tid = threadIdx.x;
    const float* src; short* dst; int K, N, kt, nt;
    if (t < 96) {
        int mat = t >> 2, sub = t & 3;
        int l = mat >> 2, m = mat & 3;
        src = (m == 0 ? Wq : m == 1 ? Wk : m == 2 ? Wv : Wsk) + l * 16384;
        dst = WT + (size_t)mat * 16384;
        K = 128; N = 128; kt = sub >> 1; nt = sub & 1;
    } else if (t < 144) {
        int i = t - 96; int l = i >> 3, sub = i & 7;
        src = Wf1 + l * 32768;
        dst = WT + 24 * 16384 + (size_t)l * 32768;
        K = 128; N = 256; kt = sub & 1; nt = sub >> 1;
    } else {
        int i = t - 144; int l = i >> 3, sub = i & 7;
        src = Wf2 + l * 32768;
        dst = WT + 24 * 16384 + 6 * 32768 + (size_t)l * 32768;
        K = 256; N = 128; kt = sub >> 1; nt = sub & 1;
    }
    int k0 = kt * 64, n0 = nt * 64;
    for (int p = 0; p < 16; p++) {
        int idx = p * 256 + tid;
        int kk = idx >> 6, nn = idx & 63;
        T[nn][kk] = (short)f2bf(src[(k0 + kk) * N + n0 + nn]);
    }
    __syncthreads();
    for (int p = 0; p < 2; p++) {
        int idx = p * 256 + tid;
        int nn = idx >> 3, sq = idx & 7;
        *(int4*)&dst[(size_t)(n0 + nn) * K + k0 + sq * 8] = *(const int4*)&T[nn][sq * 8];
    }
}

// ---------------- h = x @ Wn + bn  (K=5) ----------------
__global__ __launch_bounds__(256) void k_input(const float* __restrict__ x,
    const float* __restrict__ Wn, const float* __restrict__ bn, float* __restrict__ h)
{
    int idx = blockIdx.x * 256 + threadIdx.x;  // < 131072
    int i = idx >> 7, j = idx & 127;
    float acc = bn[j];
#pragma unroll
    for (int kk = 0; kk < 5; kk++) acc += x[i * 5 + kk] * Wn[kk * 128 + j];
    h[idx] = acc;
}

// ---------------- edge_attr ----------------
__global__ __launch_bounds__(256) void k_edge(const int* __restrict__ ei,
    const float* __restrict__ tm, const float* __restrict__ Wee, const float* __restrict__ bee,
    float* __restrict__ ea)
{
    int e = blockIdx.x * 256 + threadIdx.x;
    int s = ei[e], d = ei[EDGES + e];
    ea[e] = tm[s * N_NODES + d] * Wee[0] + bee[0];
}

// ---------------- CSR build ----------------
__global__ __launch_bounds__(256) void k_count(const int* __restrict__ ei, int* __restrict__ deg)
{
    int e = blockIdx.x * 256 + threadIdx.x;
    atomicAdd(&deg[ei[EDGES + e]], 1);
}

__global__ __launch_bounds__(1024) void k_scan(const int* __restrict__ deg, int* __restrict__ rowptr)
{
    __shared__ int tmp[1024];
    int tid = threadIdx.x;
    tmp[tid] = deg[tid];
    __syncthreads();
    for (int off = 1; off < 1024; off <<= 1) {
        int vv = (tid >= off) ? tmp[tid - off] : 0;
        __syncthreads();
        tmp[tid] += vv;
        __syncthreads();
    }
    rowptr[tid + 1] = tmp[tid];
    if (tid == 0) rowptr[0] = 0;
}

__global__ __launch_bounds__(256) void k_scatter(const int* __restrict__ ei,
    const int* __restrict__ rowptr, int* __restrict__ cursor, int* __restrict__ eorder)
{
    int e = blockIdx.x * 256 + threadIdx.x;
    int d = ei[EDGES + e];
    int pos = atomicAdd(&cursor[d], 1);
    eorder[rowptr[d] + pos] = e;
}

// ---------------- per-node bitonic sort of edge ids in LDS ----------------
__global__ __launch_bounds__(128) void k_sort2(const int* __restrict__ rowptr,
                                               int* __restrict__ eorder)
{
    __shared__ int key[256];
    int node = blockIdx.x;
    int tid = threadIdx.x;
    int beg = rowptr[node], end = rowptr[node + 1];
    int n = end - beg;
    if (n <= 256) {
        for (int i = tid; i < 256; i += 128) key[i] = (i < n) ? eorder[beg + i] : 0x7FFFFFFF;
        __syncthreads();
        for (int k = 2; k <= 256; k <<= 1) {
            for (int j = k >> 1; j > 0; j >>= 1) {
                int i = ((tid / j) * 2 * j) + (tid % j);
                int l = i + j;
                bool up = ((i & k) == 0);
                int a = key[i], b = key[l];
                if ((a > b) == up) { key[i] = b; key[l] = a; }
                __syncthreads();
            }
        }
        for (int i = tid; i < n; i += 128) eorder[beg + i] = key[i];
    } else if (tid == 0) {
        for (int i = beg + 1; i < end; ++i) {
            int kk = eorder[i];
            int j = i - 1;
            while (j >= beg && eorder[j] > kk) { eorder[j + 1] = eorder[j]; --j; }
            eorder[j + 1] = kk;
        }
    }
}

// ---------------- flatten CSR gather arrays ----------------
__global__ __launch_bounds__(256) void k_flat(const int* __restrict__ ei,
    const float* __restrict__ ea, const int* __restrict__ eorder,
    int* __restrict__ src_csr, float* __restrict__ ea_csr)
{
    int t = blockIdx.x * 256 + threadIdx.x;
    int e = eorder[t];
    src_csr[t] = ei[e];
    ea_csr[t] = ea[e];
}

// ---------------- MFMA qkvs: LN+mod fused, D = hn @ W  (one matrix per blockIdx.y) -----
__global__ __launch_bounds__(256) void k_qkvs(const float* __restrict__ h,
    const float* __restrict__ ss, const short* __restrict__ WT, int layer,
    const float* __restrict__ bq, const float* __restrict__ bk,
    const float* __restrict__ bv, const float* __restrict__ bsk,
    float* __restrict__ q, float* __restrict__ k, float* __restrict__ v, float* __restrict__ skp)
{
    __shared__ __align__(16) short As[128][136];
    __shared__ float shs[128], scs[128];
    int tid = threadIdx.x;
    int r0 = blockIdx.x * 128;
    int mat = blockIdx.y;
    if (tid < 128) { shs[tid] = ss[tid]; scs[tid] = ss[128 + tid]; }
    __syncthreads();
    {   // LN+mod -> bf16 As. 2 threads per row, 64 cols each, two-pass.
        int row = tid >> 1, o = tid & 1;
        const float* hr = h + (size_t)(r0 + row) * 128 + o * 64;
        float s = 0.f, s2 = 0.f;
#pragma unroll
        for (int j = 0; j < 16; j++) {
            float4 vv = *(const float4*)&hr[j * 4];
            s += vv.x + vv.y + vv.z + vv.w;
            s2 += vv.x * vv.x + vv.y * vv.y + vv.z * vv.z + vv.w * vv.w;
        }
        s += __shfl_xor(s, 1, 64); s2 += __shfl_xor(s2, 1, 64);
        float mu = s * (1.f / 128.f);
        float var = s2 * (1.f / 128.f) - mu * mu;
        float rs = rsqrtf(var + 1e-5f);
#pragma unroll
        for (int j = 0; j < 16; j++) {
            float4 vv = *(const float4*)&hr[j * 4];
            int cb = o * 64 + j * 4;
            short4 o4;
            o4.x = (short)f2bf((vv.x - mu) * rs * (1.f + scs[cb])     + shs[cb]);
            o4.y = (short)f2bf((vv.y - mu) * rs * (1.f + scs[cb + 1]) + shs[cb + 1]);
            o4.z = (short)f2bf((vv.z - mu) * rs * (1.f + scs[cb + 2]) + shs[cb + 2]);
            o4.w = (short)f2bf((vv.w - mu) * rs * (1.f + scs[cb + 3]) + shs[cb + 3]);
            *(short4*)&As[row][cb] = o4;
        }
    }
    __syncthreads();
    int w = tid >> 6, lane = tid & 63, c = lane & 15, g = lane >> 4;
    const short* Wm = WT + (size_t)(layer * 4 + mat) * 16384;
    f32x4 acc[2][8] = {};
#pragma unroll
    for (int kq = 0; kq < 4; kq++) {
        int ko = kq * 32 + g * 8;
        bf16x8 a0 = *(const bf16x8*)&As[w * 32 + c][ko];
        bf16x8 a1 = *(const bf16x8*)&As[w * 32 + 16 + c][ko];
        bf16x8 bfr[8];
#pragma unroll
        for (int nt = 0; nt < 8; nt++)
            bfr[nt] = *(const bf16x8*)&Wm[(size_t)(nt * 16 + c) * 128 + ko];
#pragma unroll
        for (int nt = 0; nt < 8; nt++) {
            acc[0][nt] = __builtin_amdgcn_mfma_f32_16x16x32_bf16(a0, bfr[nt], acc[0][nt], 0, 0, 0);
            acc[1][nt] = __builtin_amdgcn_mfma_f32_16x16x32_bf16(a1, bfr[nt], acc[1][nt], 0, 0, 0);
        }
    }
    const float* bias; float* out;
    switch (mat) {
        case 0:  bias = bq;  out = q;   break;
        case 1:  bias = bk;  out = k;   break;
        case 2:  bias = bv;  out = v;   break;
        default: bias = bsk; out = skp; break;
    }
#pragma unroll
    for (int it = 0; it < 2; it++)
#pragma unroll
        for (int nt = 0; nt < 8; nt++) {
            int n = nt * 16 + c;
            float bv2 = bias[n];
#pragma unroll
            for (int r = 0; r < 4; r++) {
                int i = r0 + w * 32 + it * 16 + g * 4 + r;
                out[(size_t)i * 128 + n] = acc[it][nt][r] + bv2;
            }
        }
}

// ---------------- MFMA FFN: LN2 -> f1 -> gelu -> f2 -> residual. 32 rows/block --------
__global__ __launch_bounds__(256) void k_ffn(float* __restrict__ h,
    const short* __restrict__ WT, int layer,
    const float* __restrict__ bf1, const float* __restrict__ bf2,
    const float* __restrict__ ss2)
{
    __shared__ __align__(16) short As[32][136];
    __shared__ __align__(16) short Gs[32][264];
    __shared__ float shs[128], scs[128];
    int tid = threadIdx.x;
    int r0 = blockIdx.x * 32;
    if (tid < 128) { shs[tid] = ss2[tid]; scs[tid] = ss2[128 + tid]; }
    __syncthreads();
    {   // LN+mod: 8 threads per row, 16 cols each
        int row = tid >> 3, o = tid & 7;
        const float* hr = h + (size_t)(r0 + row) * 128 + o * 16;
        float s = 0.f, s2 = 0.f;
#pragma unroll
        for (int j = 0; j < 4; j++) {
            float4 vv = *(const float4*)&hr[j * 4];
            s += vv.x + vv.y + vv.z + vv.w;
            s2 += vv.x * vv.x + vv.y * vv.y + vv.z * vv.z + vv.w * vv.w;
        }
        s += __shfl_xor(s, 1, 64); s2 += __shfl_xor(s2, 1, 64);
        s += __shfl_xor(s, 2, 64); s2 += __shfl_xor(s2, 2, 64);
        s += __shfl_xor(s, 4, 64); s2 += __shfl_xor(s2, 4, 64);
        float mu = s * (1.f / 128.f);
        float var = s2 * (1.f / 128.f) - mu * mu;
        float rs = rsqrtf(var + 1e-5f);
#pragma unroll
        for (int j = 0; j < 4; j++) {
            float4 vv = *(const float4*)&hr[j * 4];
            int cb = o * 16 + j * 4;
            short4 o4;
            o4.x = (short)f2bf((vv.x - mu) * rs * (1.f + scs[cb])     + shs[cb]);
            o4.y = (short)f2bf((vv.y - mu) * rs * (1.f + scs[cb + 1]) + shs[cb + 1]);
            o4.z = (short)f2bf((vv.z - mu) * rs * (1.f + scs[cb + 2]) + shs[cb + 2]);
            o4.w = (short)f2bf((vv.w - mu) * rs * (1.f + scs[cb + 3]) + shs[cb + 3]);
            *(short4*)&As[row][cb] = o4;
        }
    }
    __syncthreads();
    int w = tid >> 6, lane = tid & 63, c = lane & 15, g = lane >> 4;
    const short* W1 = WT + 24 * 16384 + (size_t)layer * 32768;
    const short* W2 = WT + 24 * 16384 + 6 * 32768 + (size_t)layer * 32768;
    {   // f1: wave w covers cols w*64 + nt*16 + c (nt 0..3)
        f32x4 acc[2][4] = {};
#pragma unroll
        for (int kq = 0; kq < 4; kq++) {
            int ko = kq * 32 + g * 8;
            bf16x8 a0 = *(const bf16x8*)&As[c][ko];
            bf16x8 a1 = *(const bf16x8*)&As[16 + c][ko];
#pragma unroll
            for (int nt = 0; nt < 4; nt++) {
                bf16x8 bfr = *(const bf16x8*)&W1[(size_t)(w * 64 + nt * 16 + c) * 128 + ko];
                acc[0][nt] = __builtin_amdgcn_mfma_f32_16x16x32_bf16(a0, bfr, acc[0][nt], 0, 0, 0);
                acc[1][nt] = __builtin_amdgcn_mfma_f32_16x16x32_bf16(a1, bfr, acc[1][nt], 0, 0, 0);
            }
        }
        // gelu -> Gs (bf16)
#pragma unroll
        for (int it = 0; it < 2; it++)
#pragma unroll
            for (int nt = 0; nt < 4; nt++) {
                int n = w * 64 + nt * 16 + c;
                float bv = bf1[n];
#pragma unroll
                for (int r = 0; r < 4; r++) {
                    float y = acc[it][nt][r] + bv;
                    float gl = 0.5f * y * (1.f + erff(y * 0.70710678118654752f));
                    Gs[it * 16 + g * 4 + r][n] = (short)f2bf(gl);
                }
            }
    }
    __syncthreads();
    {   // f2: K=256; wave w covers cols w*32 + nt2*16 + c
        f32x4 acc2[2][2] = {};
#pragma unroll
        for (int kq = 0; kq < 8; kq++) {
            int ko = kq * 32 + g * 8;
            bf16x8 a0 = *(const bf16x8*)&Gs[c][ko];
            bf16x8 a1 = *(const bf16x8*)&Gs[16 + c][ko];
#pragma unroll
            for (int nt2 = 0; nt2 < 2; nt2++) {
                bf16x8 bfr = *(const bf16x8*)&W2[(size_t)(w * 32 + nt2 * 16 + c) * 256 + ko];
                acc2[0][nt2] = __builtin_amdgcn_mfma_f32_16x16x32_bf16(a0, bfr, acc2[0][nt2], 0, 0, 0);
                acc2[1][nt2] = __builtin_amdgcn_mfma_f32_16x16x32_bf16(a1, bfr, acc2[1][nt2], 0, 0, 0);
            }
        }
#pragma unroll
        for (int it = 0; it < 2; it++)
#pragma unroll
            for (int nt2 = 0; nt2 < 2; nt2++) {
                int n = w * 32 + nt2 * 16 + c;
                float bv = bf2[n];
#pragma unroll
                for (int r = 0; r < 4; r++) {
                    int i = r0 + it * 16 + g * 4 + r;
                    h[(size_t)i * 128 + n] += acc2[it][nt2][r] + bv;
                }
            }
    }
}

// ---------------- attention: 2 waves per node, online-softmax halves + merge ----------
__global__ __launch_bounds__(256) void k_attn(const float* __restrict__ q,
    const float* __restrict__ k, const float* __restrict__ v,
    const float* __restrict__ skp, float* __restrict__ h,
    const int* __restrict__ src_csr, const float* __restrict__ ea_csr,
    const float* __restrict__ We_l, const int* __restrict__ rowptr)
{
    __shared__ float ms[2][64], ssb[2][64], a0s[2][64], a1s[2][64];
    int tid = threadIdx.x;
    int wid = tid >> 6;            // 0..3
    int lane = tid & 63;
    int nslot = wid >> 1;          // 0..1
    int half = wid & 1;
    int node = blockIdx.x * 2 + nslot;
    int c0 = lane * 2;
    float2 q2 = *(const float2*)&q[node * 128 + c0];
    float we0 = We_l[c0], we1 = We_l[c0 + 1];
    int beg = rowptr[node], end = rowptr[node + 1];
    int n = end - beg;
    int mid = beg + ((n + 1) >> 1);
    int tb = half ? mid : beg;
    int te = half ? end : mid;
    float m = -INFINITY, s = 0.f, a0 = 0.f, a1 = 0.f;
    const float isc = 0.17677669529663687f;  // 1/sqrt(32)

    int t = tb;
    for (; t + 3 < te; t += 4) {
        int sn0 = src_csr[t],     sn1 = src_csr[t + 1];
        int sn2 = src_csr[t + 2], sn3 = src_csr[t + 3];
        float e0 = ea_csr[t],     e1 = ea_csr[t + 1];
        float e2 = ea_csr[t + 2], e3 = ea_csr[t + 3];
        float2 k0 = *(const float2*)&k[sn0 * 128 + c0];
        float2 k1 = *(const float2*)&k[sn1 * 128 + c0];
        float2 k2 = *(const float2*)&k[sn2 * 128 + c0];
        float2 k3 = *(const float2*)&k[sn3 * 128 + c0];
        float2 v0 = *(const float2*)&v[sn0 * 128 + c0];
        float2 v1 = *(const float2*)&v[sn1 * 128 + c0];
        float2 v2 = *(const float2*)&v[sn2 * 128 + c0];
        float2 v3 = *(const float2*)&v[sn3 * 128 + c0];
        float p0 = q2.x * (k0.x + e0 * we0) + q2.y * (k0.y + e0 * we1);
        float p1 = q2.x * (k1.x + e1 * we0) + q2.y * (k1.y + e1 * we1);
        float p2 = q2.x * (k2.x + e2 * we0) + q2.y * (k2.y + e2 * we1);
        float p3 = q2.x * (k3.x + e3 * we0) + q2.y * (k3.y + e3 * we1);
        p0 += __shfl_xor(p0, 1, 16); p1 += __shfl_xor(p1, 1, 16);
        p2 += __shfl_xor(p2, 1, 16); p3 += __shfl_xor(p3, 1, 16);
        p0 += __shfl_xor(p0, 2, 16); p1 += __shfl_xor(p1, 2, 16);
        p2 += __shfl_xor(p2, 2, 16); p3 += __shfl_xor(p3, 2, 16);
        p0 += __shfl_xor(p0, 4, 16); p1 += __shfl_xor(p1, 4, 16);
        p2 += __shfl_xor(p2, 4, 16); p3 += __shfl_xor(p3, 4, 16);
        p0 += __shfl_xor(p0, 8, 16); p1 += __shfl_xor(p1, 8, 16);
        p2 += __shfl_xor(p2, 8, 16); p3 += __shfl_xor(p3, 8, 16);
        {
            float al = p0 * isc;
            float mn = fmaxf(m, al);
            float scale = __expf(m - mn), wq = __expf(al - mn);
            s = s * scale + wq;
            a0 = a0 * scale + wq * (v0.x + e0 * we0);
            a1 = a1 * scale + wq * (v0.y + e0 * we1);
            m = mn;
        }
        {
            float al = p1 * isc;
            float mn = fmaxf(m, al);
            float scale = __expf(m - mn), wq = __expf(al - mn);
            s = s * scale + wq;
            a0 = a0 * scale + wq * (v1.x + e1 * we0);
            a1 = a1 * scale + wq * (v1.y + e1 * we1);
            m = mn;
        }
        {
            float al = p2 * isc;
            float mn = fmaxf(m, al);
            float scale = __expf(m - mn), wq = __expf(al - mn);
            s = s * scale + wq;
            a0 = a0 * scale + wq * (v2.x + e2 * we0);
            a1 = a1 * scale + wq * (v2.y + e2 * we1);
            m = mn;
        }
        {
            float al = p3 * isc;
            float mn = fmaxf(m, al);
            float scale = __expf(m - mn), wq = __expf(al - mn);
            s = s * scale + wq;
            a0 = a0 * scale + wq * (v3.x + e3 * we0);
            a1 = a1 * scale + wq * (v3.y + e3 * we1);
            m = mn;
        }
    }
    for (; t < te; ++t) {
        int sn = src_csr[t];
        float eav = ea_csr[t];
        float2 kv = *(const float2*)&k[sn * 128 + c0];
        float2 vv = *(const float2*)&v[sn * 128 + c0];
        float part = q2.x * (kv.x + eav * we0) + q2.y * (kv.y + eav * we1);
        part += __shfl_xor(part, 1, 16);
        part += __shfl_xor(part, 2, 16);
        part += __shfl_xor(part, 4, 16);
        part += __shfl_xor(part, 8, 16);
        float alpha = part * isc;
        float mn = fmaxf(m, alpha);
        float scale = __expf(m - mn), wq = __expf(alpha - mn);
        s = s * scale + wq;
        a0 = a0 * scale + wq * (vv.x + eav * we0);
        a1 = a1 * scale + wq * (vv.y + eav * we1);
        m = mn;
    }
    if (half == 1) {
        ms[nslot][lane] = m; ssb[nslot][lane] = s;
        a0s[nslot][lane] = a0; a1s[nslot][lane] = a1;
    }
    __syncthreads();
    if (half == 0) {
        float mB = ms[nslot][lane], sB = ssb[nslot][lane];
        float b0 = a0s[nslot][lane], b1 = a1s[nslot][lane];
        float mm = fmaxf(m, mB);
        float eA = (m  > -1e30f) ? __expf(m  - mm) : 0.f;
        float eB = (mB > -1e30f) ? __expf(mB - mm) : 0.f;
        float sT = s * eA + sB * eB;
        float o0 = a0 * eA + b0 * eB;
        float o1 = a1 * eA + b1 * eB;
        float inv = (sT > 0.f) ? 1.f / (sT + 1e-16f) : 0.f;
        int o = node * 128 + c0;
        h[o]     += skp[o]     + o0 * inv;
        h[o + 1] += skp[o + 1] + o1 * inv;
    }
}

// ---------------- M[k][m*128+l] = sum_o Wb[o,k,l] * Wm1[o,m]  (m-outer layout!) --------
__global__ __launch_bounds__(256) void k_mprep(const float* __restrict__ Wb,
    const float* __restrict__ Wm1, float* __restrict__ M)
{
    __shared__ float wb_s[64][128];
    __shared__ float wm_s[64][128];
    int tid = threadIdx.x;
    int k = blockIdx.x;
    int mg = tid & 15, lg = tid >> 4;
    int m0 = mg * 8, l0 = lg * 8;
    float acc[8][8] = {};
    for (int oh = 0; oh < 2; ++oh) {
        __syncthreads();
        for (int idx = tid; idx < 8192; idx += 256) {
            int o = idx >> 7, c = idx & 127;
            wb_s[o][c] = Wb[(size_t)(oh * 64 + o) * 16384 + k * 128 + c];
            wm_s[o][c] = Wm1[(oh * 64 + o) * 128 + c];
        }
        __syncthreads();
        for (int o = 0; o < 64; o++) {
            float lv[8], mv[8];
#pragma unroll
            for (int i = 0; i < 8; i++) { lv[i] = wb_s[o][l0 + i]; mv[i] = wm_s[o][m0 + i]; }
#pragma unroll
            for (int li = 0; li < 8; li++)
#pragma unroll
                for (int mi = 0; mi < 8; mi++) acc[li][mi] += lv[li] * mv[mi];
        }
    }
    for (int mi = 0; mi < 8; mi++)
        for (int li = 0; li < 8; li++)
            M[(size_t)k * 16384 + (m0 + mi) * 128 + (l0 + li)] = acc[li][mi];
}

// ---------------- Mt[n][k] (bf16) <- M[k][n] (fp32) ----------------
__global__ __launch_bounds__(256) void k_mtrans(const float* __restrict__ M,
                                                short* __restrict__ Mt)
{
    __shared__ __align__(16) short Ts[64][136];
    int tid = threadIdx.x;
    int n0 = blockIdx.x * 64;
    for (int p = 0; p < 32; p++) {
        int idx = p * 256 + tid;
        int k = idx >> 6, nn = idx & 63;
        Ts[nn][k] = (short)f2bf(M[(size_t)k * 16384 + n0 + nn]);
    }
    __syncthreads();
    for (int p = 0; p < 4; p++) {
        int idx = p * 256 + tid;
        int nn = idx >> 4, s = idx & 15;
        *(int4*)&Mt[(size_t)(n0 + nn) * 128 + s * 8] = *(const int4*)&Ts[nn][s * 8];
    }
}

// ---------------- hb (bf16) <- h (fp32) ----------------
__global__ __launch_bounds__(256) void k_convh(const float* __restrict__ h,
                                               short* __restrict__ hb)
{
    int idx = (blockIdx.x * 256 + threadIdx.x) * 4;
    float4 v = *(const float4*)&h[idx];
    short4 o;
    o.x = (short)f2bf(v.x); o.y = (short)f2bf(v.y);
    o.z = (short)f2bf(v.z); o.w = (short)f2bf(v.w);
    *(short4*)&hb[idx] = o;
}

// ---------------- phase1 MFMA: U[i][n] = sum_k hb[i,k] * Mt[n,k] ----------------
__global__ __launch_bounds__(256) void k_p1(const short* __restrict__ hb,
    const short* __restrict__ Mt, short* __restrict__ U)
{
    __shared__ __align__(16) short As[128][72];
    __shared__ __align__(16) short Bs[128][72];
    int tid = threadIdx.x;
    int n0 = blockIdx.x * 128;
    int i0 = blockIdx.y * 128;
    int w = tid >> 6, lane = tid & 63, c = lane & 15, g = lane >> 4;
    f32x4 acc[2][8] = {};
    for (int kh = 0; kh < 2; kh++) {
        __syncthreads();
        for (int idx = tid; idx < 1024; idx += 256) {
            int r = idx >> 3, s = idx & 7;
            *(int4*)&As[r][s * 8] = *(const int4*)&hb[(i0 + r) * 128 + kh * 64 + s * 8];
            *(int4*)&Bs[r][s * 8] = *(const int4*)&Mt[(size_t)(n0 + r) * 128 + kh * 64 + s * 8];
        }
        __syncthreads();
#pragma unroll
        for (int kk = 0; kk < 2; kk++) {
            int ko = kk * 32 + g * 8;
            bf16x8 a0 = *(const bf16x8*)&As[w * 32 + c][ko];
            bf16x8 a1 = *(const bf16x8*)&As[w * 32 + 16 + c][ko];
#pragma unroll
            for (int nt = 0; nt < 8; nt++) {
                bf16x8 b = *(const bf16x8*)&Bs[nt * 16 + c][ko];
                acc[0][nt] = __builtin_amdgcn_mfma_f32_16x16x32_bf16(a0, b, acc[0][nt], 0, 0, 0);
                acc[1][nt] = __builtin_amdgcn_mfma_f32_16x16x32_bf16(a1, b, acc[1][nt], 0, 0, 0);
            }
        }
    }
#pragma unroll
    for (int it = 0; it < 2; it++)
#pragma unroll
        for (int nt = 0; nt < 8; nt++)
#pragma unroll
            for (int r = 0; r < 4; r++) {
                int i = i0 + w * 32 + it * 16 + g * 4 + r;
                int n = n0 + nt * 16 + c;
                U[(size_t)i * 16384 + n] = (short)f2bf(acc[it][nt][r]);
            }
}

// ---------------- phase2 MFMA: block = (i, j-half); U_i staged once; H frags from L2 ---
__global__ __launch_bounds__(256) void k_p2(const short* __restrict__ hb,
    const short* __restrict__ U, const float* __restrict__ cvec,
    const float* __restrict__ Wm2, const float* __restrict__ bm2,
    float* __restrict__ out)
{
    __shared__ __align__(16) short Us[128][136];
    __shared__ float cvs[128];
    __shared__ float w2s[128][4];
    int tid = threadIdx.x;
    int i = blockIdx.x;
    int jb = blockIdx.y;          // 0..1
    int b = i >> 8;
    int w = tid >> 6, lane = tid & 63, c = lane & 15, g = lane >> 4;
    if (tid < 128) {
        cvs[tid] = cvec[tid];
        *(float4*)&w2s[tid][0] = *(const float4*)&Wm2[tid * 4];
    }
    bf16x8 hf[2][4];
    {
        const short* hrow = hb + (size_t)(b * 256 + jb * 128 + w * 32 + c) * 128;
#pragma unroll
        for (int jt = 0; jt < 2; jt++)
#pragma unroll
            for (int kq = 0; kq < 4; kq++)
                hf[jt][kq] = *(const bf16x8*)(hrow + jt * 16 * 128 + kq * 32 + g * 8);
    }
    for (int idx = tid; idx < 2048; idx += 256) {
        int r = idx >> 4, s = idx & 15;
        *(int4*)&Us[r][s * 8] = *(const int4*)&U[(size_t)i * 16384 + r * 128 + s * 8];
    }
    __syncthreads();
    f32x4 acc[2][8] = {};
#pragma unroll
    for (int kq = 0; kq < 4; kq++) {
        int ko = kq * 32 + g * 8;
#pragma unroll
        for (int mt = 0; mt < 8; mt++) {
            bf16x8 uv = *(const bf16x8*)&Us[mt * 16 + c][ko];
            acc[0][mt] = __builtin_amdgcn_mfma_f32_16x16x32_bf16(uv, hf[0][kq], acc[0][mt], 0, 0, 0);
            acc[1][mt] = __builtin_amdgcn_mfma_f32_16x16x32_bf16(uv, hf[1][kq], acc[1][mt], 0, 0, 0);
        }
    }
    float4 bmv = *(const float4*)&bm2[0];
#pragma unroll
    for (int jt = 0; jt < 2; jt++) {
        float p0 = 0.f, p1 = 0.f, p2 = 0.f, p3 = 0.f;
#pragma unroll
        for (int mt = 0; mt < 8; mt++) {
#pragma unroll
            for (int r = 0; r < 4; r++) {
                int m = mt * 16 + g * 4 + r;
                float y = acc[jt][mt][r] + cvs[m];
                float sv = y * frcp(1.f + __expf(-y));
                p0 += sv * w2s[m][0]; p1 += sv * w2s[m][1];
                p2 += sv * w2s[m][2]; p3 += sv * w2s[m][3];
            }
        }
        p0 += __shfl_xor(p0, 16, 64); p1 += __shfl_xor(p1, 16, 64);
        p2 += __shfl_xor(p2, 16, 64); p3 += __shfl_xor(p3, 16, 64);
        p0 += __shfl_xor(p0, 32, 64); p1 += __shfl_xor(p1, 32, 64);
        p2 += __shfl_xor(p2, 32, 64); p3 += __shfl_xor(p3, 32, 64);
        if (g == 0) {
            int j = jb * 128 + w * 32 + jt * 16 + c;
            float4 o4 = { p0 + bmv.x, p1 + bmv.y, p2 + bmv.z, p3 + bmv.w };
            *(float4*)&out[((size_t)i * 256 + j) * 4] = o4;
        }
    }
}

extern "C" void kernel_launch(void* const* d_in, const int* in_sizes, int n_in,
                              void* d_out, int out_size, void* d_ws, size_t ws_size,
                              hipStream_t stream)
{
    const float* x   = (const float*)d_in[0];
    const int*   ei  = (const int*)d_in[1];
    const void*  tptr= d_in[3];
    const float* tm  = (const float*)d_in[4];
    const float* Wn  = (const float*)d_in[5];
    const float* bn  = (const float*)d_in[6];
    const float* Wee = (const float*)d_in[7];
    const float* bee = (const float*)d_in[8];
    const float* Wt1 = (const float*)d_in[9];
    const float* bt1 = (const float*)d_in[10];
    const float* Wt2 = (const float*)d_in[11];
    const float* bt2 = (const float*)d_in[12];
    const float* Wa  = (const float*)d_in[13];
    const float* ba  = (const float*)d_in[14];
    const float* Wq  = (const float*)d_in[15];
    const float* bq  = (const float*)d_in[16];
    const float* Wk  = (const float*)d_in[17];
    const float* bk  = (const float*)d_in[18];
    const float* Wv  = (const float*)d_in[19];
    const float* bv  = (const float*)d_in[20];
    const float* We  = (const float*)d_in[21];
    const float* Wsk = (const float*)d_in[22];
    const float* bsk = (const float*)d_in[23];
    const float* Wf1 = (const float*)d_in[24];
    const float* bf1 = (const float*)d_in[25];
    const float* Wf2 = (const float*)d_in[26];
    const float* bf2 = (const float*)d_in[27];
    const float* Wb  = (const float*)d_in[28];
    const float* bb  = (const float*)d_in[29];
    const float* Wm1 = (const float*)d_in[30];
    const float* bm1 = (const float*)d_in[31];
    const float* Wm2 = (const float*)d_in[32];
    const float* bm2 = (const float*)d_in[33];
    float* out = (float*)d_out;
    float* ws = (float*)d_ws;

    float* h    = ws + OFF_H;
    float* qb   = ws + OFF_Q;
    float* kb   = ws + OFF_K;
    float* vb   = ws + OFF_V;
    float* skp  = ws + OFF_SKP;
    float* ss   = ws + OFF_SS;
    float* ea   = ws + OFF_EA;
    float* cvec = ws + OFF_CVEC;
    int* iws    = (int*)(ws + OFF_INT);
    int* deg    = iws;
    int* cursor = iws + 1024;
    int* rowptr = iws + 2048;
    int* eorder = iws + 3073;
    int* src_csr   = (int*)(ws + OFF_G);
    float* ea_csr  = ws + OFF_G + 65536;
    float* Mst  = ws + OFF_M;
    short* Ub   = (short*)(ws + OFF_U);
    short* Mtb  = (short*)(ws + OFF_MT);
    short* hbb  = (short*)(ws + OFF_HB);
    float* tmod = ws + OFF_TMOD;
    short* WT   = (short*)(ws + OFF_WB);

    hipMemsetAsync(deg, 0, 2048 * sizeof(int), stream);
    k_tmod<<<1, 1024, 0, stream>>>(tptr, Wt1, bt1, Wt2, bt2, bb, Wm1, bm1, tmod, cvec);
    k_ss<<<12, 256, 0, stream>>>(tmod, Wa, ba, ss);
    k_wtrans<<<192, 256, 0, stream>>>(Wq, Wk, Wv, Wsk, Wf1, Wf2, WT);
    k_input<<<512, 256, 0, stream>>>(x, Wn, bn, h);
    k_edge<<<256, 256, 0, stream>>>(ei, tm, Wee, bee, ea);
    k_count<<<256, 256, 0, stream>>>(ei, deg);
    k_scan<<<1, 1024, 0, stream>>>(deg, rowptr);
    k_scatter<<<256, 256, 0, stream>>>(ei, rowptr, cursor, eorder);
    k_sort2<<<1024, 128, 0, stream>>>(rowptr, eorder);
    k_flat<<<256, 256, 0, stream>>>(ei, ea, eorder, src_csr, ea_csr);

    for (int l = 0; l < LAYERS; l++) {
        const float* ssl = ss + l * 512;
        k_qkvs<<<dim3(8, 4), 256, 0, stream>>>(h, ssl, WT, l,
            bq + l * 128, bk + l * 128, bv + l * 128, bsk + l * 128,
            qb, kb, vb, skp);
        k_attn<<<512, 256, 0, stream>>>(qb, kb, vb, skp, h, src_csr, ea_csr,
                                        We + l * 128, rowptr);
        k_ffn<<<32, 256, 0, stream>>>(h, WT, l, bf1 + l * 256, bf2 + l * 128, ssl + 256);
    }

    k_mprep<<<128, 256, 0, stream>>>(Wb, Wm1, Mst);
    k_mtrans<<<256, 256, 0, stream>>>(Mst, Mtb);
    k_convh<<<128, 256, 0, stream>>>(h, hbb);
    k_p1<<<dim3(128, 8), 256, 0, stream>>>(hbb, Mtb, Ub);
    k_p2<<<dim3(1024, 2), 256, 0, stream>>>(hbb, Ub, cvec, Wm2, bm2, out);
}

// Round 10
// 286.800 us; speedup vs baseline: 5.2750x; 1.2335x over previous
//
#include <hip/hip_runtime.h>
#include <math.h>

#define N_NODES 1024
#define HDIM 128
#define EDGES 65536
#define LAYERS 6

typedef __attribute__((ext_vector_type(8))) short bf16x8;
typedef __attribute__((ext_vector_type(4))) float f32x4;

// workspace float offsets
#define OFF_H     0
#define OFF_Q     131072
#define OFF_K     262144
#define OFF_V     393216
#define OFF_SKP   524288
#define OFF_G     655360       // reused: src_csr (int E) + ea_csr (float E)
#define OFF_SS    917504
#define OFF_EA    920576
#define OFF_CVEC  986112
#define OFF_INT   986240
#define OFF_M     1054912      // fp32 M [128 k][16384 n], n = m*128 + l  (m-outer!)
#define OFF_U     3152064      // bf16 U [1024 i][16384 n]
#define OFF_MT    11540672     // bf16 Mt [16384 n][128 k]
#define OFF_HB    12589248     // bf16 hb [1024][128]
#define OFF_TMOD  12654784     // fp32 tmod [128]
#define OFF_WB    12654912     // bf16 transposed layer weights (786432 shorts)

__device__ __forceinline__ float silu_f(float x) { return x / (1.f + expf(-x)); }
__device__ __forceinline__ float frcp(float x) { return __builtin_amdgcn_rcpf(x); }

__device__ __forceinline__ unsigned short f2bf(float f) {
    unsigned int u = __float_as_uint(f);
    u += 0x7FFFu + ((u >> 16) & 1u);
    return (unsigned short)(u >> 16);
}

// ---------------- setup: emb -> t_mod, cvec (1024 thr, split-K) ----------------
__global__ __launch_bounds__(1024) void k_tmod(const void* tptr,
    const float* __restrict__ Wt1, const float* __restrict__ bt1,
    const float* __restrict__ Wt2, const float* __restrict__ bt2,
    const float* __restrict__ bb, const float* __restrict__ Wm1, const float* __restrict__ bm1,
    float* __restrict__ tmod_g, float* __restrict__ cvec)
{
    __shared__ float emb_s[256];
    __shared__ float part[8][128];
    __shared__ float tmp1_s[128];
    int tid = threadIdx.x;
    int iv = *(const int*)tptr;
    float fv = __int_as_float(iv);
    float tval = (iv > -1000000 && iv < 1000000) ? (float)iv : fv;
    if (tid < 256) {
        int fi = tid & 127;
        float fr = expf(-logf(10000.f) * (float)fi / 128.f);
        float ta = tval * fr;
        emb_s[tid] = (tid < 128) ? cosf(ta) : sinf(ta);
    }
    __syncthreads();
    {
        int col = tid & 127, sl = tid >> 7;
        float p = 0.f;
#pragma unroll 8
        for (int i = sl * 32; i < sl * 32 + 32; i++) p += emb_s[i] * Wt1[i * 128 + col];
        part[sl][col] = p;
    }
    __syncthreads();
    if (tid < 128) {
        float a = bt1[tid];
#pragma unroll
        for (int s = 0; s < 8; s++) a += part[s][tid];
        tmp1_s[tid] = silu_f(a);
    }
    __syncthreads();
    {
        int col = tid & 127, sl = tid >> 7;
        float p = 0.f;
#pragma unroll 8
        for (int i = sl * 16; i < sl * 16 + 16; i++) p += tmp1_s[i] * Wt2[i * 128 + col];
        part[sl][col] = p;
    }
    __syncthreads();
    if (tid < 128) {
        float a = bt2[tid];
#pragma unroll
        for (int s = 0; s < 8; s++) a += part[s][tid];
        tmod_g[tid] = silu_f(a);
    }
    __syncthreads();
    {
        int col = tid & 127, sl = tid >> 7;
        float p = 0.f;
#pragma unroll 8
        for (int i = sl * 16; i < sl * 16 + 16; i++) p += bb[i] * Wm1[i * 128 + col];
        part[sl][col] = p;
    }
    __syncthreads();
    if (tid < 128) {
        float a = bm1[tid];
#pragma unroll
        for (int s = 0; s < 8; s++) a += part[s][tid];
        cvec[tid] = a;
    }
}

// ---------------- parallel ss projection ----------------
__global__ __launch_bounds__(256) void k_ss(const float* __restrict__ tmod_g,
    const float* __restrict__ Wa, const float* __restrict__ ba, float* __restrict__ ss_all)
{
    __shared__ float tm_s[128];
    int tid = threadIdx.x;
    if (tid < 128) tm_s[tid] = tmod_g[tid];
    __syncthreads();
    int idx = blockIdx.x * 256 + tid;       // < 3072
    int l = idx >> 9, j = idx & 511;
    float a = ba[l * 512 + j];
    const float* w = Wa + l * 65536 + j;
#pragma unroll 4
    for (int k = 0; k < 128; k++) a += tm_s[k] * w[k * 512];
    ss_all[idx] = a;
}

// ---------------- weight transpose+bf16: 192 tiles of 64x64 ----------------
__global__ __launch_bounds__(256) void k_wtrans(
    const float* __restrict__ Wq, const float* __restrict__ Wk,
    const float* __restrict__ Wv, const float* __restrict__ Wsk,
    const float* __restrict__ Wf1, const float* __restrict__ Wf2,
    short* __restrict__ WT)
{
    __shared__ __align__(16) short T[64][80];
    int t = blockIdx.x;
    int tid = threadIdx.x;
    const float* src; short* dst; int K, N, kt, nt;
    if (t < 96) {
        int mat = t >> 2, sub = t & 3;
        int l = mat >> 2, m = mat & 3;
        src = (m == 0 ? Wq : m == 1 ? Wk : m == 2 ? Wv : Wsk) + l * 16384;
        dst = WT + (size_t)mat * 16384;
        K = 128; N = 128; kt = sub >> 1; nt = sub & 1;
    } else if (t < 144) {
        int i = t - 96; int l = i >> 3, sub = i & 7;
        src = Wf1 + l * 32768;
        dst = WT + 24 * 16384 + (size_t)l * 32768;
        K = 128; N = 256; kt = sub & 1; nt = sub >> 1;
    } else {
        int i = t - 144; int l = i >> 3, sub = i & 7;
        src = Wf2 + l * 32768;
        dst = WT + 24 * 16384 + 6 * 32768 + (size_t)l * 32768;
        K = 256; N = 128; kt = sub >> 1; nt = sub & 1;
    }
    int k0 = kt * 64, n0 = nt * 64;
    for (int p = 0; p < 16; p++) {
        int idx = p * 256 + tid;
        int kk = idx >> 6, nn = idx & 63;
        T[nn][kk] = (short)f2bf(src[(k0 + kk) * N + n0 + nn]);
    }
    __syncthreads();
    for (int p = 0; p < 2; p++) {
        int idx = p * 256 + tid;
        int nn = idx >> 3, sq = idx & 7;
        *(int4*)&dst[(size_t)(n0 + nn) * K + k0 + sq * 8] = *(const int4*)&T[nn][sq * 8];
    }
}

// ---------------- h = x @ Wn + bn  (K=5) ----------------
__global__ __launch_bounds__(256) void k_input(const float* __restrict__ x,
    const float* __restrict__ Wn, const float* __restrict__ bn, float* __restrict__ h)
{
    int idx = blockIdx.x * 256 + threadIdx.x;  // < 131072
    int i = idx >> 7, j = idx & 127;
    float acc = bn[j];
#pragma unroll
    for (int kk = 0; kk < 5; kk++) acc += x[i * 5 + kk] * Wn[kk * 128 + j];
    h[idx] = acc;
}

// ---------------- edge_attr + degree count (merged) ----------------
__global__ __launch_bounds__(256) void k_edge_count(const int* __restrict__ ei,
    const float* __restrict__ tm, const float* __restrict__ Wee, const float* __restrict__ bee,
    float* __restrict__ ea, int* __restrict__ deg)
{
    int e = blockIdx.x * 256 + threadIdx.x;
    int s = ei[e], d = ei[EDGES + e];
    ea[e] = tm[s * N_NODES + d] * Wee[0] + bee[0];
    atomicAdd(&deg[d], 1);
}

__global__ __launch_bounds__(1024) void k_scan(const int* __restrict__ deg, int* __restrict__ rowptr)
{
    __shared__ int tmp[1024];
    int tid = threadIdx.x;
    tmp[tid] = deg[tid];
    __syncthreads();
    for (int off = 1; off < 1024; off <<= 1) {
        int vv = (tid >= off) ? tmp[tid - off] : 0;
        __syncthreads();
        tmp[tid] += vv;
        __syncthreads();
    }
    rowptr[tid + 1] = tmp[tid];
    if (tid == 0) rowptr[0] = 0;
}

__global__ __launch_bounds__(256) void k_scatter(const int* __restrict__ ei,
    const int* __restrict__ rowptr, int* __restrict__ cursor, int* __restrict__ eorder)
{
    int e = blockIdx.x * 256 + threadIdx.x;
    int d = ei[EDGES + e];
    int pos = atomicAdd(&cursor[d], 1);
    eorder[rowptr[d] + pos] = e;
}

// ---------------- per-node bitonic sort + CSR flatten (fused) ----------------
__global__ __launch_bounds__(128) void k_sort2(const int* __restrict__ rowptr,
    int* __restrict__ eorder, const int* __restrict__ ei, const float* __restrict__ ea,
    int* __restrict__ src_csr, float* __restrict__ ea_csr)
{
    __shared__ int key[256];
    int node = blockIdx.x;
    int tid = threadIdx.x;
    int beg = rowptr[node], end = rowptr[node + 1];
    int n = end - beg;
    if (n <= 256) {
        for (int i = tid; i < 256; i += 128) key[i] = (i < n) ? eorder[beg + i] : 0x7FFFFFFF;
        __syncthreads();
        for (int k = 2; k <= 256; k <<= 1) {
            for (int j = k >> 1; j > 0; j >>= 1) {
                int i = ((tid / j) * 2 * j) + (tid % j);
                int l = i + j;
                bool up = ((i & k) == 0);
                int a = key[i], b = key[l];
                if ((a > b) == up) { key[i] = b; key[l] = a; }
                __syncthreads();
            }
        }
        for (int i = tid; i < n; i += 128) {
            int e = key[i];
            src_csr[beg + i] = ei[e];
            ea_csr[beg + i] = ea[e];
        }
    } else {
        if (tid == 0) {
            for (int i = beg + 1; i < end; ++i) {
                int kk = eorder[i];
                int j = i - 1;
                while (j >= beg && eorder[j] > kk) { eorder[j + 1] = eorder[j]; --j; }
                eorder[j + 1] = kk;
            }
        }
        __syncthreads();
        for (int i = tid; i < n; i += 128) {
            int e = eorder[beg + i];
            src_csr[beg + i] = ei[e];
            ea_csr[beg + i] = ea[e];
        }
    }
}

// ---------------- MFMA qkvs: 32 rows/block, grid (32, 4) ----------------
__global__ __launch_bounds__(256) void k_qkvs(const float* __restrict__ h,
    const float* __restrict__ ss, const short* __restrict__ WT, int layer,
    const float* __restrict__ bq, const float* __restrict__ bk,
    const float* __restrict__ bv, const float* __restrict__ bsk,
    float* __restrict__ q, float* __restrict__ k, float* __restrict__ v, float* __restrict__ skp)
{
    __shared__ __align__(16) short As[32][136];
    __shared__ float shs[128], scs[128];
    int tid = threadIdx.x;
    int r0 = blockIdx.x * 32;
    int mat = blockIdx.y;
    if (tid < 128) { shs[tid] = ss[tid]; scs[tid] = ss[128 + tid]; }
    __syncthreads();
    {   // LN+mod -> bf16 As. 8 threads per row, 16 cols each.
        int row = tid >> 3, o = tid & 7;
        const float* hr = h + (size_t)(r0 + row) * 128 + o * 16;
        float s = 0.f, s2 = 0.f;
#pragma unroll
        for (int j = 0; j < 4; j++) {
            float4 vv = *(const float4*)&hr[j * 4];
            s += vv.x + vv.y + vv.z + vv.w;
            s2 += vv.x * vv.x + vv.y * vv.y + vv.z * vv.z + vv.w * vv.w;
        }
        s += __shfl_xor(s, 1, 64); s2 += __shfl_xor(s2, 1, 64);
        s += __shfl_xor(s, 2, 64); s2 += __shfl_xor(s2, 2, 64);
        s += __shfl_xor(s, 4, 64); s2 += __shfl_xor(s2, 4, 64);
        float mu = s * (1.f / 128.f);
        float var = s2 * (1.f / 128.f) - mu * mu;
        float rs = rsqrtf(var + 1e-5f);
#pragma unroll
        for (int j = 0; j < 4; j++) {
            float4 vv = *(const float4*)&hr[j * 4];
            int cb = o * 16 + j * 4;
            short4 o4;
            o4.x = (short)f2bf((vv.x - mu) * rs * (1.f + scs[cb])     + shs[cb]);
            o4.y = (short)f2bf((vv.y - mu) * rs * (1.f + scs[cb + 1]) + shs[cb + 1]);
            o4.z = (short)f2bf((vv.z - mu) * rs * (1.f + scs[cb + 2]) + shs[cb + 2]);
            o4.w = (short)f2bf((vv.w - mu) * rs * (1.f + scs[cb + 3]) + shs[cb + 3]);
            *(short4*)&As[row][cb] = o4;
        }
    }
    __syncthreads();
    int w = tid >> 6, lane = tid & 63, c = lane & 15, g = lane >> 4;
    const short* Wm = WT + (size_t)(layer * 4 + mat) * 16384;
    f32x4 acc[2][2] = {};
#pragma unroll
    for (int kq = 0; kq < 4; kq++) {
        int ko = kq * 32 + g * 8;
        bf16x8 a0 = *(const bf16x8*)&As[c][ko];
        bf16x8 a1 = *(const bf16x8*)&As[16 + c][ko];
#pragma unroll
        for (int nt = 0; nt < 2; nt++) {
            bf16x8 bfr = *(const bf16x8*)&Wm[(size_t)(w * 32 + nt * 16 + c) * 128 + ko];
            acc[0][nt] = __builtin_amdgcn_mfma_f32_16x16x32_bf16(a0, bfr, acc[0][nt], 0, 0, 0);
            acc[1][nt] = __builtin_amdgcn_mfma_f32_16x16x32_bf16(a1, bfr, acc[1][nt], 0, 0, 0);
        }
    }
    const float* bias; float* out;
    switch (mat) {
        case 0:  bias = bq;  out = q;   break;
        case 1:  bias = bk;  out = k;   break;
        case 2:  bias = bv;  out = v;   break;
        default: bias = bsk; out = skp; break;
    }
#pragma unroll
    for (int it = 0; it < 2; it++)
#pragma unroll
        for (int nt = 0; nt < 2; nt++) {
            int n = w * 32 + nt * 16 + c;
            float bv2 = bias[n];
#pragma unroll
            for (int r = 0; r < 4; r++) {
                int i = r0 + it * 16 + g * 4 + r;
                out[(size_t)i * 128 + n] = acc[it][nt][r] + bv2;
            }
        }
}

// ---------------- MFMA FFN: 16 rows/block, grid 64; last layer also writes hb ---------
__global__ __launch_bounds__(256) void k_ffn(float* __restrict__ h,
    const short* __restrict__ WT, int layer,
    const float* __restrict__ bf1, const float* __restrict__ bf2,
    const float* __restrict__ ss2, short* __restrict__ hb, int last)
{
    __shared__ __align__(16) short As[16][136];
    __shared__ __align__(16) short Gs[16][264];
    __shared__ float shs[128], scs[128];
    int tid = threadIdx.x;
    int r0 = blockIdx.x * 16;
    if (tid < 128) { shs[tid] = ss2[tid]; scs[tid] = ss2[128 + tid]; }
    __syncthreads();
    {   // LN+mod: 16 threads per row, 8 cols each
        int row = tid >> 4, o = tid & 15;
        const float* hr = h + (size_t)(r0 + row) * 128 + o * 8;
        float s = 0.f, s2 = 0.f;
#pragma unroll
        for (int j = 0; j < 2; j++) {
            float4 vv = *(const float4*)&hr[j * 4];
            s += vv.x + vv.y + vv.z + vv.w;
            s2 += vv.x * vv.x + vv.y * vv.y + vv.z * vv.z + vv.w * vv.w;
        }
        s += __shfl_xor(s, 1, 64); s2 += __shfl_xor(s2, 1, 64);
        s += __shfl_xor(s, 2, 64); s2 += __shfl_xor(s2, 2, 64);
        s += __shfl_xor(s, 4, 64); s2 += __shfl_xor(s2, 4, 64);
        s += __shfl_xor(s, 8, 64); s2 += __shfl_xor(s2, 8, 64);
        float mu = s * (1.f / 128.f);
        float var = s2 * (1.f / 128.f) - mu * mu;
        float rs = rsqrtf(var + 1e-5f);
#pragma unroll
        for (int j = 0; j < 2; j++) {
            float4 vv = *(const float4*)&hr[j * 4];
            int cb = o * 8 + j * 4;
            short4 o4;
            o4.x = (short)f2bf((vv.x - mu) * rs * (1.f + scs[cb])     + shs[cb]);
            o4.y = (short)f2bf((vv.y - mu) * rs * (1.f + scs[cb + 1]) + shs[cb + 1]);
            o4.z = (short)f2bf((vv.z - mu) * rs * (1.f + scs[cb + 2]) + shs[cb + 2]);
            o4.w = (short)f2bf((vv.w - mu) * rs * (1.f + scs[cb + 3]) + shs[cb + 3]);
            *(short4*)&As[row][cb] = o4;
        }
    }
    __syncthreads();
    int w = tid >> 6, lane = tid & 63, c = lane & 15, g = lane >> 4;
    const short* W1 = WT + 24 * 16384 + (size_t)layer * 32768;
    const short* W2 = WT + 24 * 16384 + 6 * 32768 + (size_t)layer * 32768;
    {   // f1: wave w covers cols w*64 + nt*16 + c (nt 0..3)
        f32x4 acc[4] = {};
#pragma unroll
        for (int kq = 0; kq < 4; kq++) {
            int ko = kq * 32 + g * 8;
            bf16x8 a0 = *(const bf16x8*)&As[c][ko];
#pragma unroll
            for (int nt = 0; nt < 4; nt++) {
                bf16x8 bfr = *(const bf16x8*)&W1[(size_t)(w * 64 + nt * 16 + c) * 128 + ko];
                acc[nt] = __builtin_amdgcn_mfma_f32_16x16x32_bf16(a0, bfr, acc[nt], 0, 0, 0);
            }
        }
#pragma unroll
        for (int nt = 0; nt < 4; nt++) {
            int n = w * 64 + nt * 16 + c;
            float bv = bf1[n];
#pragma unroll
            for (int r = 0; r < 4; r++) {
                float y = acc[nt][r] + bv;
                float gl = 0.5f * y * (1.f + erff(y * 0.70710678118654752f));
                Gs[g * 4 + r][n] = (short)f2bf(gl);
            }
        }
    }
    __syncthreads();
    {   // f2: K=256; wave w covers cols w*32 + nt2*16 + c
        f32x4 acc2[2] = {};
#pragma unroll
        for (int kq = 0; kq < 8; kq++) {
            int ko = kq * 32 + g * 8;
            bf16x8 a0 = *(const bf16x8*)&Gs[c][ko];
#pragma unroll
            for (int nt2 = 0; nt2 < 2; nt2++) {
                bf16x8 bfr = *(const bf16x8*)&W2[(size_t)(w * 32 + nt2 * 16 + c) * 256 + ko];
                acc2[nt2] = __builtin_amdgcn_mfma_f32_16x16x32_bf16(a0, bfr, acc2[nt2], 0, 0, 0);
            }
        }
#pragma unroll
        for (int nt2 = 0; nt2 < 2; nt2++) {
            int n = w * 32 + nt2 * 16 + c;
            float bv = bf2[n];
#pragma unroll
            for (int r = 0; r < 4; r++) {
                int i = r0 + g * 4 + r;
                float nv = h[(size_t)i * 128 + n] + acc2[nt2][r] + bv;
                h[(size_t)i * 128 + n] = nv;
                if (last) hb[(size_t)i * 128 + n] = (short)f2bf(nv);
            }
        }
    }
}

// ---------------- attention: 2 waves per node, online-softmax halves + merge ----------
__global__ __launch_bounds__(256) void k_attn(const float* __restrict__ q,
    const float* __restrict__ k, const float* __restrict__ v,
    const float* __restrict__ skp, float* __restrict__ h,
    const int* __restrict__ src_csr, const float* __restrict__ ea_csr,
    const float* __restrict__ We_l, const int* __restrict__ rowptr)
{
    __shared__ float ms[2][64], ssb[2][64], a0s[2][64], a1s[2][64];
    int tid = threadIdx.x;
    int wid = tid >> 6;            // 0..3
    int lane = tid & 63;
    int nslot = wid >> 1;          // 0..1
    int half = wid & 1;
    int node = blockIdx.x * 2 + nslot;
    int c0 = lane * 2;
    float2 q2 = *(const float2*)&q[node * 128 + c0];
    float we0 = We_l[c0], we1 = We_l[c0 + 1];
    int beg = rowptr[node], end = rowptr[node + 1];
    int n = end - beg;
    int mid = beg + ((n + 1) >> 1);
    int tb = half ? mid : beg;
    int te = half ? end : mid;
    float m = -INFINITY, s = 0.f, a0 = 0.f, a1 = 0.f;
    const float isc = 0.17677669529663687f;  // 1/sqrt(32)

    int t = tb;
    for (; t + 3 < te; t += 4) {
        int sn0 = src_csr[t],     sn1 = src_csr[t + 1];
        int sn2 = src_csr[t + 2], sn3 = src_csr[t + 3];
        float e0 = ea_csr[t],     e1 = ea_csr[t + 1];
        float e2 = ea_csr[t + 2], e3 = ea_csr[t + 3];
        float2 k0 = *(const float2*)&k[sn0 * 128 + c0];
        float2 k1 = *(const float2*)&k[sn1 * 128 + c0];
        float2 k2 = *(const float2*)&k[sn2 * 128 + c0];
        float2 k3 = *(const float2*)&k[sn3 * 128 + c0];
        float2 v0 = *(const float2*)&v[sn0 * 128 + c0];
        float2 v1 = *(const float2*)&v[sn1 * 128 + c0];
        float2 v2 = *(const float2*)&v[sn2 * 128 + c0];
        float2 v3 = *(const float2*)&v[sn3 * 128 + c0];
        float p0 = q2.x * (k0.x + e0 * we0) + q2.y * (k0.y + e0 * we1);
        float p1 = q2.x * (k1.x + e1 * we0) + q2.y * (k1.y + e1 * we1);
        float p2 = q2.x * (k2.x + e2 * we0) + q2.y * (k2.y + e2 * we1);
        float p3 = q2.x * (k3.x + e3 * we0) + q2.y * (k3.y + e3 * we1);
        p0 += __shfl_xor(p0, 1, 16); p1 += __shfl_xor(p1, 1, 16);
        p2 += __shfl_xor(p2, 1, 16); p3 += __shfl_xor(p3, 1, 16);
        p0 += __shfl_xor(p0, 2, 16); p1 += __shfl_xor(p1, 2, 16);
        p2 += __shfl_xor(p2, 2, 16); p3 += __shfl_xor(p3, 2, 16);
        p0 += __shfl_xor(p0, 4, 16); p1 += __shfl_xor(p1, 4, 16);
        p2 += __shfl_xor(p2, 4, 16); p3 += __shfl_xor(p3, 4, 16);
        p0 += __shfl_xor(p0, 8, 16); p1 += __shfl_xor(p1, 8, 16);
        p2 += __shfl_xor(p2, 8, 16); p3 += __shfl_xor(p3, 8, 16);
        {
            float al = p0 * isc;
            float mn = fmaxf(m, al);
            float scale = __expf(m - mn), wq = __expf(al - mn);
            s = s * scale + wq;
            a0 = a0 * scale + wq * (v0.x + e0 * we0);
            a1 = a1 * scale + wq * (v0.y + e0 * we1);
            m = mn;
        }
        {
            float al = p1 * isc;
            float mn = fmaxf(m, al);
            float scale = __expf(m - mn), wq = __expf(al - mn);
            s = s * scale + wq;
            a0 = a0 * scale + wq * (v1.x + e1 * we0);
            a1 = a1 * scale + wq * (v1.y + e1 * we1);
            m = mn;
        }
        {
            float al = p2 * isc;
            float mn = fmaxf(m, al);
            float scale = __expf(m - mn), wq = __expf(al - mn);
            s = s * scale + wq;
            a0 = a0 * scale + wq * (v2.x + e2 * we0);
            a1 = a1 * scale + wq * (v2.y + e2 * we1);
            m = mn;
        }
        {
            float al = p3 * isc;
            float mn = fmaxf(m, al);
            float scale = __expf(m - mn), wq = __expf(al - mn);
            s = s * scale + wq;
            a0 = a0 * scale + wq * (v3.x + e3 * we0);
            a1 = a1 * scale + wq * (v3.y + e3 * we1);
            m = mn;
        }
    }
    for (; t < te; ++t) {
        int sn = src_csr[t];
        float eav = ea_csr[t];
        float2 kv = *(const float2*)&k[sn * 128 + c0];
        float2 vv = *(const float2*)&v[sn * 128 + c0];
        float part = q2.x * (kv.x + eav * we0) + q2.y * (kv.y + eav * we1);
        part += __shfl_xor(part, 1, 16);
        part += __shfl_xor(part, 2, 16);
        part += __shfl_xor(part, 4, 16);
        part += __shfl_xor(part, 8, 16);
        float alpha = part * isc;
        float mn = fmaxf(m, alpha);
        float scale = __expf(m - mn), wq = __expf(alpha - mn);
        s = s * scale + wq;
        a0 = a0 * scale + wq * (vv.x + eav * we0);
        a1 = a1 * scale + wq * (vv.y + eav * we1);
        m = mn;
    }
    if (half == 1) {
        ms[nslot][lane] = m; ssb[nslot][lane] = s;
        a0s[nslot][lane] = a0; a1s[nslot][lane] = a1;
    }
    __syncthreads();
    if (half == 0) {
        float mB = ms[nslot][lane], sB = ssb[nslot][lane];
        float b0 = a0s[nslot][lane], b1 = a1s[nslot][lane];
        float mm = fmaxf(m, mB);
        float eA = (m  > -1e30f) ? __expf(m  - mm) : 0.f;
        float eB = (mB > -1e30f) ? __expf(mB - mm) : 0.f;
        float sT = s * eA + sB * eB;
        float o0 = a0 * eA + b0 * eB;
        float o1 = a1 * eA + b1 * eB;
        float inv = (sT > 0.f) ? 1.f / (sT + 1e-16f) : 0.f;
        int o = node * 128 + c0;
        h[o]     += skp[o]     + o0 * inv;
        h[o + 1] += skp[o + 1] + o1 * inv;
    }
}

// ---------------- M[k][m*128+l] = sum_o Wb[o,k,l] * Wm1[o,m]  (m-outer layout!) --------
__global__ __launch_bounds__(256) void k_mprep(const float* __restrict__ Wb,
    const float* __restrict__ Wm1, float* __restrict__ M)
{
    __shared__ float wb_s[64][128];
    __shared__ float wm_s[64][128];
    int tid = threadIdx.x;
    int k = blockIdx.x;
    int mg = tid & 15, lg = tid >> 4;
    int m0 = mg * 8, l0 = lg * 8;
    float acc[8][8] = {};
    for (int oh = 0; oh < 2; ++oh) {
        __syncthreads();
        for (int idx = tid; idx < 8192; idx += 256) {
            int o = idx >> 7, c = idx & 127;
            wb_s[o][c] = Wb[(size_t)(oh * 64 + o) * 16384 + k * 128 + c];
            wm_s[o][c] = Wm1[(oh * 64 + o) * 128 + c];
        }
        __syncthreads();
        for (int o = 0; o < 64; o++) {
            float lv[8], mv[8];
#pragma unroll
            for (int i = 0; i < 8; i++) { lv[i] = wb_s[o][l0 + i]; mv[i] = wm_s[o][m0 + i]; }
#pragma unroll
            for (int li = 0; li < 8; li++)
#pragma unroll
                for (int mi = 0; mi < 8; mi++) acc[li][mi] += lv[li] * mv[mi];
        }
    }
    for (int mi = 0; mi < 8; mi++)
        for (int li = 0; li < 8; li++)
            M[(size_t)k * 16384 + (m0 + mi) * 128 + (l0 + li)] = acc[li][mi];
}

// ---------------- Mt[n][k] (bf16) <- M[k][n] (fp32) ----------------
__global__ __launch_bounds__(256) void k_mtrans(const float* __restrict__ M,
                                                short* __restrict__ Mt)
{
    __shared__ __align__(16) short Ts[64][136];
    int tid = threadIdx.x;
    int n0 = blockIdx.x * 64;
    for (int p = 0; p < 32; p++) {
        int idx = p * 256 + tid;
        int k = idx >> 6, nn = idx & 63;
        Ts[nn][k] = (short)f2bf(M[(size_t)k * 16384 + n0 + nn]);
    }
    __syncthreads();
    for (int p = 0; p < 4; p++) {
        int idx = p * 256 + tid;
        int nn = idx >> 4, s = idx & 15;
        *(int4*)&Mt[(size_t)(n0 + nn) * 128 + s * 8] = *(const int4*)&Ts[nn][s * 8];
    }
}

// ---------------- phase1 MFMA: U[i][n] = sum_k hb[i,k] * Mt[n,k] ----------------
__global__ __launch_bounds__(256) void k_p1(const short* __restrict__ hb,
    const short* __restrict__ Mt, short* __restrict__ U)
{
    __shared__ __align__(16) short As[128][72];
    __shared__ __align__(16) short Bs[128][72];
    int tid = threadIdx.x;
    int n0 = blockIdx.x * 128;
    int i0 = blockIdx.y * 128;
    int w = tid >> 6, lane = tid & 63, c = lane & 15, g = lane >> 4;
    f32x4 acc[2][8] = {};
    for (int kh = 0; kh < 2; kh++) {
        __syncthreads();
        for (int idx = tid; idx < 1024; idx += 256) {
            int r = idx >> 3, s = idx & 7;
            *(int4*)&As[r][s * 8] = *(const int4*)&hb[(i0 + r) * 128 + kh * 64 + s * 8];
            *(int4*)&Bs[r][s * 8] = *(const int4*)&Mt[(size_t)(n0 + r) * 128 + kh * 64 + s * 8];
        }
        __syncthreads();
#pragma unroll
        for (int kk = 0; kk < 2; kk++) {
            int ko = kk * 32 + g * 8;
            bf16x8 a0 = *(const bf16x8*)&As[w * 32 + c][ko];
            bf16x8 a1 = *(const bf16x8*)&As[w * 32 + 16 + c][ko];
#pragma unroll
            for (int nt = 0; nt < 8; nt++) {
                bf16x8 b = *(const bf16x8*)&Bs[nt * 16 + c][ko];
                acc[0][nt] = __builtin_amdgcn_mfma_f32_16x16x32_bf16(a0, b, acc[0][nt], 0, 0, 0);
                acc[1][nt] = __builtin_amdgcn_mfma_f32_16x16x32_bf16(a1, b, acc[1][nt], 0, 0, 0);
            }
        }
    }
#pragma unroll
    for (int it = 0; it < 2; it++)
#pragma unroll
        for (int nt = 0; nt < 8; nt++)
#pragma unroll
            for (int r = 0; r < 4; r++) {
                int i = i0 + w * 32 + it * 16 + g * 4 + r;
                int n = n0 + nt * 16 + c;
                U[(size_t)i * 16384 + n] = (short)f2bf(acc[it][nt][r]);
            }
}

// ---------------- phase2 MFMA: block = (i, j-half); U_i staged once; H frags from L2 ---
__global__ __launch_bounds__(256) void k_p2(const short* __restrict__ hb,
    const short* __restrict__ U, const float* __restrict__ cvec,
    const float* __restrict__ Wm2, const float* __restrict__ bm2,
    float* __restrict__ out)
{
    __shared__ __align__(16) short Us[128][136];
    __shared__ float cvs[128];
    __shared__ float w2s[128][4];
    int tid = threadIdx.x;
    int i = blockIdx.x;
    int jb = blockIdx.y;          // 0..1
    int b = i >> 8;
    int w = tid >> 6, lane = tid & 63, c = lane & 15, g = lane >> 4;
    if (tid < 128) {
        cvs[tid] = cvec[tid];
        *(float4*)&w2s[tid][0] = *(const float4*)&Wm2[tid * 4];
    }
    bf16x8 hf[2][4];
    {
        const short* hrow = hb + (size_t)(b * 256 + jb * 128 + w * 32 + c) * 128;
#pragma unroll
        for (int jt = 0; jt < 2; jt++)
#pragma unroll
            for (int kq = 0; kq < 4; kq++)
                hf[jt][kq] = *(const bf16x8*)(hrow + jt * 16 * 128 + kq * 32 + g * 8);
    }
    for (int idx = tid; idx < 2048; idx += 256) {
        int r = idx >> 4, s = idx & 15;
        *(int4*)&Us[r][s * 8] = *(const int4*)&U[(size_t)i * 16384 + r * 128 + s * 8];
    }
    __syncthreads();
    f32x4 acc[2][8] = {};
#pragma unroll
    for (int kq = 0; kq < 4; kq++) {
        int ko = kq * 32 + g * 8;
#pragma unroll
        for (int mt = 0; mt < 8; mt++) {
            bf16x8 uv = *(const bf16x8*)&Us[mt * 16 + c][ko];
            acc[0][mt] = __builtin_amdgcn_mfma_f32_16x16x32_bf16(uv, hf[0][kq], acc[0][mt], 0, 0, 0);
            acc[1][mt] = __builtin_amdgcn_mfma_f32_16x16x32_bf16(uv, hf[1][kq], acc[1][mt], 0, 0, 0);
        }
    }
    float4 bmv = *(const float4*)&bm2[0];
#pragma unroll
    for (int jt = 0; jt < 2; jt++) {
        float p0 = 0.f, p1 = 0.f, p2 = 0.f, p3 = 0.f;
#pragma unroll
        for (int mt = 0; mt < 8; mt++) {
#pragma unroll
            for (int r = 0; r < 4; r++) {
                int m = mt * 16 + g * 4 + r;
                float y = acc[jt][mt][r] + cvs[m];
                float sv = y * frcp(1.f + __expf(-y));
                p0 += sv * w2s[m][0]; p1 += sv * w2s[m][1];
                p2 += sv * w2s[m][2]; p3 += sv * w2s[m][3];
            }
        }
        p0 += __shfl_xor(p0, 16, 64); p1 += __shfl_xor(p1, 16, 64);
        p2 += __shfl_xor(p2, 16, 64); p3 += __shfl_xor(p3, 16, 64);
        p0 += __shfl_xor(p0, 32, 64); p1 += __shfl_xor(p1, 32, 64);
        p2 += __shfl_xor(p2, 32, 64); p3 += __shfl_xor(p3, 32, 64);
        if (g == 0) {
            int j = jb * 128 + w * 32 + jt * 16 + c;
            float4 o4 = { p0 + bmv.x, p1 + bmv.y, p2 + bmv.z, p3 + bmv.w };
            *(float4*)&out[((size_t)i * 256 + j) * 4] = o4;
        }
    }
}

extern "C" void kernel_launch(void* const* d_in, const int* in_sizes, int n_in,
                              void* d_out, int out_size, void* d_ws, size_t ws_size,
                              hipStream_t stream)
{
    const float* x   = (const float*)d_in[0];
    const int*   ei  = (const int*)d_in[1];
    const void*  tptr= d_in[3];
    const float* tm  = (const float*)d_in[4];
    const float* Wn  = (const float*)d_in[5];
    const float* bn  = (const float*)d_in[6];
    const float* Wee = (const float*)d_in[7];
    const float* bee = (const float*)d_in[8];
    const float* Wt1 = (const float*)d_in[9];
    const float* bt1 = (const float*)d_in[10];
    const float* Wt2 = (const float*)d_in[11];
    const float* bt2 = (const float*)d_in[12];
    const float* Wa  = (const float*)d_in[13];
    const float* ba  = (const float*)d_in[14];
    const float* Wq  = (const float*)d_in[15];
    const float* bq  = (const float*)d_in[16];
    const float* Wk  = (const float*)d_in[17];
    const float* bk  = (const float*)d_in[18];
    const float* Wv  = (const float*)d_in[19];
    const float* bv  = (const float*)d_in[20];
    const float* We  = (const float*)d_in[21];
    const float* Wsk = (const float*)d_in[22];
    const float* bsk = (const float*)d_in[23];
    const float* Wf1 = (const float*)d_in[24];
    const float* bf1 = (const float*)d_in[25];
    const float* Wf2 = (const float*)d_in[26];
    const float* bf2 = (const float*)d_in[27];
    const float* Wb  = (const float*)d_in[28];
    const float* bb  = (const float*)d_in[29];
    const float* Wm1 = (const float*)d_in[30];
    const float* bm1 = (const float*)d_in[31];
    const float* Wm2 = (const float*)d_in[32];
    const float* bm2 = (const float*)d_in[33];
    float* out = (float*)d_out;
    float* ws = (float*)d_ws;

    float* h    = ws + OFF_H;
    float* qb   = ws + OFF_Q;
    float* kb   = ws + OFF_K;
    float* vb   = ws + OFF_V;
    float* skp  = ws + OFF_SKP;
    float* ss   = ws + OFF_SS;
    float* ea   = ws + OFF_EA;
    float* cvec = ws + OFF_CVEC;
    int* iws    = (int*)(ws + OFF_INT);
    int* deg    = iws;
    int* cursor = iws + 1024;
    int* rowptr = iws + 2048;
    int* eorder = iws + 3073;
    int* src_csr   = (int*)(ws + OFF_G);
    float* ea_csr  = ws + OFF_G + 65536;
    float* Mst  = ws + OFF_M;
    short* Ub   = (short*)(ws + OFF_U);
    short* Mtb  = (short*)(ws + OFF_MT);
    short* hbb  = (short*)(ws + OFF_HB);
    float* tmod = ws + OFF_TMOD;
    short* WT   = (short*)(ws + OFF_WB);

    hipMemsetAsync(deg, 0, 2048 * sizeof(int), stream);
    k_tmod<<<1, 1024, 0, stream>>>(tptr, Wt1, bt1, Wt2, bt2, bb, Wm1, bm1, tmod, cvec);
    k_ss<<<12, 256, 0, stream>>>(tmod, Wa, ba, ss);
    k_wtrans<<<192, 256, 0, stream>>>(Wq, Wk, Wv, Wsk, Wf1, Wf2, WT);
    k_input<<<512, 256, 0, stream>>>(x, Wn, bn, h);
    k_edge_count<<<256, 256, 0, stream>>>(ei, tm, Wee, bee, ea, deg);
    k_scan<<<1, 1024, 0, stream>>>(deg, rowptr);
    k_scatter<<<256, 256, 0, stream>>>(ei, rowptr, cursor, eorder);
    k_sort2<<<1024, 128, 0, stream>>>(rowptr, eorder, ei, ea, src_csr, ea_csr);

    for (int l = 0; l < LAYERS; l++) {
        const float* ssl = ss + l * 512;
        k_qkvs<<<dim3(32, 4), 256, 0, stream>>>(h, ssl, WT, l,
            bq + l * 128, bk + l * 128, bv + l * 128, bsk + l * 128,
            qb, kb, vb, skp);
        k_attn<<<512, 256, 0, stream>>>(qb, kb, vb, skp, h, src_csr, ea_csr,
                                        We + l * 128, rowptr);
        k_ffn<<<64, 256, 0, stream>>>(h, WT, l, bf1 + l * 256, bf2 + l * 128,
                                      ssl + 256, hbb, l == LAYERS - 1);
    }

    k_mprep<<<128, 256, 0, stream>>>(Wb, Wm1, Mst);
    k_mtrans<<<256, 256, 0, stream>>>(Mst, Mtb);
    k_p1<<<dim3(128, 8), 256, 0, stream>>>(hbb, Mtb, Ub);
    k_p2<<<dim3(1024, 2), 256, 0, stream>>>(hbb, Ub, cvec, Wm2, bm2, out);
}

// Round 11
// 266.280 us; speedup vs baseline: 5.6815x; 1.0771x over previous
//
#include <hip/hip_runtime.h>
#include <math.h>

#define N_NODES 1024
#define HDIM 128
#define EDGES 65536
#define LAYERS 6

typedef __attribute__((ext_vector_type(8))) short bf16x8;
typedef __attribute__((ext_vector_type(4))) float f32x4;

// workspace float offsets
#define OFF_H     0
#define OFF_Q     131072
#define OFF_K     262144
#define OFF_V     393216
#define OFF_SKP   524288
#define OFF_G     655360       // reused: src_csr (int E) + ea_csr (float E)
#define OFF_SS    917504
#define OFF_EA    920576
#define OFF_CVEC  986112
#define OFF_INT   986240
#define OFF_M     1054912      // fp32 M [128 k][16384 n], n = m*128 + l  (m-outer!)
#define OFF_U     3152064      // bf16 U [1024 i][16384 n]
#define OFF_MT    11540672     // bf16 Mt [16384 n][128 k]
#define OFF_HB    12589248     // bf16 hb [1024][128]
#define OFF_TMOD  12654784     // (unused now)
#define OFF_WB    12654912     // bf16 transposed weights: 24*16384 qkvs + 6*32768 f1 + 6*32768 f2 + 16384 Wm1T

#define WM1T_OFF  786432       // short offset of Wm1T inside WT

__device__ __forceinline__ float silu_f(float x) { return x / (1.f + expf(-x)); }
__device__ __forceinline__ float frcp(float x) { return __builtin_amdgcn_rcpf(x); }

__device__ __forceinline__ unsigned short f2bf(float f) {
    unsigned int u = __float_as_uint(f);
    u += 0x7FFFu + ((u >> 16) & 1u);
    return (unsigned short)(u >> 16);
}

// ---------------- fused setup: emb -> t_mod (redundant per block) -> ss slice; cvec ----
__global__ __launch_bounds__(256) void k_ssf(const void* tptr,
    const float* __restrict__ Wt1, const float* __restrict__ bt1,
    const float* __restrict__ Wt2, const float* __restrict__ bt2,
    const float* __restrict__ bb, const float* __restrict__ Wm1, const float* __restrict__ bm1,
    const float* __restrict__ Wa, const float* __restrict__ ba,
    float* __restrict__ ss_all, float* __restrict__ cvec)
{
    __shared__ float emb_s[256];
    __shared__ float part[2][128];
    __shared__ float tmp1_s[128];
    __shared__ float tmod_s[128];
    int tid = threadIdx.x;
    int iv = *(const int*)tptr;
    float fv = __int_as_float(iv);
    float tval = (iv > -1000000 && iv < 1000000) ? (float)iv : fv;
    {
        int fi = tid & 127;
        float fr = expf(-logf(10000.f) * (float)fi / 128.f);
        float ta = tval * fr;
        emb_s[tid] = (tid < 128) ? cosf(ta) : sinf(ta);
    }
    __syncthreads();
    {   // GEMV1 K=256: 2 slices x 128
        int col = tid & 127, sl = tid >> 7;
        float p = 0.f;
#pragma unroll 8
        for (int i = sl * 128; i < sl * 128 + 128; i++) p += emb_s[i] * Wt1[i * 128 + col];
        part[sl][col] = p;
    }
    __syncthreads();
    if (tid < 128) tmp1_s[tid] = silu_f(bt1[tid] + part[0][tid] + part[1][tid]);
    __syncthreads();
    {   // GEMV2 K=128
        int col = tid & 127, sl = tid >> 7;
        float p = 0.f;
#pragma unroll 8
        for (int i = sl * 64; i < sl * 64 + 64; i++) p += tmp1_s[i] * Wt2[i * 128 + col];
        part[sl][col] = p;
    }
    __syncthreads();
    if (tid < 128) tmod_s[tid] = silu_f(bt2[tid] + part[0][tid] + part[1][tid]);
    __syncthreads();
    {   // ss slice for this block
        int idx = blockIdx.x * 256 + tid;       // < 3072
        int l = idx >> 9, j = idx & 511;
        float a = ba[l * 512 + j];
        const float* w = Wa + l * 65536 + j;
#pragma unroll 4
        for (int k = 0; k < 128; k++) a += tmod_s[k] * w[k * 512];
        ss_all[idx] = a;
    }
    if (blockIdx.x == 0) {
        {
            int col = tid & 127, sl = tid >> 7;
            float p = 0.f;
#pragma unroll 8
            for (int i = sl * 64; i < sl * 64 + 64; i++) p += bb[i] * Wm1[i * 128 + col];
            part[sl][col] = p;
        }
        __syncthreads();
        if (tid < 128) cvec[tid] = bm1[tid] + part[0][tid] + part[1][tid];
    }
}

// ---------------- weight transpose+bf16: 196 tiles of 64x64 (incl. Wm1T) --------------
__global__ __launch_bounds__(256) void k_wtrans(
    const float* __restrict__ Wq, const float* __restrict__ Wk,
    const float* __restrict__ Wv, const float* __restrict__ Wsk,
    const float* __restrict__ Wf1, const float* __restrict__ Wf2,
    const float* __restrict__ Wm1, short* __restrict__ WT)
{
    __shared__ __align__(16) short T[64][80];
    int t = blockIdx.x;
    int tid = threadIdx.x;
    const float* src; short* dst; int K, N, kt, nt;
    if (t < 96) {
        int mat = t >> 2, sub = t & 3;
        int l = mat >> 2, m = mat & 3;
        src = (m == 0 ? Wq : m == 1 ? Wk : m == 2 ? Wv : Wsk) + l * 16384;
        dst = WT + (size_t)mat * 16384;
        K = 128; N = 128; kt = sub >> 1; nt = sub & 1;
    } else if (t < 144) {
        int i = t - 96; int l = i >> 3, sub = i & 7;
        src = Wf1 + l * 32768;
        dst = WT + 24 * 16384 + (size_t)l * 32768;
        K = 128; N = 256; kt = sub & 1; nt = sub >> 1;
    } else if (t < 192) {
        int i = t - 144; int l = i >> 3, sub = i & 7;
        src = Wf2 + l * 32768;
        dst = WT + 24 * 16384 + 6 * 32768 + (size_t)l * 32768;
        K = 256; N = 128; kt = sub >> 1; nt = sub & 1;
    } else {
        int sub = t - 192;
        src = Wm1;
        dst = WT + WM1T_OFF;
        K = 128; N = 128; kt = sub >> 1; nt = sub & 1;
    }
    int k0 = kt * 64, n0 = nt * 64;
    for (int p = 0; p < 16; p++) {
        int idx = p * 256 + tid;
        int kk = idx >> 6, nn = idx & 63;
        T[nn][kk] = (short)f2bf(src[(k0 + kk) * N + n0 + nn]);
    }
    __syncthreads();
    for (int p = 0; p < 2; p++) {
        int idx = p * 256 + tid;
        int nn = idx >> 3, sq = idx & 7;
        *(int4*)&dst[(size_t)(n0 + nn) * K + k0 + sq * 8] = *(const int4*)&T[nn][sq * 8];
    }
}

// ---------------- fused: h = x@Wn+bn (blocks 0..511) | edge_attr+deg (512..767) --------
__global__ __launch_bounds__(256) void k_inpedge(const float* __restrict__ x,
    const float* __restrict__ Wn, const float* __restrict__ bn, float* __restrict__ h,
    const int* __restrict__ ei, const float* __restrict__ tm,
    const float* __restrict__ Wee, const float* __restrict__ bee,
    float* __restrict__ ea, int* __restrict__ deg)
{
    int bid = blockIdx.x;
    int tid = threadIdx.x;
    if (bid < 512) {
        int idx = bid * 256 + tid;  // < 131072
        int i = idx >> 7, j = idx & 127;
        float acc = bn[j];
#pragma unroll
        for (int kk = 0; kk < 5; kk++) acc += x[i * 5 + kk] * Wn[kk * 128 + j];
        h[idx] = acc;
    } else {
        int e = (bid - 512) * 256 + tid;
        int s = ei[e], d = ei[EDGES + e];
        ea[e] = tm[s * N_NODES + d] * Wee[0] + bee[0];
        atomicAdd(&deg[d], 1);
    }
}

__global__ __launch_bounds__(1024) void k_scan(const int* __restrict__ deg, int* __restrict__ rowptr)
{
    __shared__ int tmp[1024];
    int tid = threadIdx.x;
    tmp[tid] = deg[tid];
    __syncthreads();
    for (int off = 1; off < 1024; off <<= 1) {
        int vv = (tid >= off) ? tmp[tid - off] : 0;
        __syncthreads();
        tmp[tid] += vv;
        __syncthreads();
    }
    rowptr[tid + 1] = tmp[tid];
    if (tid == 0) rowptr[0] = 0;
}

__global__ __launch_bounds__(256) void k_scatter(const int* __restrict__ ei,
    const int* __restrict__ rowptr, int* __restrict__ cursor, int* __restrict__ eorder)
{
    int e = blockIdx.x * 256 + threadIdx.x;
    int d = ei[EDGES + e];
    int pos = atomicAdd(&cursor[d], 1);
    eorder[rowptr[d] + pos] = e;
}

// ---------------- per-node bitonic sort + CSR flatten (fused) ----------------
__global__ __launch_bounds__(128) void k_sort2(const int* __restrict__ rowptr,
    int* __restrict__ eorder, const int* __restrict__ ei, const float* __restrict__ ea,
    int* __restrict__ src_csr, float* __restrict__ ea_csr)
{
    __shared__ int key[256];
    int node = blockIdx.x;
    int tid = threadIdx.x;
    int beg = rowptr[node], end = rowptr[node + 1];
    int n = end - beg;
    if (n <= 256) {
        for (int i = tid; i < 256; i += 128) key[i] = (i < n) ? eorder[beg + i] : 0x7FFFFFFF;
        __syncthreads();
        for (int k = 2; k <= 256; k <<= 1) {
            for (int j = k >> 1; j > 0; j >>= 1) {
                int i = ((tid / j) * 2 * j) + (tid % j);
                int l = i + j;
                bool up = ((i & k) == 0);
                int a = key[i], b = key[l];
                if ((a > b) == up) { key[i] = b; key[l] = a; }
                __syncthreads();
            }
        }
        for (int i = tid; i < n; i += 128) {
            int e = key[i];
            src_csr[beg + i] = ei[e];
            ea_csr[beg + i] = ea[e];
        }
    } else {
        if (tid == 0) {
            for (int i = beg + 1; i < end; ++i) {
                int kk = eorder[i];
                int j = i - 1;
                while (j >= beg && eorder[j] > kk) { eorder[j + 1] = eorder[j]; --j; }
                eorder[j + 1] = kk;
            }
        }
        __syncthreads();
        for (int i = tid; i < n; i += 128) {
            int e = eorder[beg + i];
            src_csr[beg + i] = ei[e];
            ea_csr[beg + i] = ea[e];
        }
    }
}

// ---------------- MFMA qkvs: 32 rows/block, grid (32, 4) ----------------
__global__ __launch_bounds__(256) void k_qkvs(const float* __restrict__ h,
    const float* __restrict__ ss, const short* __restrict__ WT, int layer,
    const float* __restrict__ bq, const float* __restrict__ bk,
    const float* __restrict__ bv, const float* __restrict__ bsk,
    float* __restrict__ q, float* __restrict__ k, float* __restrict__ v, float* __restrict__ skp)
{
    __shared__ __align__(16) short As[32][136];
    __shared__ float shs[128], scs[128];
    int tid = threadIdx.x;
    int r0 = blockIdx.x * 32;
    int mat = blockIdx.y;
    if (tid < 128) { shs[tid] = ss[tid]; scs[tid] = ss[128 + tid]; }
    __syncthreads();
    {   // LN+mod -> bf16 As. 8 threads per row, 16 cols each.
        int row = tid >> 3, o = tid & 7;
        const float* hr = h + (size_t)(r0 + row) * 128 + o * 16;
        float s = 0.f, s2 = 0.f;
#pragma unroll
        for (int j = 0; j < 4; j++) {
            float4 vv = *(const float4*)&hr[j * 4];
            s += vv.x + vv.y + vv.z + vv.w;
            s2 += vv.x * vv.x + vv.y * vv.y + vv.z * vv.z + vv.w * vv.w;
        }
        s += __shfl_xor(s, 1, 64); s2 += __shfl_xor(s2, 1, 64);
        s += __shfl_xor(s, 2, 64); s2 += __shfl_xor(s2, 2, 64);
        s += __shfl_xor(s, 4, 64); s2 += __shfl_xor(s2, 4, 64);
        float mu = s * (1.f / 128.f);
        float var = s2 * (1.f / 128.f) - mu * mu;
        float rs = rsqrtf(var + 1e-5f);
#pragma unroll
        for (int j = 0; j < 4; j++) {
            float4 vv = *(const float4*)&hr[j * 4];
            int cb = o * 16 + j * 4;
            short4 o4;
            o4.x = (short)f2bf((vv.x - mu) * rs * (1.f + scs[cb])     + shs[cb]);
            o4.y = (short)f2bf((vv.y - mu) * rs * (1.f + scs[cb + 1]) + shs[cb + 1]);
            o4.z = (short)f2bf((vv.z - mu) * rs * (1.f + scs[cb + 2]) + shs[cb + 2]);
            o4.w = (short)f2bf((vv.w - mu) * rs * (1.f + scs[cb + 3]) + shs[cb + 3]);
            *(short4*)&As[row][cb] = o4;
        }
    }
    __syncthreads();
    int w = tid >> 6, lane = tid & 63, c = lane & 15, g = lane >> 4;
    const short* Wm = WT + (size_t)(layer * 4 + mat) * 16384;
    f32x4 acc[2][2] = {};
#pragma unroll
    for (int kq = 0; kq < 4; kq++) {
        int ko = kq * 32 + g * 8;
        bf16x8 a0 = *(const bf16x8*)&As[c][ko];
        bf16x8 a1 = *(const bf16x8*)&As[16 + c][ko];
#pragma unroll
        for (int nt = 0; nt < 2; nt++) {
            bf16x8 bfr = *(const bf16x8*)&Wm[(size_t)(w * 32 + nt * 16 + c) * 128 + ko];
            acc[0][nt] = __builtin_amdgcn_mfma_f32_16x16x32_bf16(a0, bfr, acc[0][nt], 0, 0, 0);
            acc[1][nt] = __builtin_amdgcn_mfma_f32_16x16x32_bf16(a1, bfr, acc[1][nt], 0, 0, 0);
        }
    }
    const float* bias; float* out;
    switch (mat) {
        case 0:  bias = bq;  out = q;   break;
        case 1:  bias = bk;  out = k;   break;
        case 2:  bias = bv;  out = v;   break;
        default: bias = bsk; out = skp; break;
    }
#pragma unroll
    for (int it = 0; it < 2; it++)
#pragma unroll
        for (int nt = 0; nt < 2; nt++) {
            int n = w * 32 + nt * 16 + c;
            float bv2 = bias[n];
#pragma unroll
            for (int r = 0; r < 4; r++) {
                int i = r0 + it * 16 + g * 4 + r;
                out[(size_t)i * 128 + n] = acc[it][nt][r] + bv2;
            }
        }
}

// ---------------- MFMA FFN: 16 rows/block, grid 64; last layer also writes hb ---------
__global__ __launch_bounds__(256) void k_ffn(float* __restrict__ h,
    const short* __restrict__ WT, int layer,
    const float* __restrict__ bf1, const float* __restrict__ bf2,
    const float* __restrict__ ss2, short* __restrict__ hb, int last)
{
    __shared__ __align__(16) short As[16][136];
    __shared__ __align__(16) short Gs[16][264];
    __shared__ float shs[128], scs[128];
    int tid = threadIdx.x;
    int r0 = blockIdx.x * 16;
    if (tid < 128) { shs[tid] = ss2[tid]; scs[tid] = ss2[128 + tid]; }
    __syncthreads();
    {   // LN+mod: 16 threads per row, 8 cols each
        int row = tid >> 4, o = tid & 15;
        const float* hr = h + (size_t)(r0 + row) * 128 + o * 8;
        float s = 0.f, s2 = 0.f;
#pragma unroll
        for (int j = 0; j < 2; j++) {
            float4 vv = *(const float4*)&hr[j * 4];
            s += vv.x + vv.y + vv.z + vv.w;
            s2 += vv.x * vv.x + vv.y * vv.y + vv.z * vv.z + vv.w * vv.w;
        }
        s += __shfl_xor(s, 1, 64); s2 += __shfl_xor(s2, 1, 64);
        s += __shfl_xor(s, 2, 64); s2 += __shfl_xor(s2, 2, 64);
        s += __shfl_xor(s, 4, 64); s2 += __shfl_xor(s2, 4, 64);
        s += __shfl_xor(s, 8, 64); s2 += __shfl_xor(s2, 8, 64);
        float mu = s * (1.f / 128.f);
        float var = s2 * (1.f / 128.f) - mu * mu;
        float rs = rsqrtf(var + 1e-5f);
#pragma unroll
        for (int j = 0; j < 2; j++) {
            float4 vv = *(const float4*)&hr[j * 4];
            int cb = o * 8 + j * 4;
            short4 o4;
            o4.x = (short)f2bf((vv.x - mu) * rs * (1.f + scs[cb])     + shs[cb]);
            o4.y = (short)f2bf((vv.y - mu) * rs * (1.f + scs[cb + 1]) + shs[cb + 1]);
            o4.z = (short)f2bf((vv.z - mu) * rs * (1.f + scs[cb + 2]) + shs[cb + 2]);
            o4.w = (short)f2bf((vv.w - mu) * rs * (1.f + scs[cb + 3]) + shs[cb + 3]);
            *(short4*)&As[row][cb] = o4;
        }
    }
    __syncthreads();
    int w = tid >> 6, lane = tid & 63, c = lane & 15, g = lane >> 4;
    const short* W1 = WT + 24 * 16384 + (size_t)layer * 32768;
    const short* W2 = WT + 24 * 16384 + 6 * 32768 + (size_t)layer * 32768;
    {   // f1: wave w covers cols w*64 + nt*16 + c (nt 0..3)
        f32x4 acc[4] = {};
#pragma unroll
        for (int kq = 0; kq < 4; kq++) {
            int ko = kq * 32 + g * 8;
            bf16x8 a0 = *(const bf16x8*)&As[c][ko];
#pragma unroll
            for (int nt = 0; nt < 4; nt++) {
                bf16x8 bfr = *(const bf16x8*)&W1[(size_t)(w * 64 + nt * 16 + c) * 128 + ko];
                acc[nt] = __builtin_amdgcn_mfma_f32_16x16x32_bf16(a0, bfr, acc[nt], 0, 0, 0);
            }
        }
#pragma unroll
        for (int nt = 0; nt < 4; nt++) {
            int n = w * 64 + nt * 16 + c;
            float bv = bf1[n];
#pragma unroll
            for (int r = 0; r < 4; r++) {
                float y = acc[nt][r] + bv;
                float gl = 0.5f * y * (1.f + erff(y * 0.70710678118654752f));
                Gs[g * 4 + r][n] = (short)f2bf(gl);
            }
        }
    }
    __syncthreads();
    {   // f2: K=256; wave w covers cols w*32 + nt2*16 + c
        f32x4 acc2[2] = {};
#pragma unroll
        for (int kq = 0; kq < 8; kq++) {
            int ko = kq * 32 + g * 8;
            bf16x8 a0 = *(const bf16x8*)&Gs[c][ko];
#pragma unroll
            for (int nt2 = 0; nt2 < 2; nt2++) {
                bf16x8 bfr = *(const bf16x8*)&W2[(size_t)(w * 32 + nt2 * 16 + c) * 256 + ko];
                acc2[nt2] = __builtin_amdgcn_mfma_f32_16x16x32_bf16(a0, bfr, acc2[nt2], 0, 0, 0);
            }
        }
#pragma unroll
        for (int nt2 = 0; nt2 < 2; nt2++) {
            int n = w * 32 + nt2 * 16 + c;
            float bv = bf2[n];
#pragma unroll
            for (int r = 0; r < 4; r++) {
                int i = r0 + g * 4 + r;
                float nv = h[(size_t)i * 128 + n] + acc2[nt2][r] + bv;
                h[(size_t)i * 128 + n] = nv;
                if (last) hb[(size_t)i * 128 + n] = (short)f2bf(nv);
            }
        }
    }
}

// ---------------- attention: 4 waves per node (quarter-chains), LDS 4-way merge -------
__global__ __launch_bounds__(256) void k_attn(const float* __restrict__ q,
    const float* __restrict__ k, const float* __restrict__ v,
    const float* __restrict__ skp, float* __restrict__ h,
    const int* __restrict__ src_csr, const float* __restrict__ ea_csr,
    const float* __restrict__ We_l, const int* __restrict__ rowptr)
{
    __shared__ float ms[3][64], ssb[3][64], a0s[3][64], a1s[3][64];
    int tid = threadIdx.x;
    int wid = tid >> 6;            // 0..3 = quarter
    int lane = tid & 63;
    int node = blockIdx.x;
    int c0 = lane * 2;
    float2 q2 = *(const float2*)&q[node * 128 + c0];
    float we0 = We_l[c0], we1 = We_l[c0 + 1];
    int beg = rowptr[node], end = rowptr[node + 1];
    int n = end - beg;
    int tb = beg + (n * wid) / 4;
    int te = beg + (n * (wid + 1)) / 4;
    float m = -INFINITY, s = 0.f, a0 = 0.f, a1 = 0.f;
    const float isc = 0.17677669529663687f;  // 1/sqrt(32)

    int t = tb;
    for (; t + 3 < te; t += 4) {
        int sn0 = src_csr[t],     sn1 = src_csr[t + 1];
        int sn2 = src_csr[t + 2], sn3 = src_csr[t + 3];
        float e0 = ea_csr[t],     e1 = ea_csr[t + 1];
        float e2 = ea_csr[t + 2], e3 = ea_csr[t + 3];
        float2 k0 = *(const float2*)&k[sn0 * 128 + c0];
        float2 k1 = *(const float2*)&k[sn1 * 128 + c0];
        float2 k2 = *(const float2*)&k[sn2 * 128 + c0];
        float2 k3 = *(const float2*)&k[sn3 * 128 + c0];
        float2 v0 = *(const float2*)&v[sn0 * 128 + c0];
        float2 v1 = *(const float2*)&v[sn1 * 128 + c0];
        float2 v2 = *(const float2*)&v[sn2 * 128 + c0];
        float2 v3 = *(const float2*)&v[sn3 * 128 + c0];
        float p0 = q2.x * (k0.x + e0 * we0) + q2.y * (k0.y + e0 * we1);
        float p1 = q2.x * (k1.x + e1 * we0) + q2.y * (k1.y + e1 * we1);
        float p2 = q2.x * (k2.x + e2 * we0) + q2.y * (k2.y + e2 * we1);
        float p3 = q2.x * (k3.x + e3 * we0) + q2.y * (k3.y + e3 * we1);
        p0 += __shfl_xor(p0, 1, 16); p1 += __shfl_xor(p1, 1, 16);
        p2 += __shfl_xor(p2, 1, 16); p3 += __shfl_xor(p3, 1, 16);
        p0 += __shfl_xor(p0, 2, 16); p1 += __shfl_xor(p1, 2, 16);
        p2 += __shfl_xor(p2, 2, 16); p3 += __shfl_xor(p3, 2, 16);
        p0 += __shfl_xor(p0, 4, 16); p1 += __shfl_xor(p1, 4, 16);
        p2 += __shfl_xor(p2, 4, 16); p3 += __shfl_xor(p3, 4, 16);
        p0 += __shfl_xor(p0, 8, 16); p1 += __shfl_xor(p1, 8, 16);
        p2 += __shfl_xor(p2, 8, 16); p3 += __shfl_xor(p3, 8, 16);
        {
            float al = p0 * isc;
            float mn = fmaxf(m, al);
            float scale = __expf(m - mn), wq = __expf(al - mn);
            s = s * scale + wq;
            a0 = a0 * scale + wq * (v0.x + e0 * we0);
            a1 = a1 * scale + wq * (v0.y + e0 * we1);
            m = mn;
        }
        {
            float al = p1 * isc;
            float mn = fmaxf(m, al);
            float scale = __expf(m - mn), wq = __expf(al - mn);
            s = s * scale + wq;
            a0 = a0 * scale + wq * (v1.x + e1 * we0);
            a1 = a1 * scale + wq * (v1.y + e1 * we1);
            m = mn;
        }
        {
            float al = p2 * isc;
            float mn = fmaxf(m, al);
            float scale = __expf(m - mn), wq = __expf(al - mn);
            s = s * scale + wq;
            a0 = a0 * scale + wq * (v2.x + e2 * we0);
            a1 = a1 * scale + wq * (v2.y + e2 * we1);
            m = mn;
        }
        {
            float al = p3 * isc;
            float mn = fmaxf(m, al);
            float scale = __expf(m - mn), wq = __expf(al - mn);
            s = s * scale + wq;
            a0 = a0 * scale + wq * (v3.x + e3 * we0);
            a1 = a1 * scale + wq * (v3.y + e3 * we1);
            m = mn;
        }
    }
    for (; t < te; ++t) {
        int sn = src_csr[t];
        float eav = ea_csr[t];
        float2 kv = *(const float2*)&k[sn * 128 + c0];
        float2 vv = *(const float2*)&v[sn * 128 + c0];
        float part = q2.x * (kv.x + eav * we0) + q2.y * (kv.y + eav * we1);
        part += __shfl_xor(part, 1, 16);
        part += __shfl_xor(part, 2, 16);
        part += __shfl_xor(part, 4, 16);
        part += __shfl_xor(part, 8, 16);
        float alpha = part * isc;
        float mn = fmaxf(m, alpha);
        float scale = __expf(m - mn), wq = __expf(alpha - mn);
        s = s * scale + wq;
        a0 = a0 * scale + wq * (vv.x + eav * we0);
        a1 = a1 * scale + wq * (vv.y + eav * we1);
        m = mn;
    }
    if (wid > 0) {
        ms[wid - 1][lane] = m; ssb[wid - 1][lane] = s;
        a0s[wid - 1][lane] = a0; a1s[wid - 1][lane] = a1;
    }
    __syncthreads();
    if (wid == 0) {
#pragma unroll
        for (int p = 0; p < 3; p++) {
            float mB = ms[p][lane], sB = ssb[p][lane];
            float b0 = a0s[p][lane], b1 = a1s[p][lane];
            float mm = fmaxf(m, mB);
            float eA = (m  > -1e30f) ? __expf(m  - mm) : 0.f;
            float eB = (mB > -1e30f) ? __expf(mB - mm) : 0.f;
            s = s * eA + sB * eB;
            a0 = a0 * eA + b0 * eB;
            a1 = a1 * eA + b1 * eB;
            m = mm;
        }
        float inv = (s > 0.f) ? 1.f / (s + 1e-16f) : 0.f;
        int o = node * 128 + c0;
        h[o]     += skp[o]     + a0 * inv;
        h[o + 1] += skp[o + 1] + a1 * inv;
    }
}

// ---------------- MFMA mprep: per k, M_k[m][l] = Wm1T(m,o) x Wb_k(l,o)^T ----------------
__global__ __launch_bounds__(256) void k_mprep(const float* __restrict__ Wb,
    const short* __restrict__ WT, float* __restrict__ M)
{
    __shared__ __align__(16) short Bls[128][136];   // [l][o] bf16
    int tid = threadIdx.x;
    int k = blockIdx.x;
    const short* Wm1T = WT + WM1T_OFF;
    {   // stage Wb[:,k,:] transposed: lanes read 128 contiguous l for one o
        int lq = (tid & 31) * 4;
        int ob = tid >> 5;  // 0..7
        for (int it = 0; it < 16; it++) {
            int o = it * 8 + ob;
            float4 vv = *(const float4*)&Wb[(size_t)o * 16384 + k * 128 + lq];
            Bls[lq][o]     = (short)f2bf(vv.x);
            Bls[lq + 1][o] = (short)f2bf(vv.y);
            Bls[lq + 2][o] = (short)f2bf(vv.z);
            Bls[lq + 3][o] = (short)f2bf(vv.w);
        }
    }
    __syncthreads();
    int w = tid >> 6, lane = tid & 63, c = lane & 15, g = lane >> 4;
    f32x4 acc[2][8] = {};
#pragma unroll
    for (int kq = 0; kq < 4; kq++) {
        int ko = kq * 32 + g * 8;
        bf16x8 a0 = *(const bf16x8*)&Wm1T[(size_t)(w * 32 + c) * 128 + ko];
        bf16x8 a1 = *(const bf16x8*)&Wm1T[(size_t)(w * 32 + 16 + c) * 128 + ko];
#pragma unroll
        for (int nt = 0; nt < 8; nt++) {
            bf16x8 b = *(const bf16x8*)&Bls[nt * 16 + c][ko];
            acc[0][nt] = __builtin_amdgcn_mfma_f32_16x16x32_bf16(a0, b, acc[0][nt], 0, 0, 0);
            acc[1][nt] = __builtin_amdgcn_mfma_f32_16x16x32_bf16(a1, b, acc[1][nt], 0, 0, 0);
        }
    }
    float* Mk = M + (size_t)k * 16384;
#pragma unroll
    for (int it = 0; it < 2; it++)
#pragma unroll
        for (int nt = 0; nt < 8; nt++)
#pragma unroll
            for (int r = 0; r < 4; r++) {
                int m = w * 32 + it * 16 + g * 4 + r;
                int l = nt * 16 + c;
                Mk[m * 128 + l] = acc[it][nt][r];
            }
}

// ---------------- Mt[n][k] (bf16) <- M[k][n] (fp32) ----------------
__global__ __launch_bounds__(256) void k_mtrans(const float* __restrict__ M,
                                                short* __restrict__ Mt)
{
    __shared__ __align__(16) short Ts[64][136];
    int tid = threadIdx.x;
    int n0 = blockIdx.x * 64;
    for (int p = 0; p < 32; p++) {
        int idx = p * 256 + tid;
        int k = idx >> 6, nn = idx & 63;
        Ts[nn][k] = (short)f2bf(M[(size_t)k * 16384 + n0 + nn]);
    }
    __syncthreads();
    for (int p = 0; p < 4; p++) {
        int idx = p * 256 + tid;
        int nn = idx >> 4, s = idx & 15;
        *(int4*)&Mt[(size_t)(n0 + nn) * 128 + s * 8] = *(const int4*)&Ts[nn][s * 8];
    }
}

// ---------------- phase1 MFMA: U[i][n] = sum_k hb[i,k] * Mt[n,k] ----------------
__global__ __launch_bounds__(256) void k_p1(const short* __restrict__ hb,
    const short* __restrict__ Mt, short* __restrict__ U)
{
    __shared__ __align__(16) short As[128][72];
    __shared__ __align__(16) short Bs[128][72];
    int tid = threadIdx.x;
    int n0 = blockIdx.x * 128;
    int i0 = blockIdx.y * 128;
    int w = tid >> 6, lane = tid & 63, c = lane & 15, g = lane >> 4;
    f32x4 acc[2][8] = {};
    for (int kh = 0; kh < 2; kh++) {
        __syncthreads();
        for (int idx = tid; idx < 1024; idx += 256) {
            int r = idx >> 3, s = idx & 7;
            *(int4*)&As[r][s * 8] = *(const int4*)&hb[(i0 + r) * 128 + kh * 64 + s * 8];
            *(int4*)&Bs[r][s * 8] = *(const int4*)&Mt[(size_t)(n0 + r) * 128 + kh * 64 + s * 8];
        }
        __syncthreads();
#pragma unroll
        for (int kk = 0; kk < 2; kk++) {
            int ko = kk * 32 + g * 8;
            bf16x8 a0 = *(const bf16x8*)&As[w * 32 + c][ko];
            bf16x8 a1 = *(const bf16x8*)&As[w * 32 + 16 + c][ko];
#pragma unroll
            for (int nt = 0; nt < 8; nt++) {
                bf16x8 b = *(const bf16x8*)&Bs[nt * 16 + c][ko];
                acc[0][nt] = __builtin_amdgcn_mfma_f32_16x16x32_bf16(a0, b, acc[0][nt], 0, 0, 0);
                acc[1][nt] = __builtin_amdgcn_mfma_f32_16x16x32_bf16(a1, b, acc[1][nt], 0, 0, 0);
            }
        }
    }
#pragma unroll
    for (int it = 0; it < 2; it++)
#pragma unroll
        for (int nt = 0; nt < 8; nt++)
#pragma unroll
            for (int r = 0; r < 4; r++) {
                int i = i0 + w * 32 + it * 16 + g * 4 + r;
                int n = n0 + nt * 16 + c;
                U[(size_t)i * 16384 + n] = (short)f2bf(acc[it][nt][r]);
            }
}

// ---------------- phase2 MFMA: block = (i, j-half); U_i staged once; H frags from L2 ---
__global__ __launch_bounds__(256) void k_p2(const short* __restrict__ hb,
    const short* __restrict__ U, const float* __restrict__ cvec,
    const float* __restrict__ Wm2, const float* __restrict__ bm2,
    float* __restrict__ out)
{
    __shared__ __align__(16) short Us[128][136];
    __shared__ float cvs[128];
    __shared__ float w2s[128][4];
    int tid = threadIdx.x;
    int i = blockIdx.x;
    int jb = blockIdx.y;          // 0..1
    int b = i >> 8;
    int w = tid >> 6, lane = tid & 63, c = lane & 15, g = lane >> 4;
    if (tid < 128) {
        cvs[tid] = cvec[tid];
        *(float4*)&w2s[tid][0] = *(const float4*)&Wm2[tid * 4];
    }
    bf16x8 hf[2][4];
    {
        const short* hrow = hb + (size_t)(b * 256 + jb * 128 + w * 32 + c) * 128;
#pragma unroll
        for (int jt = 0; jt < 2; jt++)
#pragma unroll
            for (int kq = 0; kq < 4; kq++)
                hf[jt][kq] = *(const bf16x8*)(hrow + jt * 16 * 128 + kq * 32 + g * 8);
    }
    for (int idx = tid; idx < 2048; idx += 256) {
        int r = idx >> 4, s = idx & 15;
        *(int4*)&Us[r][s * 8] = *(const int4*)&U[(size_t)i * 16384 + r * 128 + s * 8];
    }
    __syncthreads();
    f32x4 acc[2][8] = {};
#pragma unroll
    for (int kq = 0; kq < 4; kq++) {
        int ko = kq * 32 + g * 8;
#pragma unroll
        for (int mt = 0; mt < 8; mt++) {
            bf16x8 uv = *(const bf16x8*)&Us[mt * 16 + c][ko];
            acc[0][mt] = __builtin_amdgcn_mfma_f32_16x16x32_bf16(uv, hf[0][kq], acc[0][mt], 0, 0, 0);
            acc[1][mt] = __builtin_amdgcn_mfma_f32_16x16x32_bf16(uv, hf[1][kq], acc[1][mt], 0, 0, 0);
        }
    }
    float4 bmv = *(const float4*)&bm2[0];
#pragma unroll
    for (int jt = 0; jt < 2; jt++) {
        float p0 = 0.f, p1 = 0.f, p2 = 0.f, p3 = 0.f;
#pragma unroll
        for (int mt = 0; mt < 8; mt++) {
#pragma unroll
            for (int r = 0; r < 4; r++) {
                int m = mt * 16 + g * 4 + r;
                float y = acc[jt][mt][r] + cvs[m];
                float sv = y * frcp(1.f + __expf(-y));
                p0 += sv * w2s[m][0]; p1 += sv * w2s[m][1];
                p2 += sv * w2s[m][2]; p3 += sv * w2s[m][3];
            }
        }
        p0 += __shfl_xor(p0, 16, 64); p1 += __shfl_xor(p1, 16, 64);
        p2 += __shfl_xor(p2, 16, 64); p3 += __shfl_xor(p3, 16, 64);
        p0 += __shfl_xor(p0, 32, 64); p1 += __shfl_xor(p1, 32, 64);
        p2 += __shfl_xor(p2, 32, 64); p3 += __shfl_xor(p3, 32, 64);
        if (g == 0) {
            int j = jb * 128 + w * 32 + jt * 16 + c;
            float4 o4 = { p0 + bmv.x, p1 + bmv.y, p2 + bmv.z, p3 + bmv.w };
            *(float4*)&out[((size_t)i * 256 + j) * 4] = o4;
        }
    }
}

extern "C" void kernel_launch(void* const* d_in, const int* in_sizes, int n_in,
                              void* d_out, int out_size, void* d_ws, size_t ws_size,
                              hipStream_t stream)
{
    const float* x   = (const float*)d_in[0];
    const int*   ei  = (const int*)d_in[1];
    const void*  tptr= d_in[3];
    const float* tm  = (const float*)d_in[4];
    const float* Wn  = (const float*)d_in[5];
    const float* bn  = (const float*)d_in[6];
    const float* Wee = (const float*)d_in[7];
    const float* bee = (const float*)d_in[8];
    const float* Wt1 = (const float*)d_in[9];
    const float* bt1 = (const float*)d_in[10];
    const float* Wt2 = (const float*)d_in[11];
    const float* bt2 = (const float*)d_in[12];
    const float* Wa  = (const float*)d_in[13];
    const float* ba  = (const float*)d_in[14];
    const float* Wq  = (const float*)d_in[15];
    const float* bq  = (const float*)d_in[16];
    const float* Wk  = (const float*)d_in[17];
    const float* bk  = (const float*)d_in[18];
    const float* Wv  = (const float*)d_in[19];
    const float* bv  = (const float*)d_in[20];
    const float* We  = (const float*)d_in[21];
    const float* Wsk = (const float*)d_in[22];
    const float* bsk = (const float*)d_in[23];
    const float* Wf1 = (const float*)d_in[24];
    const float* bf1 = (const float*)d_in[25];
    const float* Wf2 = (const float*)d_in[26];
    const float* bf2 = (const float*)d_in[27];
    const float* Wb  = (const float*)d_in[28];
    const float* bb  = (const float*)d_in[29];
    const float* Wm1 = (const float*)d_in[30];
    const float* bm1 = (const float*)d_in[31];
    const float* Wm2 = (const float*)d_in[32];
    const float* bm2 = (const float*)d_in[33];
    float* out = (float*)d_out;
    float* ws = (float*)d_ws;

    float* h    = ws + OFF_H;
    float* qb   = ws + OFF_Q;
    float* kb   = ws + OFF_K;
    float* vb   = ws + OFF_V;
    float* skp  = ws + OFF_SKP;
    float* ss   = ws + OFF_SS;
    float* ea   = ws + OFF_EA;
    float* cvec = ws + OFF_CVEC;
    int* iws    = (int*)(ws + OFF_INT);
    int* deg    = iws;
    int* cursor = iws + 1024;
    int* rowptr = iws + 2048;
    int* eorder = iws + 3073;
    int* src_csr   = (int*)(ws + OFF_G);
    float* ea_csr  = ws + OFF_G + 65536;
    float* Mst  = ws + OFF_M;
    short* Ub   = (short*)(ws + OFF_U);
    short* Mtb  = (short*)(ws + OFF_MT);
    short* hbb  = (short*)(ws + OFF_HB);
    short* WT   = (short*)(ws + OFF_WB);

    hipMemsetAsync(deg, 0, 2048 * sizeof(int), stream);
    k_ssf<<<12, 256, 0, stream>>>(tptr, Wt1, bt1, Wt2, bt2, bb, Wm1, bm1, Wa, ba, ss, cvec);
    k_wtrans<<<196, 256, 0, stream>>>(Wq, Wk, Wv, Wsk, Wf1, Wf2, Wm1, WT);
    k_inpedge<<<768, 256, 0, stream>>>(x, Wn, bn, h, ei, tm, Wee, bee, ea, deg);
    k_scan<<<1, 1024, 0, stream>>>(deg, rowptr);
    k_scatter<<<256, 256, 0, stream>>>(ei, rowptr, cursor, eorder);
    k_sort2<<<1024, 128, 0, stream>>>(rowptr, eorder, ei, ea, src_csr, ea_csr);

    for (int l = 0; l < LAYERS; l++) {
        const float* ssl = ss + l * 512;
        k_qkvs<<<dim3(32, 4), 256, 0, stream>>>(h, ssl, WT, l,
            bq + l * 128, bk + l * 128, bv + l * 128, bsk + l * 128,
            qb, kb, vb, skp);
        k_attn<<<1024, 256, 0, stream>>>(qb, kb, vb, skp, h, src_csr, ea_csr,
                                         We + l * 128, rowptr);
        k_ffn<<<64, 256, 0, stream>>>(h, WT, l, bf1 + l * 256, bf2 + l * 128,
                                      ssl + 256, hbb, l == LAYERS - 1);
    }

    k_mprep<<<128, 256, 0, stream>>>(Wb, WT, Mst);
    k_mtrans<<<256, 256, 0, stream>>>(Mst, Mtb);
    k_p1<<<dim3(128, 8), 256, 0, stream>>>(hbb, Mtb, Ub);
    k_p2<<<dim3(1024, 2), 256, 0, stream>>>(hbb, Ub, cvec, Wm2, bm2, out);
}